// Round 7
// baseline (1519.358 us; speedup 1.0000x reference)
//
#include <hip/hip_runtime.h>
#include <math.h>

// ---------------------------------------------------------------------------
// ModularSelectCascadeNet forward. B=16384, M=8, NUM_LAYERS=4.
// R7: megakernel spill fix (per-slice acc[2][4], no launch_bounds reg cap,
//     dynamic LDS, A-tile kept live). W0 GEMMs batched via grid.z.
// ---------------------------------------------------------------------------

#define EPI_NONE  0
#define EPI_RELU  1
#define EPI_TANH  2
#define EPI_COND  3
#define EPI_STATS 4

typedef short bf16x8 __attribute__((ext_vector_type(8)));
typedef float f32x4 __attribute__((ext_vector_type(4)));

__device__ __forceinline__ unsigned short f2bf(float f) {
  unsigned u = __float_as_uint(f);
  u += 0x7fffu + ((u >> 16) & 1u);
  return (unsigned short)(u >> 16);
}
__device__ __forceinline__ float bf2f(unsigned short h) {
  return __uint_as_float(((unsigned)h) << 16);
}
__device__ __forceinline__ void gload_lds16(const void* g, void* l) {
  __builtin_amdgcn_global_load_lds(
      (const __attribute__((address_space(1))) unsigned int*)g,
      (__attribute__((address_space(3))) unsigned int*)l, 16, 0, 0);
}
__device__ __forceinline__ bf16x8 relu_bf8(bf16x8 v) {
  bf16x8 r;
  #pragma unroll
  for (int j = 0; j < 8; ++j) r[j] = v[j] > 0 ? v[j] : (short)0;
  return r;
}

// ---------------------------------------------------------------------------
// Fused prep (unchanged from R5/R6).
__global__ __launch_bounds__(256) void prep_all(
    const float* __restrict__ x, const float* __restrict__ embi,
    const float* __restrict__ base_W0, const float* __restrict__ em_W0,
    const float* __restrict__ base_W1, const float* __restrict__ gat_W0,
    const float* __restrict__ gat_W1, const float* __restrict__ sel_W,
    const float* __restrict__ cond_W, const float* __restrict__ last_W,
    unsigned short* __restrict__ x_bf, unsigned short* __restrict__ e_bf,
    unsigned short* __restrict__ W0t, unsigned short* __restrict__ emW0t,
    unsigned short* __restrict__ W1t, unsigned short* __restrict__ g0t,
    unsigned short* __restrict__ g1t, unsigned short* __restrict__ selWt,
    unsigned short* __restrict__ condWt, unsigned short* __restrict__ lastWt,
    float* __restrict__ stats)
{
  __shared__ float t[32][33];
  int bid = blockIdx.x;
  const int tid = threadIdx.x;

  if (bid < 4096) {
    const float* src = bid < 2048 ? x : embi;
    unsigned short* dst = bid < 2048 ? x_bf : e_bf;
    const int i = ((bid & 2047) * 256 + tid) * 4;
    const float4 v = *reinterpret_cast<const float4*>(&src[i]);
    ushort4 o;
    o.x = f2bf(v.x); o.y = f2bf(v.y); o.z = f2bf(v.z); o.w = f2bf(v.w);
    *reinterpret_cast<ushort4*>(&dst[i]) = o;
    return;
  }
  bid -= 4096;

  const int tx = tid & 31, ty = tid >> 5;

  if (bid < 496) {
    const float* src; unsigned short* dst; int K, N, KP, gx, local;
    if (bid < 64)       { src = base_W0; dst = W0t;   K = 128; N = 400; KP = 128; gx = 4;  local = bid; }
    else if (bid < 128) { src = em_W0;   dst = emW0t; K = 128; N = 400; KP = 128; gx = 4;  local = bid - 64; }
    else if (bid < 232) { src = base_W1; dst = W1t;   K = 400; N = 256; KP = 416; gx = 13; local = bid - 128; }
    else if (bid < 336) { src = gat_W0;  dst = g0t;   K = 400; N = 256; KP = 416; gx = 13; local = bid - 232; }
    else if (bid < 400) { src = gat_W1;  dst = g1t;   K = 256; N = 256; KP = 256; gx = 8;  local = bid - 336; }
    else if (bid < 448) {
      const int i = (bid - 400) / 16;
      src = sel_W + i * 16384; dst = selWt + i * 16384;
      K = 256; N = 64; KP = 256; gx = 8; local = (bid - 400) % 16;
    } else {
      const int i = (bid - 448) / 16;
      src = cond_W + i * 16384; dst = condWt + i * 16384;
      K = 64; N = 256; KP = 64; gx = 2; local = (bid - 448) % 16;
    }
    const int k0 = (local % gx) * 32, n0 = (local / gx) * 32;
    #pragma unroll
    for (int p = 0; p < 4; ++p) {
      const int k = k0 + ty + p * 8;
      t[ty + p * 8][tx] = (k < K && n0 + tx < N) ? src[(size_t)k * N + n0 + tx] : 0.f;
    }
    __syncthreads();
    #pragma unroll
    for (int p = 0; p < 4; ++p) {
      const int n = n0 + ty + p * 8;
      dst[(size_t)n * KP + k0 + tx] = f2bf(t[tx][ty + p * 8]);
    }
    return;
  }
  bid -= 496;

  if (bid < 8) {
    const int k0 = bid * 32;
    #pragma unroll
    for (int p = 0; p < 4; ++p)
      t[ty + p * 8][tx] = (tx < 18) ? last_W[(size_t)(k0 + ty + p * 8) * 18 + tx] : 0.f;
    __syncthreads();
    #pragma unroll
    for (int p = 0; p < 4; ++p) {
      const int n = ty + p * 8;
      lastWt[(size_t)n * 256 + k0 + tx] = f2bf(t[tx][n]);
      lastWt[(size_t)(n + 32) * 256 + k0 + tx] = 0;
    }
    return;
  }

  for (int i = tid; i < 4608; i += 256) stats[i] = 0.f;
}

// ---------------------------------------------------------------------------
// Generic bf16 MFMA GEMM for the front chain. BM=128, BK=32.
// Optional grid.z batching: when blockIdx.z==1, use (A2, W2, bias_b, C2).
template<int BN, int WM, int WN, int EPI, bool RELU_A>
__global__ __launch_bounds__(256) void gemm_bf16(
    const unsigned short* __restrict__ A, int AS,
    const unsigned short* __restrict__ Wt, const float* __restrict__ bias,
    unsigned short* __restrict__ C, int CS, int Nreal, int NP, int K,
    const unsigned short* __restrict__ emb,
    float* __restrict__ sum, float* __restrict__ sumsq,
    const unsigned short* A2, const unsigned short* W2,
    const float* bias_b, unsigned short* C2)
{
  constexpr int FRAG_M = 128 / WM / 16;
  constexpr int FRAG_N = BN / WN / 16;
  __shared__ unsigned short As[128 * 32];
  __shared__ unsigned short Bs[BN * 32];
  const unsigned short* Ap = (blockIdx.z == 0) ? A : A2;
  const unsigned short* Wp = (blockIdx.z == 0) ? Wt : W2;
  const float* bp = (blockIdx.z == 0) ? bias : bias_b;
  unsigned short* Cp = (blockIdx.z == 0) ? C : C2;
  const int row0 = blockIdx.y * 128;
  const int n0 = blockIdx.x * BN;
  const int tid = threadIdx.x;
  const int wid = tid >> 6, lane = tid & 63;
  const int wr = wid / WN, wc = wid % WN;
  const int arow = tid >> 2;
  const int kcol = (tid & 3) * 8;
  const int lr = lane & 15, lk = (lane >> 4) * 8;
  const int lrow = (lane >> 4) * 4;

  f32x4 acc[FRAG_M][FRAG_N] = {};
  for (int k0 = 0; k0 < K; k0 += 32) {
    gload_lds16(Ap + (size_t)(row0 + arow) * AS + k0 + kcol, (char*)As + tid * 16);
    gload_lds16(Ap + (size_t)(row0 + 64 + arow) * AS + k0 + kcol, (char*)As + 4096 + tid * 16);
    gload_lds16(Wp + (size_t)(n0 + arow) * K + k0 + kcol, (char*)Bs + tid * 16);
    if constexpr (BN == 128)
      gload_lds16(Wp + (size_t)(n0 + 64 + arow) * K + k0 + kcol, (char*)Bs + 4096 + tid * 16);
    __syncthreads();
    bf16x8 a[FRAG_M], b[FRAG_N];
    #pragma unroll
    for (int i = 0; i < FRAG_M; ++i) {
      a[i] = *reinterpret_cast<const bf16x8*>(&As[(wr * (128 / WM) + i * 16 + lr) * 32 + lk]);
      if (RELU_A) a[i] = relu_bf8(a[i]);
    }
    #pragma unroll
    for (int j = 0; j < FRAG_N; ++j)
      b[j] = *reinterpret_cast<const bf16x8*>(&Bs[(wc * (BN / WN) + j * 16 + lr) * 32 + lk]);
    #pragma unroll
    for (int i = 0; i < FRAG_M; ++i)
      #pragma unroll
      for (int j = 0; j < FRAG_N; ++j)
        acc[i][j] = __builtin_amdgcn_mfma_f32_16x16x32_bf16(a[i], b[j], acc[i][j], 0, 0, 0);
    __syncthreads();
  }
  #pragma unroll
  for (int j = 0; j < FRAG_N; ++j) {
    const int col = n0 + wc * (BN / WN) + j * 16 + lr;
    if (col >= NP) continue;
    const bool real = col < Nreal;
    const float bv = real ? bp[col] : 0.f;
    float s = 0.f, q = 0.f;
    #pragma unroll
    for (int i = 0; i < FRAG_M; ++i) {
      #pragma unroll
      for (int r = 0; r < 4; ++r) {
        const int row = row0 + wr * (128 / WM) + i * 16 + lrow + r;
        float v = acc[i][j][r] + bv;
        if (EPI == EPI_RELU) v = fmaxf(v, 0.f);
        if (EPI == EPI_TANH) v = tanhf(v);
        if (EPI == EPI_COND) { v *= bf2f(emb[(size_t)row * 256 + col]); v = fmaxf(v, 0.f); }
        if (!real) v = 0.f;
        const unsigned short hv = f2bf(v);
        Cp[(size_t)row * CS + col] = hv;
        if (EPI == EPI_STATS) {
          const float vr = bf2f(hv);
          s += vr;
          q = fmaf(vr, vr, q);
        }
      }
    }
    if (EPI == EPI_STATS) {
      s += __shfl_xor(s, 16); s += __shfl_xor(s, 32);
      q += __shfl_xor(q, 16); q += __shfl_xor(q, 32);
      if (lane < 16) {
        atomicAdd(&sum[col], s);
        atomicAdd(&sumsq[col], q);
      }
    }
  }
}

// ---------------------------------------------------------------------------
// Gumbel softmax over groups of 8 (bf16 logits).
__global__ void gumbel8(const unsigned short* __restrict__ logit, const float* __restrict__ u,
                        float* __restrict__ out, int u_off, int u_stride)
{
  const int idx = blockIdx.x * 256 + threadIdx.x;
  const int b = idx >> 3, m = idx & 7;
  const unsigned short* lp = logit + (size_t)b * 64 + m * 8;
  const float* up = u + (size_t)b * u_stride + u_off + m * 8;
  float v[8];
  #pragma unroll
  for (int j = 0; j < 8; ++j) {
    const float uu = fminf(fmaxf(up[j], 1e-10f), 0.9999999f);
    v[j] = bf2f(lp[j]) - logf(-logf(uu));
  }
  float mx = v[0];
  #pragma unroll
  for (int j = 1; j < 8; ++j) mx = fmaxf(mx, v[j]);
  float s = 0.f;
  #pragma unroll
  for (int j = 0; j < 8; ++j) { v[j] = expf(v[j] - mx); s += v[j]; }
  const float inv = 1.f / s;
  float* op = out + (size_t)b * 64 + m * 8;
  #pragma unroll
  for (int j = 0; j < 8; ++j) op[j] = v[j] * inv;
}

__global__ void final_select_k(const unsigned short* __restrict__ si, const float* __restrict__ Wf,
                               const float* __restrict__ bias, const float* __restrict__ u,
                               float* __restrict__ fs)
{
  const int idx = blockIdx.x * 256 + threadIdx.x;
  const int b = idx >> 3, j = idx & 7;
  const unsigned short* sp = si + (size_t)b * 256;
  float acc = bias[j];
  for (int k = 0; k < 256; ++k) acc = fmaf(bf2f(sp[k]), Wf[k * 8 + j], acc);
  const float uu = fminf(fmaxf(u[(size_t)b * 8 + j], 1e-10f), 0.9999999f);
  float v = acc - logf(-logf(uu));
  float mx = v;
  #pragma unroll
  for (int d = 1; d < 8; d <<= 1) mx = fmaxf(mx, __shfl_xor(mx, d, 8));
  float e = expf(v - mx);
  float s = e;
  #pragma unroll
  for (int d = 1; d < 8; d <<= 1) s += __shfl_xor(s, d, 8);
  fs[(size_t)b * 8 + j] = e / s;
}

// ---------------------------------------------------------------------------
// Fold mod weights with inline bn1 finalize. grid (8, 8, 9).
__global__ __launch_bounds__(256) void fold_modw_all(
    const float* __restrict__ W, const float* __restrict__ g1,
    const float* __restrict__ b1, const float* __restrict__ modb,
    const float* __restrict__ sum1, const float* __restrict__ sumsq1,
    unsigned short* __restrict__ Wt, float* __restrict__ bias2)
{
  const float invB = 1.f / 16384.f;
  if (blockIdx.z == 8) {
    if (blockIdx.y != 0) return;
    const int m = blockIdx.x, h = threadIdx.x;
    float acc = modb[m * 256 + h];
    for (int d = 0; d < 256; ++d) {
      const float mean = sum1[d] * invB;
      const float var = sumsq1[d] * invB - mean * mean;
      const float r = rsqrtf(var + 1e-5f);
      const float c = b1[m * 256 + d] - mean * r * g1[m * 256 + d];
      acc = fmaf(c, W[((size_t)m * 256 + d) * 256 + h], acc);
    }
    bias2[m * 256 + h] = acc;
    return;
  }
  __shared__ float t[32][33];
  const int m = blockIdx.z, d0 = blockIdx.y * 32, h0 = blockIdx.x * 32;
  const int tx = threadIdx.x & 31, ty = threadIdx.x >> 5;
  #pragma unroll
  for (int p = 0; p < 4; ++p) {
    const int d = d0 + ty + p * 8;
    const float mean = sum1[d] * invB;
    const float var = sumsq1[d] * invB - mean * mean;
    const float r = rsqrtf(var + 1e-5f);
    t[ty + p * 8][tx] = W[((size_t)m * 256 + d) * 256 + h0 + tx] * r * g1[m * 256 + d];
  }
  __syncthreads();
  #pragma unroll
  for (int p = 0; p < 4; ++p) {
    const int h = h0 + ty + p * 8;
    Wt[((size_t)m * 256 + h) * 256 + d0 + tx] = f2bf(t[tx][ty + p * 8]);
  }
}

// Reshuffle modWt [m][h][d] -> Wt2 MFMA-fragment layout (verified in R6).
__global__ __launch_bounds__(256) void reshuffle_w(
    const unsigned short* __restrict__ modWt, unsigned short* __restrict__ Wt2)
{
  const int idx = blockIdx.x * 256 + threadIdx.x;   // 16384
  const int ks = idx & 7, col = (idx >> 3) & 255, m = idx >> 11;
  const unsigned short* src = modWt + ((size_t)m * 256 + col) * 256 + ks * 32;
  unsigned short* dst = Wt2 + (size_t)((m * 16 + (col >> 4)) * 8 + ks) * 512 + (col & 15) * 8;
  #pragma unroll
  for (int h2 = 0; h2 < 4; ++h2)
    *reinterpret_cast<uint4*>(dst + h2 * 128) = *reinterpret_cast<const uint4*>(src + h2 * 8);
}

// bn2 finalize with bias2 folded into shift.
__global__ void finalize_bn2(const float* __restrict__ sum, const float* __restrict__ sumsq,
                             const float* __restrict__ bias2, const float* __restrict__ g,
                             const float* __restrict__ b, float* __restrict__ scale,
                             float* __restrict__ shift)
{
  const int i = blockIdx.x * 256 + threadIdx.x;   // 2048
  const float invB = 1.f / 16384.f;
  const float m = sum[i] * invB;
  const float v = sumsq[i] * invB - m * m;
  const float sc = rsqrtf(v + 1e-5f) * g[i];
  scale[i] = sc;
  shift[i] = (bias2[i] - m) * sc + b[i];
}

// ---------------------------------------------------------------------------
// Megakernel, spill-proof: per-slice acc[2][4] (32 VGPR), A-tile live in LDS.
// STATS: bn2 column stats of H+bias2. FULL: H -> bn2 -> cascade -> last GEMM.
// 512 threads (wave wv = module), 512 blocks, dynamic LDS.
template<bool STATS>
__global__ __launch_bounds__(512) void mega_mod(
    const unsigned short* __restrict__ Abf,   // out_bf [16384][256]
    const unsigned short* __restrict__ Wt2,   // fragment layout, 1 MB
    const float* __restrict__ bias2,
    float* __restrict__ sum, float* __restrict__ sumsq,
    const float* __restrict__ scale2, const float* __restrict__ shift2,
    const float* __restrict__ gs0, const float* __restrict__ gs1,
    const float* __restrict__ gs2, const float* __restrict__ fs,
    const unsigned short* __restrict__ lastWt, const float* __restrict__ lastb,
    float* __restrict__ out)
{
  extern __shared__ __align__(16) unsigned char LDSBUF[];
  unsigned short* A_lds = (unsigned short*)LDSBUF;               // 16384 B, live
  unsigned short* Hs    = (unsigned short*)(LDSBUF + 16384);     // 34560 B (FULL)
  unsigned short* ovl   = (unsigned short*)(LDSBUF + 16384 + 34560); // 16896 B

  const int tid = threadIdx.x;
  const int wv = tid >> 6;           // wave == module m
  const int lane = tid & 63;
  const int lr = lane & 15, hi = lane >> 4;
  const int b0 = blockIdx.x * 32;

  // Stage A tile [32][256] bf16, chunk ^= (row&7) swizzle via pre-swz source.
  {
    const int row0 = tid >> 5;           // 0..15
    const int cg = (tid & 31) ^ (row0 & 7);
    gload_lds16(Abf + (size_t)(b0 + row0) * 256 + cg * 8, (char*)A_lds + tid * 16);
    gload_lds16(Abf + (size_t)(b0 + 16 + row0) * 256 + cg * 8,
                (char*)LDSBUF + 8192 + tid * 16);
  }
  __syncthreads();

  #pragma unroll
  for (int t = 0; t < 4; ++t) {
    // --- MFMA for this slice: cols [t*64, t*64+64) of module wv ---
    f32x4 acc[2][4] = {};
    #pragma unroll
    for (int ks = 0; ks < 8; ++ks) {
      const int ch0 = (ks * 4 + hi) ^ (lr & 7);
      const bf16x8 a0 = *reinterpret_cast<const bf16x8*>(&A_lds[lr * 256 + ch0 * 8]);
      const int row1 = 16 + lr;
      const int ch1 = (ks * 4 + hi) ^ (row1 & 7);
      const bf16x8 a1 = *reinterpret_cast<const bf16x8*>(&A_lds[row1 * 256 + ch1 * 8]);
      #pragma unroll
      for (int jj = 0; jj < 4; ++jj) {
        const int j = t * 4 + jj;
        const bf16x8 b = *reinterpret_cast<const bf16x8*>(
            Wt2 + (size_t)((wv * 16 + j) * 8 + ks) * 512 + lane * 8);
        acc[0][jj] = __builtin_amdgcn_mfma_f32_16x16x32_bf16(a0, b, acc[0][jj], 0, 0, 0);
        acc[1][jj] = __builtin_amdgcn_mfma_f32_16x16x32_bf16(a1, b, acc[1][jj], 0, 0, 0);
      }
    }

    if (STATS) {
      #pragma unroll
      for (int jj = 0; jj < 4; ++jj) {
        const int gc = wv * 256 + (t * 4 + jj) * 16 + lr;
        const float bv = bias2[gc];
        float s = 0.f, q = 0.f;
        #pragma unroll
        for (int i = 0; i < 2; ++i)
          #pragma unroll
          for (int r = 0; r < 4; ++r) {
            const float v = acc[i][jj][r] + bv;
            s += v;
            q = fmaf(v, v, q);
          }
        s += __shfl_xor(s, 16); s += __shfl_xor(s, 32);
        q += __shfl_xor(q, 16); q += __shfl_xor(q, 32);
        if (lane < 16) {
          atomicAdd(&sum[gc], s);
          atomicAdd(&sumsq[gc], q);
        }
      }
    } else {
      // --- write slice to Hs, then per-sample cascade on these 64 cols ---
      __syncthreads();   // t>0: prior slice's Hs reads done (harmless at t=0)
      #pragma unroll
      for (int jj = 0; jj < 4; ++jj)
        #pragma unroll
        for (int i = 0; i < 2; ++i)
          #pragma unroll
          for (int r = 0; r < 4; ++r) {
            const int s = i * 16 + hi * 4 + r;
            Hs[s * 540 + wv * 66 + jj * 16 + lr] = f2bf(acc[i][jj][r]);
          }
      __syncthreads();
      const int col = lane;   // 0..63
      float sc_r[8], sh_r[8];
      #pragma unroll
      for (int m = 0; m < 8; ++m) {
        const int gc = m * 256 + t * 64 + col;
        sc_r[m] = scale2[gc];
        sh_r[m] = shift2[gc];
      }
      #pragma unroll
      for (int p = 0; p < 4; ++p) {
        const int s = wv * 4 + p;
        const int bg = b0 + s;
        float prev[8];
        #pragma unroll
        for (int m = 0; m < 8; ++m)
          prev[m] = bf2f(Hs[s * 540 + m * 66 + col]) * sc_r[m] + sh_r[m];
        const float* sel_l[3] = { gs2 + (size_t)bg * 64, gs1 + (size_t)bg * 64,
                                  gs0 + (size_t)bg * 64 };
        #pragma unroll
        for (int l = 0; l < 3; ++l) {
          const float* sp = sel_l[l];
          float nw[8];
          #pragma unroll
          for (int mm = 0; mm < 8; ++mm) {
            float a = 0.f;
            #pragma unroll
            for (int k = 0; k < 8; ++k) a = fmaf(sp[mm * 8 + k], prev[k], a);
            nw[mm] = fmaxf(a, 0.f);
          }
          #pragma unroll
          for (int mm = 0; mm < 8; ++mm) prev[mm] = nw[mm];
        }
        const float* fp = fs + (size_t)bg * 8;
        float o = 0.f;
        #pragma unroll
        for (int m = 0; m < 8; ++m) o = fmaf(fp[m], prev[m], o);
        ovl[s * 264 + t * 64 + col] = f2bf(o);
      }
    }
  }

  if (!STATS) {
    __syncthreads();
    // Fused last GEMM: waves 0,1; 16 samples each; cols 0..31 (18 real).
    if (wv < 2) {
      f32x4 acc2[2] = {};
      #pragma unroll
      for (int ks = 0; ks < 8; ++ks) {
        const bf16x8 a = *reinterpret_cast<const bf16x8*>(
            &ovl[(wv * 16 + lr) * 264 + ks * 32 + hi * 8]);
        #pragma unroll
        for (int j = 0; j < 2; ++j) {
          const bf16x8 b = *reinterpret_cast<const bf16x8*>(
              lastWt + (size_t)(j * 16 + lr) * 256 + ks * 32 + hi * 8);
          acc2[j] = __builtin_amdgcn_mfma_f32_16x16x32_bf16(a, b, acc2[j], 0, 0, 0);
        }
      }
      #pragma unroll
      for (int j = 0; j < 2; ++j) {
        const int colo = j * 16 + lr;
        if (colo < 18) {
          const float bv = lastb[colo];
          #pragma unroll
          for (int r = 0; r < 4; ++r) {
            const int srow = wv * 16 + hi * 4 + r;
            out[(size_t)(b0 + srow) * 18 + colo] = acc2[j][r] + bv;
          }
        }
      }
    }
  }
}

extern "C" void kernel_launch(void* const* d_in, const int* in_sizes, int n_in,
                              void* d_out, int out_size, void* d_ws, size_t ws_size,
                              hipStream_t stream)
{
  (void)in_sizes; (void)n_in; (void)out_size; (void)ws_size;
  const float* x       = (const float*)d_in[0];
  const float* embi    = (const float*)d_in[1];
  const float* u_sel   = (const float*)d_in[2];
  const float* u_fin   = (const float*)d_in[3];
  const float* base_W0 = (const float*)d_in[4];
  const float* base_b0 = (const float*)d_in[5];
  const float* base_W1 = (const float*)d_in[6];
  const float* base_b1 = (const float*)d_in[7];
  const float* em_W0   = (const float*)d_in[8];
  const float* em_b0   = (const float*)d_in[9];
  const float* gat_W0  = (const float*)d_in[10];
  const float* gat_b0  = (const float*)d_in[11];
  const float* gat_W1  = (const float*)d_in[12];
  const float* gat_b1  = (const float*)d_in[13];
  const float* sel_W   = (const float*)d_in[14];
  const float* sel_b   = (const float*)d_in[15];
  const float* selF_W  = (const float*)d_in[16];
  const float* selF_b  = (const float*)d_in[17];
  const float* cond_W  = (const float*)d_in[18];
  const float* cond_b  = (const float*)d_in[19];
  const float* mod_W   = (const float*)d_in[20];
  const float* mod_b   = (const float*)d_in[21];
  const float* last_W  = (const float*)d_in[22];
  const float* last_b  = (const float*)d_in[23];
  const float* bn1_g   = (const float*)d_in[24];
  const float* bn1_b   = (const float*)d_in[25];
  const float* bn2_g   = (const float*)d_in[26];
  const float* bn2_b   = (const float*)d_in[27];

  // --- workspace layout (byte offsets) ---
  char* WSB = (char*)d_ws;
  unsigned short* Wt2      = (unsigned short*)(WSB + 0);          // 1 MB frag layout
  unsigned short* h1e      = (unsigned short*)(WSB + 33554432);   // 16384x416 (em chain)
  unsigned short* h1       = (unsigned short*)(WSB + 67108864);   // 16384x416 (base)
  unsigned short* x_bf     = (unsigned short*)(WSB + 80740352);   // 16384x128
  unsigned short* e_bf     = (unsigned short*)(WSB + 84934656);   // 16384x128
  unsigned short* emb_bf   = (unsigned short*)(WSB + 89128960);   // 16384x256
  unsigned short* si_bf    = (unsigned short*)(WSB + 97517568);   // 16384x256
  unsigned short* out_bf   = (unsigned short*)(WSB + 105906176);  // 16384x256
  unsigned short* logit_bf = (unsigned short*)(WSB + 114294784);  // 16384x64
  float* gs0   = (float*)(WSB + 116391936);  // 16384x64
  float* gs1   = (float*)(WSB + 120586240);
  float* gs2   = (float*)(WSB + 124780544);
  float* bufFs = (float*)(WSB + 128974848);  // 16384x8
  unsigned short* W0t   = (unsigned short*)(WSB + 129499136);  // 512x128
  unsigned short* emW0t = (unsigned short*)(WSB + 129630208);  // 512x128
  unsigned short* W1t   = (unsigned short*)(WSB + 129761280);  // 256x416
  unsigned short* g0t   = (unsigned short*)(WSB + 129974272);  // 256x416
  unsigned short* g1t   = (unsigned short*)(WSB + 130187264);  // 256x256
  unsigned short* selWt = (unsigned short*)(WSB + 130318336);  // 3x64x256
  unsigned short* condWt= (unsigned short*)(WSB + 130416640);  // 3x256x64
  unsigned short* modWt = (unsigned short*)(WSB + 130514944);  // 8x256x256
  float* bias2  = (float*)(WSB + 131563520);  // 2048
  float* stats  = (float*)(WSB + 131571712);  // 4608 floats
  unsigned short* lastWt = (unsigned short*)(WSB + 131590144); // 64x256 bf16
  float* scale2 = (float*)(WSB + 131622912);  // 2048
  float* shift2 = (float*)(WSB + 131631104);  // 2048
  float* sum1   = stats;        float* sumsq1 = stats + 256;
  float* sum2   = stats + 512;  float* sumsq2 = stats + 2560;

  const dim3 blk(256);
  // fused prep (converts + weight transposes + stats zero)
  prep_all<<<dim3(4601), blk, 0, stream>>>(
      x, embi, base_W0, em_W0, base_W1, gat_W0, gat_W1, sel_W, cond_W, last_W,
      x_bf, e_bf, W0t, emW0t, W1t, g0t, g1t, selWt, condWt, lastWt, stats);

  // batched W0 GEMMs: z=0 base (x -> h1), z=1 em (e -> h1e), both RELU
  gemm_bf16<128, 2, 2, EPI_RELU, false><<<dim3(4, 128, 2), blk, 0, stream>>>(
      x_bf, 128, W0t, base_b0, h1, 416, 400, 416, 128, nullptr, nullptr, nullptr,
      e_bf, emW0t, em_b0, h1e);
  // base W1 -> out (fused bn1 stats)
  gemm_bf16<128, 2, 2, EPI_STATS, false><<<dim3(2, 128), blk, 0, stream>>>(
      h1, 416, W1t, base_b1, out_bf, 256, 256, 256, 416, nullptr, sum1, sumsq1,
      nullptr, nullptr, nullptr, nullptr);
  // gating
  gemm_bf16<128, 2, 2, EPI_RELU, false><<<dim3(2, 128), blk, 0, stream>>>(
      h1e, 416, g0t, gat_b0, si_bf, 256, 256, 256, 416, nullptr, nullptr, nullptr,
      nullptr, nullptr, nullptr, nullptr);
  gemm_bf16<128, 2, 2, EPI_NONE, false><<<dim3(2, 128), blk, 0, stream>>>(
      si_bf, 256, g1t, gat_b1, emb_bf, 256, 256, 256, 256, nullptr, nullptr, nullptr,
      nullptr, nullptr, nullptr, nullptr);
  // select loop
  float* gs[3] = {gs0, gs1, gs2};
  for (int i = 0; i < 3; ++i) {
    if (i == 0)
      gemm_bf16<64, 4, 1, EPI_TANH, true><<<dim3(1, 128), blk, 0, stream>>>(
          emb_bf, 256, selWt, sel_b, logit_bf, 64, 64, 64, 256, nullptr, nullptr, nullptr,
          nullptr, nullptr, nullptr, nullptr);
    else
      gemm_bf16<64, 4, 1, EPI_TANH, false><<<dim3(1, 128), blk, 0, stream>>>(
          si_bf, 256, selWt + i * 16384, sel_b + i * 64, logit_bf, 64, 64, 64, 256,
          nullptr, nullptr, nullptr, nullptr, nullptr, nullptr, nullptr);
    gumbel8<<<dim3(512), blk, 0, stream>>>(logit_bf, u_sel, gs[i], i * 64, 192);
    gemm_bf16<128, 2, 2, EPI_COND, false><<<dim3(2, 128), blk, 0, stream>>>(
        logit_bf, 64, condWt + i * 16384, cond_b + i * 256, si_bf, 256, 256, 256, 64,
        emb_bf, nullptr, nullptr, nullptr, nullptr, nullptr, nullptr);
  }
  final_select_k<<<dim3(512), blk, 0, stream>>>(si_bf, selF_W, selF_b, u_fin, bufFs);
  // bn1 finalize + mod weight fold + bias2 (one kernel), then fragment reshuffle
  fold_modw_all<<<dim3(8, 8, 9), blk, 0, stream>>>(
      mod_W, bn1_g, bn1_b, mod_b, sum1, sumsq1, modWt, bias2);
  reshuffle_w<<<dim3(64), blk, 0, stream>>>(modWt, Wt2);
  // pass A: bn2 stats (no H store); LDS = A tile only
  mega_mod<true><<<dim3(512), dim3(512), 16384, stream>>>(
      out_bf, Wt2, bias2, sum2, sumsq2, nullptr, nullptr,
      nullptr, nullptr, nullptr, nullptr, nullptr, nullptr, nullptr);
  finalize_bn2<<<dim3(8), blk, 0, stream>>>(sum2, sumsq2, bias2, bn2_g, bn2_b, scale2, shift2);
  // pass B: fused einsum + bn2 + cascade + last GEMM; LDS = A + Hs + ovl
  mega_mod<false><<<dim3(512), dim3(512), 67840, stream>>>(
      out_bf, Wt2, nullptr, nullptr, nullptr, scale2, shift2,
      gs0, gs1, gs2, bufFs, lastWt, last_b, (float*)d_out);
}

// Round 8
// 296.068 us; speedup vs baseline: 5.1318x; 5.1318x over previous
//
#include <hip/hip_runtime.h>
#include <math.h>

// ---------------------------------------------------------------------------
// ModularSelectCascadeNet forward. B=16384, M=8, NUM_LAYERS=4.
// R8: revert to R5 structure; mod-GEMM rebuilt: B direct-from-L2 in MFMA
//     fragment layout (no Bs LDS), A staged with XOR swizzle, C staged in LDS
//     for coalesced 16B stores. Megakernel abandoned (R6/R7 spill storms).
// ---------------------------------------------------------------------------

#define EPI_NONE  0
#define EPI_RELU  1
#define EPI_TANH  2
#define EPI_COND  3
#define EPI_STATS 4

typedef short bf16x8 __attribute__((ext_vector_type(8)));
typedef float f32x4 __attribute__((ext_vector_type(4)));

__device__ __forceinline__ unsigned short f2bf(float f) {
  unsigned u = __float_as_uint(f);
  u += 0x7fffu + ((u >> 16) & 1u);
  return (unsigned short)(u >> 16);
}
__device__ __forceinline__ float bf2f(unsigned short h) {
  return __uint_as_float(((unsigned)h) << 16);
}
__device__ __forceinline__ void gload_lds16(const void* g, void* l) {
  __builtin_amdgcn_global_load_lds(
      (const __attribute__((address_space(1))) unsigned int*)g,
      (__attribute__((address_space(3))) unsigned int*)l, 16, 0, 0);
}
__device__ __forceinline__ bf16x8 relu_bf8(bf16x8 v) {
  bf16x8 r;
  #pragma unroll
  for (int j = 0; j < 8; ++j) r[j] = v[j] > 0 ? v[j] : (short)0;
  return r;
}

// ---------------------------------------------------------------------------
// Fused prep (unchanged).
__global__ __launch_bounds__(256) void prep_all(
    const float* __restrict__ x, const float* __restrict__ embi,
    const float* __restrict__ base_W0, const float* __restrict__ em_W0,
    const float* __restrict__ base_W1, const float* __restrict__ gat_W0,
    const float* __restrict__ gat_W1, const float* __restrict__ sel_W,
    const float* __restrict__ cond_W, const float* __restrict__ last_W,
    unsigned short* __restrict__ x_bf, unsigned short* __restrict__ e_bf,
    unsigned short* __restrict__ W0t, unsigned short* __restrict__ emW0t,
    unsigned short* __restrict__ W1t, unsigned short* __restrict__ g0t,
    unsigned short* __restrict__ g1t, unsigned short* __restrict__ selWt,
    unsigned short* __restrict__ condWt, unsigned short* __restrict__ lastWt,
    float* __restrict__ stats)
{
  __shared__ float t[32][33];
  int bid = blockIdx.x;
  const int tid = threadIdx.x;

  if (bid < 4096) {
    const float* src = bid < 2048 ? x : embi;
    unsigned short* dst = bid < 2048 ? x_bf : e_bf;
    const int i = ((bid & 2047) * 256 + tid) * 4;
    const float4 v = *reinterpret_cast<const float4*>(&src[i]);
    ushort4 o;
    o.x = f2bf(v.x); o.y = f2bf(v.y); o.z = f2bf(v.z); o.w = f2bf(v.w);
    *reinterpret_cast<ushort4*>(&dst[i]) = o;
    return;
  }
  bid -= 4096;

  const int tx = tid & 31, ty = tid >> 5;

  if (bid < 496) {
    const float* src; unsigned short* dst; int K, N, KP, gx, local;
    if (bid < 64)       { src = base_W0; dst = W0t;   K = 128; N = 400; KP = 128; gx = 4;  local = bid; }
    else if (bid < 128) { src = em_W0;   dst = emW0t; K = 128; N = 400; KP = 128; gx = 4;  local = bid - 64; }
    else if (bid < 232) { src = base_W1; dst = W1t;   K = 400; N = 256; KP = 416; gx = 13; local = bid - 128; }
    else if (bid < 336) { src = gat_W0;  dst = g0t;   K = 400; N = 256; KP = 416; gx = 13; local = bid - 232; }
    else if (bid < 400) { src = gat_W1;  dst = g1t;   K = 256; N = 256; KP = 256; gx = 8;  local = bid - 336; }
    else if (bid < 448) {
      const int i = (bid - 400) / 16;
      src = sel_W + i * 16384; dst = selWt + i * 16384;
      K = 256; N = 64; KP = 256; gx = 8; local = (bid - 400) % 16;
    } else {
      const int i = (bid - 448) / 16;
      src = cond_W + i * 16384; dst = condWt + i * 16384;
      K = 64; N = 256; KP = 64; gx = 2; local = (bid - 448) % 16;
    }
    const int k0 = (local % gx) * 32, n0 = (local / gx) * 32;
    #pragma unroll
    for (int p = 0; p < 4; ++p) {
      const int k = k0 + ty + p * 8;
      t[ty + p * 8][tx] = (k < K && n0 + tx < N) ? src[(size_t)k * N + n0 + tx] : 0.f;
    }
    __syncthreads();
    #pragma unroll
    for (int p = 0; p < 4; ++p) {
      const int n = n0 + ty + p * 8;
      dst[(size_t)n * KP + k0 + tx] = f2bf(t[tx][ty + p * 8]);
    }
    return;
  }
  bid -= 496;

  if (bid < 8) {
    const int k0 = bid * 32;
    #pragma unroll
    for (int p = 0; p < 4; ++p)
      t[ty + p * 8][tx] = (tx < 18) ? last_W[(size_t)(k0 + ty + p * 8) * 18 + tx] : 0.f;
    __syncthreads();
    #pragma unroll
    for (int p = 0; p < 4; ++p) {
      const int n = ty + p * 8;
      lastWt[(size_t)n * 256 + k0 + tx] = f2bf(t[tx][n]);
      lastWt[(size_t)(n + 32) * 256 + k0 + tx] = 0;
    }
    return;
  }

  for (int i = tid; i < 4608; i += 256) stats[i] = 0.f;
}

// ---------------------------------------------------------------------------
// Generic bf16 MFMA GEMM for the front chain. BM=128, BK=32.
// Optional grid.z batching: when blockIdx.z==1, use (A2, W2, bias_b, C2).
template<int BN, int WM, int WN, int EPI, bool RELU_A>
__global__ __launch_bounds__(256) void gemm_bf16(
    const unsigned short* __restrict__ A, int AS,
    const unsigned short* __restrict__ Wt, const float* __restrict__ bias,
    unsigned short* __restrict__ C, int CS, int Nreal, int NP, int K,
    const unsigned short* __restrict__ emb,
    float* __restrict__ sum, float* __restrict__ sumsq,
    const unsigned short* A2, const unsigned short* W2,
    const float* bias_b, unsigned short* C2)
{
  constexpr int FRAG_M = 128 / WM / 16;
  constexpr int FRAG_N = BN / WN / 16;
  __shared__ unsigned short As[128 * 32];
  __shared__ unsigned short Bs[BN * 32];
  const unsigned short* Ap = (blockIdx.z == 0) ? A : A2;
  const unsigned short* Wp = (blockIdx.z == 0) ? Wt : W2;
  const float* bp = (blockIdx.z == 0) ? bias : bias_b;
  unsigned short* Cp = (blockIdx.z == 0) ? C : C2;
  const int row0 = blockIdx.y * 128;
  const int n0 = blockIdx.x * BN;
  const int tid = threadIdx.x;
  const int wid = tid >> 6, lane = tid & 63;
  const int wr = wid / WN, wc = wid % WN;
  const int arow = tid >> 2;
  const int kcol = (tid & 3) * 8;
  const int lr = lane & 15, lk = (lane >> 4) * 8;
  const int lrow = (lane >> 4) * 4;

  f32x4 acc[FRAG_M][FRAG_N] = {};
  for (int k0 = 0; k0 < K; k0 += 32) {
    gload_lds16(Ap + (size_t)(row0 + arow) * AS + k0 + kcol, (char*)As + tid * 16);
    gload_lds16(Ap + (size_t)(row0 + 64 + arow) * AS + k0 + kcol, (char*)As + 4096 + tid * 16);
    gload_lds16(Wp + (size_t)(n0 + arow) * K + k0 + kcol, (char*)Bs + tid * 16);
    if constexpr (BN == 128)
      gload_lds16(Wp + (size_t)(n0 + 64 + arow) * K + k0 + kcol, (char*)Bs + 4096 + tid * 16);
    __syncthreads();
    bf16x8 a[FRAG_M], b[FRAG_N];
    #pragma unroll
    for (int i = 0; i < FRAG_M; ++i) {
      a[i] = *reinterpret_cast<const bf16x8*>(&As[(wr * (128 / WM) + i * 16 + lr) * 32 + lk]);
      if (RELU_A) a[i] = relu_bf8(a[i]);
    }
    #pragma unroll
    for (int j = 0; j < FRAG_N; ++j)
      b[j] = *reinterpret_cast<const bf16x8*>(&Bs[(wc * (BN / WN) + j * 16 + lr) * 32 + lk]);
    #pragma unroll
    for (int i = 0; i < FRAG_M; ++i)
      #pragma unroll
      for (int j = 0; j < FRAG_N; ++j)
        acc[i][j] = __builtin_amdgcn_mfma_f32_16x16x32_bf16(a[i], b[j], acc[i][j], 0, 0, 0);
    __syncthreads();
  }
  #pragma unroll
  for (int j = 0; j < FRAG_N; ++j) {
    const int col = n0 + wc * (BN / WN) + j * 16 + lr;
    if (col >= NP) continue;
    const bool real = col < Nreal;
    const float bv = real ? bp[col] : 0.f;
    float s = 0.f, q = 0.f;
    #pragma unroll
    for (int i = 0; i < FRAG_M; ++i) {
      #pragma unroll
      for (int r = 0; r < 4; ++r) {
        const int row = row0 + wr * (128 / WM) + i * 16 + lrow + r;
        float v = acc[i][j][r] + bv;
        if (EPI == EPI_RELU) v = fmaxf(v, 0.f);
        if (EPI == EPI_TANH) v = tanhf(v);
        if (EPI == EPI_COND) { v *= bf2f(emb[(size_t)row * 256 + col]); v = fmaxf(v, 0.f); }
        if (!real) v = 0.f;
        const unsigned short hv = f2bf(v);
        Cp[(size_t)row * CS + col] = hv;
        if (EPI == EPI_STATS) {
          const float vr = bf2f(hv);
          s += vr;
          q = fmaf(vr, vr, q);
        }
      }
    }
    if (EPI == EPI_STATS) {
      s += __shfl_xor(s, 16); s += __shfl_xor(s, 32);
      q += __shfl_xor(q, 16); q += __shfl_xor(q, 32);
      if (lane < 16) {
        atomicAdd(&sum[col], s);
        atomicAdd(&sumsq[col], q);
      }
    }
  }
}

// ---------------------------------------------------------------------------
// Mod-einsum GEMM, fragment-B version. Tile 128 rows x 128 cols, 4 waves 2x2.
// grid (16, 128): blockIdx.x -> (m = x>>1, half = x&1). B fragments streamed
// from L2 (Wt2, MFMA-fragment layout) straight to VGPRs. A staged via
// global_load_lds with chunk^=(row&3) XOR swizzle (pre-swizzled source).
// Epilogue: bn2 stats (shfl+atomics) + C staged in padded LDS -> 16B stores.
__global__ __launch_bounds__(256) void gemm_mod_frag(
    const unsigned short* __restrict__ Abf,   // out_bf [16384][256]
    const unsigned short* __restrict__ Wt2,   // fragment layout, 1 MB
    const float* __restrict__ bias2,
    unsigned short* __restrict__ H,           // [16384][2048]
    float* __restrict__ sum, float* __restrict__ sumsq)
{
  __shared__ unsigned short As[128 * 32];     // 8 KB
  __shared__ unsigned short Cs[128 * 136];    // 34 KB, 272B row stride (16B-aligned)
  const int tid = threadIdx.x;
  const int wid = tid >> 6, lane = tid & 63;
  const int wr = wid >> 1, wc = wid & 1;
  const int lr = lane & 15, hi = lane >> 4;
  const int m = blockIdx.x >> 1, half = blockIdx.x & 1;
  const int row0 = blockIdx.y * 128;
  const int arow = tid >> 2;
  const int cg = (tid & 3) ^ (arow & 3);      // swizzled source chunk

  f32x4 acc[4][4] = {};
  for (int ks = 0; ks < 8; ++ks) {
    const int k0 = ks * 32;
    __syncthreads();   // prior iteration's As reads complete
    gload_lds16(Abf + (size_t)(row0 + arow) * 256 + k0 + cg * 8, (char*)As + tid * 16);
    gload_lds16(Abf + (size_t)(row0 + 64 + arow) * 256 + k0 + cg * 8,
                (char*)As + 4096 + tid * 16);
    __syncthreads();
    bf16x8 a[4], b[4];
    #pragma unroll
    for (int i = 0; i < 4; ++i) {
      const int row = wr * 64 + i * 16 + lr;
      a[i] = *reinterpret_cast<const bf16x8*>(
          (const char*)As + row * 64 + ((hi ^ (lr & 3)) * 16));
    }
    #pragma unroll
    for (int j = 0; j < 4; ++j) {
      const int J = half * 8 + wc * 4 + j;
      b[j] = *reinterpret_cast<const bf16x8*>(
          Wt2 + (size_t)((m * 16 + J) * 8 + ks) * 512 + lane * 8);
    }
    #pragma unroll
    for (int i = 0; i < 4; ++i)
      #pragma unroll
      for (int j = 0; j < 4; ++j)
        acc[i][j] = __builtin_amdgcn_mfma_f32_16x16x32_bf16(a[i], b[j], acc[i][j], 0, 0, 0);
  }

  // Epilogue: bias + bf16 quantize -> Cs; fused bn2 stats from quantized H.
  __syncthreads();
  #pragma unroll
  for (int j = 0; j < 4; ++j) {
    const int J = half * 8 + wc * 4 + j;
    const int gc = m * 256 + J * 16 + lr;
    const float bv = bias2[gc];
    float s = 0.f, q = 0.f;
    #pragma unroll
    for (int i = 0; i < 4; ++i) {
      #pragma unroll
      for (int r = 0; r < 4; ++r) {
        const unsigned short hv = f2bf(acc[i][j][r] + bv);
        Cs[(wr * 64 + i * 16 + hi * 4 + r) * 136 + wc * 64 + j * 16 + lr] = hv;
        const float vr = bf2f(hv);
        s += vr;
        q = fmaf(vr, vr, q);
      }
    }
    s += __shfl_xor(s, 16); s += __shfl_xor(s, 32);
    q += __shfl_xor(q, 16); q += __shfl_xor(q, 32);
    if (lane < 16) {
      atomicAdd(&sum[gc], s);
      atomicAdd(&sumsq[gc], q);
    }
  }
  __syncthreads();
  // Coalesced H stores: thread (row=tid>>2, q=tid&3) writes 32 contiguous cols.
  const int colbase = m * 256 + half * 128;
  #pragma unroll
  for (int pass = 0; pass < 2; ++pass) {
    const int row = pass * 64 + (tid >> 2);
    const int qc = (tid & 3) * 32;
    #pragma unroll
    for (int v = 0; v < 4; ++v) {
      const uint4 d = *reinterpret_cast<const uint4*>(&Cs[row * 136 + qc + v * 8]);
      *reinterpret_cast<uint4*>(&H[(size_t)(row0 + row) * 2048 + colbase + qc + v * 8]) = d;
    }
  }
}

// ---------------------------------------------------------------------------
// Gumbel softmax over groups of 8 (bf16 logits).
__global__ void gumbel8(const unsigned short* __restrict__ logit, const float* __restrict__ u,
                        float* __restrict__ out, int u_off, int u_stride)
{
  const int idx = blockIdx.x * 256 + threadIdx.x;
  const int b = idx >> 3, m = idx & 7;
  const unsigned short* lp = logit + (size_t)b * 64 + m * 8;
  const float* up = u + (size_t)b * u_stride + u_off + m * 8;
  float v[8];
  #pragma unroll
  for (int j = 0; j < 8; ++j) {
    const float uu = fminf(fmaxf(up[j], 1e-10f), 0.9999999f);
    v[j] = bf2f(lp[j]) - logf(-logf(uu));
  }
  float mx = v[0];
  #pragma unroll
  for (int j = 1; j < 8; ++j) mx = fmaxf(mx, v[j]);
  float s = 0.f;
  #pragma unroll
  for (int j = 0; j < 8; ++j) { v[j] = expf(v[j] - mx); s += v[j]; }
  const float inv = 1.f / s;
  float* op = out + (size_t)b * 64 + m * 8;
  #pragma unroll
  for (int j = 0; j < 8; ++j) op[j] = v[j] * inv;
}

__global__ void final_select_k(const unsigned short* __restrict__ si, const float* __restrict__ Wf,
                               const float* __restrict__ bias, const float* __restrict__ u,
                               float* __restrict__ fs)
{
  const int idx = blockIdx.x * 256 + threadIdx.x;
  const int b = idx >> 3, j = idx & 7;
  const unsigned short* sp = si + (size_t)b * 256;
  float acc = bias[j];
  for (int k = 0; k < 256; ++k) acc = fmaf(bf2f(sp[k]), Wf[k * 8 + j], acc);
  const float uu = fminf(fmaxf(u[(size_t)b * 8 + j], 1e-10f), 0.9999999f);
  float v = acc - logf(-logf(uu));
  float mx = v;
  #pragma unroll
  for (int d = 1; d < 8; d <<= 1) mx = fmaxf(mx, __shfl_xor(mx, d, 8));
  float e = expf(v - mx);
  float s = e;
  #pragma unroll
  for (int d = 1; d < 8; d <<= 1) s += __shfl_xor(s, d, 8);
  fs[(size_t)b * 8 + j] = e / s;
}

// ---------------------------------------------------------------------------
// Fold mod weights with inline bn1 finalize. grid (8, 8, 9).
__global__ __launch_bounds__(256) void fold_modw_all(
    const float* __restrict__ W, const float* __restrict__ g1,
    const float* __restrict__ b1, const float* __restrict__ modb,
    const float* __restrict__ sum1, const float* __restrict__ sumsq1,
    unsigned short* __restrict__ Wt, float* __restrict__ bias2)
{
  const float invB = 1.f / 16384.f;
  if (blockIdx.z == 8) {
    if (blockIdx.y != 0) return;
    const int m = blockIdx.x, h = threadIdx.x;
    float acc = modb[m * 256 + h];
    for (int d = 0; d < 256; ++d) {
      const float mean = sum1[d] * invB;
      const float var = sumsq1[d] * invB - mean * mean;
      const float r = rsqrtf(var + 1e-5f);
      const float c = b1[m * 256 + d] - mean * r * g1[m * 256 + d];
      acc = fmaf(c, W[((size_t)m * 256 + d) * 256 + h], acc);
    }
    bias2[m * 256 + h] = acc;
    return;
  }
  __shared__ float t[32][33];
  const int m = blockIdx.z, d0 = blockIdx.y * 32, h0 = blockIdx.x * 32;
  const int tx = threadIdx.x & 31, ty = threadIdx.x >> 5;
  #pragma unroll
  for (int p = 0; p < 4; ++p) {
    const int d = d0 + ty + p * 8;
    const float mean = sum1[d] * invB;
    const float var = sumsq1[d] * invB - mean * mean;
    const float r = rsqrtf(var + 1e-5f);
    t[ty + p * 8][tx] = W[((size_t)m * 256 + d) * 256 + h0 + tx] * r * g1[m * 256 + d];
  }
  __syncthreads();
  #pragma unroll
  for (int p = 0; p < 4; ++p) {
    const int h = h0 + ty + p * 8;
    Wt[((size_t)m * 256 + h) * 256 + d0 + tx] = f2bf(t[tx][ty + p * 8]);
  }
}

// Reshuffle modWt [m][h][d] -> Wt2 MFMA-fragment layout (verified R6/R7).
__global__ __launch_bounds__(256) void reshuffle_w(
    const unsigned short* __restrict__ modWt, unsigned short* __restrict__ Wt2)
{
  const int idx = blockIdx.x * 256 + threadIdx.x;   // 16384
  const int ks = idx & 7, col = (idx >> 3) & 255, m = idx >> 11;
  const unsigned short* src = modWt + ((size_t)m * 256 + col) * 256 + ks * 32;
  unsigned short* dst = Wt2 + (size_t)((m * 16 + (col >> 4)) * 8 + ks) * 512 + (col & 15) * 8;
  #pragma unroll
  for (int h2 = 0; h2 < 4; ++h2)
    *reinterpret_cast<uint4*>(dst + h2 * 128) = *reinterpret_cast<const uint4*>(src + h2 * 8);
}

// bn2 finalize (H already includes bias2): scale2/shift2.
__global__ void finalize_bn2(const float* __restrict__ sum, const float* __restrict__ sumsq,
                             const float* __restrict__ g, const float* __restrict__ b,
                             float* __restrict__ scale, float* __restrict__ shift)
{
  const int i = blockIdx.x * 256 + threadIdx.x;   // 2048
  const float invB = 1.f / 16384.f;
  const float m = sum[i] * invB;
  const float v = sumsq[i] * invB - m * m;
  const float r = rsqrtf(v + 1e-5f);
  const float sc = r * g[i];
  scale[i] = sc;
  shift[i] = b[i] - m * sc;
}

// ---------------------------------------------------------------------------
// Cascade (R5-proven): bn2 apply + 3 select rounds + final mix -> ovec bf16.
__global__ __launch_bounds__(256) void final_cascade(
    const unsigned short* __restrict__ H, const float* __restrict__ scale2,
    const float* __restrict__ shift2, const float* __restrict__ gs0,
    const float* __restrict__ gs1, const float* __restrict__ gs2,
    const float* __restrict__ fs, unsigned short* __restrict__ ovec)
{
  const int wave = threadIdx.x >> 6, lane = threadIdx.x & 63;
  const int b = __builtin_amdgcn_readfirstlane(blockIdx.x * 4 + wave);
  const int c0 = lane << 2;

  float prev[8][4];
  #pragma unroll
  for (int m = 0; m < 8; ++m) {
    const int gc = m * 256 + c0;
    const ushort4 h = *reinterpret_cast<const ushort4*>(&H[(size_t)b * 2048 + gc]);
    const float4 sc = *reinterpret_cast<const float4*>(&scale2[gc]);
    const float4 sh = *reinterpret_cast<const float4*>(&shift2[gc]);
    prev[m][0] = bf2f(h.x) * sc.x + sh.x;
    prev[m][1] = bf2f(h.y) * sc.y + sh.y;
    prev[m][2] = bf2f(h.z) * sc.z + sh.z;
    prev[m][3] = bf2f(h.w) * sc.w + sh.w;
  }

  const float* sel0 = gs2 + (size_t)b * 64;
  const float* sel1 = gs1 + (size_t)b * 64;
  const float* sel2 = gs0 + (size_t)b * 64;
  #pragma unroll
  for (int l = 0; l < 3; ++l) {
    const float* sp = (l == 0) ? sel0 : (l == 1) ? sel1 : sel2;
    float nw[8][4];
    #pragma unroll
    for (int m = 0; m < 8; ++m) {
      float a0 = 0.f, a1 = 0.f, a2 = 0.f, a3 = 0.f;
      #pragma unroll
      for (int k = 0; k < 8; ++k) {
        const float s = sp[m * 8 + k];
        a0 = fmaf(s, prev[k][0], a0);
        a1 = fmaf(s, prev[k][1], a1);
        a2 = fmaf(s, prev[k][2], a2);
        a3 = fmaf(s, prev[k][3], a3);
      }
      nw[m][0] = fmaxf(a0, 0.f); nw[m][1] = fmaxf(a1, 0.f);
      nw[m][2] = fmaxf(a2, 0.f); nw[m][3] = fmaxf(a3, 0.f);
    }
    #pragma unroll
    for (int m = 0; m < 8; ++m)
      #pragma unroll
      for (int c = 0; c < 4; ++c)
        prev[m][c] = nw[m][c];
  }

  const float* fp = fs + (size_t)b * 8;
  float ov[4] = {0.f, 0.f, 0.f, 0.f};
  #pragma unroll
  for (int m = 0; m < 8; ++m) {
    const float s = fp[m];
    ov[0] = fmaf(s, prev[m][0], ov[0]);
    ov[1] = fmaf(s, prev[m][1], ov[1]);
    ov[2] = fmaf(s, prev[m][2], ov[2]);
    ov[3] = fmaf(s, prev[m][3], ov[3]);
  }
  ushort4 o;
  o.x = f2bf(ov[0]); o.y = f2bf(ov[1]); o.z = f2bf(ov[2]); o.w = f2bf(ov[3]);
  *reinterpret_cast<ushort4*>(&ovec[(size_t)b * 256 + c0]) = o;
}

// ---------------------------------------------------------------------------
// Last GEMM (R5-proven): out[16384][18] f32 = ovec_bf @ lastWt^T + lastb.
__global__ __launch_bounds__(256) void gemm_last(
    const unsigned short* __restrict__ A, const unsigned short* __restrict__ Wt,
    const float* __restrict__ bias, float* __restrict__ out)
{
  __shared__ unsigned short As[128 * 32];
  __shared__ unsigned short Bs[64 * 32];
  const int row0 = blockIdx.y * 128;
  const int tid = threadIdx.x;
  const int wid = tid >> 6, lane = tid & 63;
  const int arow = tid >> 2;
  const int kcol = (tid & 3) * 8;
  const int lr = lane & 15, lk = (lane >> 4) * 8;
  const int lrow = (lane >> 4) * 4;

  f32x4 acc[2][4] = {};
  for (int k0 = 0; k0 < 256; k0 += 32) {
    gload_lds16(A + (size_t)(row0 + arow) * 256 + k0 + kcol, (char*)As + tid * 16);
    gload_lds16(A + (size_t)(row0 + 64 + arow) * 256 + k0 + kcol, (char*)As + 4096 + tid * 16);
    gload_lds16(Wt + (size_t)arow * 256 + k0 + kcol, (char*)Bs + tid * 16);
    __syncthreads();
    bf16x8 a[2], b[4];
    #pragma unroll
    for (int i = 0; i < 2; ++i)
      a[i] = *reinterpret_cast<const bf16x8*>(&As[(wid * 32 + i * 16 + lr) * 32 + lk]);
    #pragma unroll
    for (int j = 0; j < 4; ++j)
      b[j] = *reinterpret_cast<const bf16x8*>(&Bs[(j * 16 + lr) * 32 + lk]);
    #pragma unroll
    for (int i = 0; i < 2; ++i)
      #pragma unroll
      for (int j = 0; j < 4; ++j)
        acc[i][j] = __builtin_amdgcn_mfma_f32_16x16x32_bf16(a[i], b[j], acc[i][j], 0, 0, 0);
    __syncthreads();
  }
  #pragma unroll
  for (int j = 0; j < 2; ++j) {
    const int col = j * 16 + lr;
    if (col >= 18) continue;
    const float bv = bias[col];
    #pragma unroll
    for (int i = 0; i < 2; ++i) {
      #pragma unroll
      for (int r = 0; r < 4; ++r) {
        const int row = row0 + wid * 32 + i * 16 + lrow + r;
        out[(size_t)row * 18 + col] = acc[i][j][r] + bv;
      }
    }
  }
}

extern "C" void kernel_launch(void* const* d_in, const int* in_sizes, int n_in,
                              void* d_out, int out_size, void* d_ws, size_t ws_size,
                              hipStream_t stream)
{
  (void)in_sizes; (void)n_in; (void)out_size; (void)ws_size;
  const float* x       = (const float*)d_in[0];
  const float* embi    = (const float*)d_in[1];
  const float* u_sel   = (const float*)d_in[2];
  const float* u_fin   = (const float*)d_in[3];
  const float* base_W0 = (const float*)d_in[4];
  const float* base_b0 = (const float*)d_in[5];
  const float* base_W1 = (const float*)d_in[6];
  const float* base_b1 = (const float*)d_in[7];
  const float* em_W0   = (const float*)d_in[8];
  const float* em_b0   = (const float*)d_in[9];
  const float* gat_W0  = (const float*)d_in[10];
  const float* gat_b0  = (const float*)d_in[11];
  const float* gat_W1  = (const float*)d_in[12];
  const float* gat_b1  = (const float*)d_in[13];
  const float* sel_W   = (const float*)d_in[14];
  const float* sel_b   = (const float*)d_in[15];
  const float* selF_W  = (const float*)d_in[16];
  const float* selF_b  = (const float*)d_in[17];
  const float* cond_W  = (const float*)d_in[18];
  const float* cond_b  = (const float*)d_in[19];
  const float* mod_W   = (const float*)d_in[20];
  const float* mod_b   = (const float*)d_in[21];
  const float* last_W  = (const float*)d_in[22];
  const float* last_b  = (const float*)d_in[23];
  const float* bn1_g   = (const float*)d_in[24];
  const float* bn1_b   = (const float*)d_in[25];
  const float* bn2_g   = (const float*)d_in[26];
  const float* bn2_b   = (const float*)d_in[27];

  // --- workspace layout (byte offsets) ---
  char* WSB = (char*)d_ws;
  unsigned short* h_big    = (unsigned short*)(WSB + 0);          // 16384x2048 bf16
  unsigned short* h1e      = (unsigned short*)(WSB + 67108864);   // 16384x416 (em)
  unsigned short* ovec_bf  = (unsigned short*)(WSB + 67108864);   // overlaps dead h1e
  unsigned short* h1       = (unsigned short*)(WSB + 81000448);   // 16384x416 (base)
  unsigned short* x_bf     = (unsigned short*)(WSB + 94631936);   // 16384x128
  unsigned short* e_bf     = (unsigned short*)(WSB + 98826240);   // 16384x128
  unsigned short* emb_bf   = (unsigned short*)(WSB + 103020544);  // 16384x256
  unsigned short* si_bf    = (unsigned short*)(WSB + 111409152);  // 16384x256
  unsigned short* out_bf   = (unsigned short*)(WSB + 119797760);  // 16384x256
  unsigned short* logit_bf = (unsigned short*)(WSB + 128186368);  // 16384x64
  float* gs0   = (float*)(WSB + 130283520);  // 16384x64
  float* gs1   = (float*)(WSB + 134477824);
  float* gs2   = (float*)(WSB + 138672128);
  float* bufFs = (float*)(WSB + 142866432);  // 16384x8
  unsigned short* W0t   = (unsigned short*)(WSB + 143390720);  // 512x128
  unsigned short* emW0t = (unsigned short*)(WSB + 143521792);  // 512x128
  unsigned short* W1t   = (unsigned short*)(WSB + 143652864);  // 256x416
  unsigned short* g0t   = (unsigned short*)(WSB + 143865856);  // 256x416
  unsigned short* g1t   = (unsigned short*)(WSB + 144078848);  // 256x256
  unsigned short* selWt = (unsigned short*)(WSB + 144209920);  // 3x64x256
  unsigned short* condWt= (unsigned short*)(WSB + 144308224);  // 3x256x64
  unsigned short* modWt = (unsigned short*)(WSB + 144406528);  // 8x256x256
  unsigned short* Wt2   = (unsigned short*)(WSB + 145455104);  // 1 MB frag layout
  float* bias2  = (float*)(WSB + 146503680);  // 2048
  float* stats  = (float*)(WSB + 146511872);  // 4608 floats
  unsigned short* lastWt = (unsigned short*)(WSB + 146530304); // 64x256 bf16
  float* scale2 = (float*)(WSB + 146563072);  // 2048
  float* shift2 = (float*)(WSB + 146571264);  // 2048
  float* sum1   = stats;        float* sumsq1 = stats + 256;
  float* sum2   = stats + 512;  float* sumsq2 = stats + 2560;

  const dim3 blk(256);
  // fused prep (converts + weight transposes + stats zero)
  prep_all<<<dim3(4601), blk, 0, stream>>>(
      x, embi, base_W0, em_W0, base_W1, gat_W0, gat_W1, sel_W, cond_W, last_W,
      x_bf, e_bf, W0t, emW0t, W1t, g0t, g1t, selWt, condWt, lastWt, stats);

  // batched W0 GEMMs: z=0 base (x -> h1), z=1 em (e -> h1e), both RELU
  gemm_bf16<128, 2, 2, EPI_RELU, false><<<dim3(4, 128, 2), blk, 0, stream>>>(
      x_bf, 128, W0t, base_b0, h1, 416, 400, 416, 128, nullptr, nullptr, nullptr,
      e_bf, emW0t, em_b0, h1e);
  // base W1 -> out (fused bn1 stats)
  gemm_bf16<128, 2, 2, EPI_STATS, false><<<dim3(2, 128), blk, 0, stream>>>(
      h1, 416, W1t, base_b1, out_bf, 256, 256, 256, 416, nullptr, sum1, sumsq1,
      nullptr, nullptr, nullptr, nullptr);
  // gating
  gemm_bf16<128, 2, 2, EPI_RELU, false><<<dim3(2, 128), blk, 0, stream>>>(
      h1e, 416, g0t, gat_b0, si_bf, 256, 256, 256, 416, nullptr, nullptr, nullptr,
      nullptr, nullptr, nullptr, nullptr);
  gemm_bf16<128, 2, 2, EPI_NONE, false><<<dim3(2, 128), blk, 0, stream>>>(
      si_bf, 256, g1t, gat_b1, emb_bf, 256, 256, 256, 256, nullptr, nullptr, nullptr,
      nullptr, nullptr, nullptr, nullptr);
  // select loop
  float* gs[3] = {gs0, gs1, gs2};
  for (int i = 0; i < 3; ++i) {
    if (i == 0)
      gemm_bf16<64, 4, 1, EPI_TANH, true><<<dim3(1, 128), blk, 0, stream>>>(
          emb_bf, 256, selWt, sel_b, logit_bf, 64, 64, 64, 256, nullptr, nullptr, nullptr,
          nullptr, nullptr, nullptr, nullptr);
    else
      gemm_bf16<64, 4, 1, EPI_TANH, false><<<dim3(1, 128), blk, 0, stream>>>(
          si_bf, 256, selWt + i * 16384, sel_b + i * 64, logit_bf, 64, 64, 64, 256,
          nullptr, nullptr, nullptr, nullptr, nullptr, nullptr, nullptr);
    gumbel8<<<dim3(512), blk, 0, stream>>>(logit_bf, u_sel, gs[i], i * 64, 192);
    gemm_bf16<128, 2, 2, EPI_COND, false><<<dim3(2, 128), blk, 0, stream>>>(
        logit_bf, 64, condWt + i * 16384, cond_b + i * 256, si_bf, 256, 256, 256, 64,
        emb_bf, nullptr, nullptr, nullptr, nullptr, nullptr, nullptr);
  }
  final_select_k<<<dim3(512), blk, 0, stream>>>(si_bf, selF_W, selF_b, u_fin, bufFs);
  // bn1 finalize + mod weight fold + bias2, then fragment reshuffle
  fold_modw_all<<<dim3(8, 8, 9), blk, 0, stream>>>(
      mod_W, bn1_g, bn1_b, mod_b, sum1, sumsq1, modWt, bias2);
  reshuffle_w<<<dim3(64), blk, 0, stream>>>(modWt, Wt2);
  // mod einsum -> h_big (bf16) with fused bn2 stats (fragment-B kernel)
  gemm_mod_frag<<<dim3(16, 128), blk, 0, stream>>>(
      out_bf, Wt2, bias2, h_big, sum2, sumsq2);
  finalize_bn2<<<dim3(8), blk, 0, stream>>>(sum2, sumsq2, bn2_g, bn2_b, scale2, shift2);
  // cascade -> ovec (bf16), then last GEMM -> d_out f32
  final_cascade<<<dim3(4096), blk, 0, stream>>>(
      h_big, scale2, shift2, gs0, gs1, gs2, bufFs, ovec_bf);
  gemm_last<<<dim3(1, 128), blk, 0, stream>>>(ovec_bf, lastWt, last_b, (float*)d_out);
}

// Round 9
// 288.872 us; speedup vs baseline: 5.2596x; 1.0249x over previous
//
#include <hip/hip_runtime.h>
#include <math.h>

// ---------------------------------------------------------------------------
// ModularSelectCascadeNet forward. B=16384, M=8, NUM_LAYERS=4.
// R9: mod GEMM fully barrier-free (A and B direct L2->VGPR, LDS only for the
//     coalesced-store epilogue); front-chain N=256 GEMMs moved to BN=64 tiles
//     for 2x block count (occupancy was 1 block/CU).
// ---------------------------------------------------------------------------

#define EPI_NONE  0
#define EPI_RELU  1
#define EPI_TANH  2
#define EPI_COND  3
#define EPI_STATS 4

typedef short bf16x8 __attribute__((ext_vector_type(8)));
typedef float f32x4 __attribute__((ext_vector_type(4)));

__device__ __forceinline__ unsigned short f2bf(float f) {
  unsigned u = __float_as_uint(f);
  u += 0x7fffu + ((u >> 16) & 1u);
  return (unsigned short)(u >> 16);
}
__device__ __forceinline__ float bf2f(unsigned short h) {
  return __uint_as_float(((unsigned)h) << 16);
}
__device__ __forceinline__ void gload_lds16(const void* g, void* l) {
  __builtin_amdgcn_global_load_lds(
      (const __attribute__((address_space(1))) unsigned int*)g,
      (__attribute__((address_space(3))) unsigned int*)l, 16, 0, 0);
}
__device__ __forceinline__ bf16x8 relu_bf8(bf16x8 v) {
  bf16x8 r;
  #pragma unroll
  for (int j = 0; j < 8; ++j) r[j] = v[j] > 0 ? v[j] : (short)0;
  return r;
}

// ---------------------------------------------------------------------------
// Fused prep (unchanged).
__global__ __launch_bounds__(256) void prep_all(
    const float* __restrict__ x, const float* __restrict__ embi,
    const float* __restrict__ base_W0, const float* __restrict__ em_W0,
    const float* __restrict__ base_W1, const float* __restrict__ gat_W0,
    const float* __restrict__ gat_W1, const float* __restrict__ sel_W,
    const float* __restrict__ cond_W, const float* __restrict__ last_W,
    unsigned short* __restrict__ x_bf, unsigned short* __restrict__ e_bf,
    unsigned short* __restrict__ W0t, unsigned short* __restrict__ emW0t,
    unsigned short* __restrict__ W1t, unsigned short* __restrict__ g0t,
    unsigned short* __restrict__ g1t, unsigned short* __restrict__ selWt,
    unsigned short* __restrict__ condWt, unsigned short* __restrict__ lastWt,
    float* __restrict__ stats)
{
  __shared__ float t[32][33];
  int bid = blockIdx.x;
  const int tid = threadIdx.x;

  if (bid < 4096) {
    const float* src = bid < 2048 ? x : embi;
    unsigned short* dst = bid < 2048 ? x_bf : e_bf;
    const int i = ((bid & 2047) * 256 + tid) * 4;
    const float4 v = *reinterpret_cast<const float4*>(&src[i]);
    ushort4 o;
    o.x = f2bf(v.x); o.y = f2bf(v.y); o.z = f2bf(v.z); o.w = f2bf(v.w);
    *reinterpret_cast<ushort4*>(&dst[i]) = o;
    return;
  }
  bid -= 4096;

  const int tx = tid & 31, ty = tid >> 5;

  if (bid < 496) {
    const float* src; unsigned short* dst; int K, N, KP, gx, local;
    if (bid < 64)       { src = base_W0; dst = W0t;   K = 128; N = 400; KP = 128; gx = 4;  local = bid; }
    else if (bid < 128) { src = em_W0;   dst = emW0t; K = 128; N = 400; KP = 128; gx = 4;  local = bid - 64; }
    else if (bid < 232) { src = base_W1; dst = W1t;   K = 400; N = 256; KP = 416; gx = 13; local = bid - 128; }
    else if (bid < 336) { src = gat_W0;  dst = g0t;   K = 400; N = 256; KP = 416; gx = 13; local = bid - 232; }
    else if (bid < 400) { src = gat_W1;  dst = g1t;   K = 256; N = 256; KP = 256; gx = 8;  local = bid - 336; }
    else if (bid < 448) {
      const int i = (bid - 400) / 16;
      src = sel_W + i * 16384; dst = selWt + i * 16384;
      K = 256; N = 64; KP = 256; gx = 8; local = (bid - 400) % 16;
    } else {
      const int i = (bid - 448) / 16;
      src = cond_W + i * 16384; dst = condWt + i * 16384;
      K = 64; N = 256; KP = 64; gx = 2; local = (bid - 448) % 16;
    }
    const int k0 = (local % gx) * 32, n0 = (local / gx) * 32;
    #pragma unroll
    for (int p = 0; p < 4; ++p) {
      const int k = k0 + ty + p * 8;
      t[ty + p * 8][tx] = (k < K && n0 + tx < N) ? src[(size_t)k * N + n0 + tx] : 0.f;
    }
    __syncthreads();
    #pragma unroll
    for (int p = 0; p < 4; ++p) {
      const int n = n0 + ty + p * 8;
      dst[(size_t)n * KP + k0 + tx] = f2bf(t[tx][ty + p * 8]);
    }
    return;
  }
  bid -= 496;

  if (bid < 8) {
    const int k0 = bid * 32;
    #pragma unroll
    for (int p = 0; p < 4; ++p)
      t[ty + p * 8][tx] = (tx < 18) ? last_W[(size_t)(k0 + ty + p * 8) * 18 + tx] : 0.f;
    __syncthreads();
    #pragma unroll
    for (int p = 0; p < 4; ++p) {
      const int n = ty + p * 8;
      lastWt[(size_t)n * 256 + k0 + tx] = f2bf(t[tx][n]);
      lastWt[(size_t)(n + 32) * 256 + k0 + tx] = 0;
    }
    return;
  }

  for (int i = tid; i < 4608; i += 256) stats[i] = 0.f;
}

// ---------------------------------------------------------------------------
// Generic bf16 MFMA GEMM for the front chain. BM=128, BK=32.
// Optional grid.z batching: when blockIdx.z==1, use (A2, W2, bias_b, C2).
template<int BN, int WM, int WN, int EPI, bool RELU_A>
__global__ __launch_bounds__(256) void gemm_bf16(
    const unsigned short* __restrict__ A, int AS,
    const unsigned short* __restrict__ Wt, const float* __restrict__ bias,
    unsigned short* __restrict__ C, int CS, int Nreal, int NP, int K,
    const unsigned short* __restrict__ emb,
    float* __restrict__ sum, float* __restrict__ sumsq,
    const unsigned short* A2, const unsigned short* W2,
    const float* bias_b, unsigned short* C2)
{
  constexpr int FRAG_M = 128 / WM / 16;
  constexpr int FRAG_N = BN / WN / 16;
  __shared__ unsigned short As[128 * 32];
  __shared__ unsigned short Bs[BN * 32];
  const unsigned short* Ap = (blockIdx.z == 0) ? A : A2;
  const unsigned short* Wp = (blockIdx.z == 0) ? Wt : W2;
  const float* bp = (blockIdx.z == 0) ? bias : bias_b;
  unsigned short* Cp = (blockIdx.z == 0) ? C : C2;
  const int row0 = blockIdx.y * 128;
  const int n0 = blockIdx.x * BN;
  const int tid = threadIdx.x;
  const int wid = tid >> 6, lane = tid & 63;
  const int wr = wid / WN, wc = wid % WN;
  const int arow = tid >> 2;
  const int kcol = (tid & 3) * 8;
  const int lr = lane & 15, lk = (lane >> 4) * 8;
  const int lrow = (lane >> 4) * 4;

  f32x4 acc[FRAG_M][FRAG_N] = {};
  for (int k0 = 0; k0 < K; k0 += 32) {
    gload_lds16(Ap + (size_t)(row0 + arow) * AS + k0 + kcol, (char*)As + tid * 16);
    gload_lds16(Ap + (size_t)(row0 + 64 + arow) * AS + k0 + kcol, (char*)As + 4096 + tid * 16);
    gload_lds16(Wp + (size_t)(n0 + arow) * K + k0 + kcol, (char*)Bs + tid * 16);
    if constexpr (BN == 128)
      gload_lds16(Wp + (size_t)(n0 + 64 + arow) * K + k0 + kcol, (char*)Bs + 4096 + tid * 16);
    __syncthreads();
    bf16x8 a[FRAG_M], b[FRAG_N];
    #pragma unroll
    for (int i = 0; i < FRAG_M; ++i) {
      a[i] = *reinterpret_cast<const bf16x8*>(&As[(wr * (128 / WM) + i * 16 + lr) * 32 + lk]);
      if (RELU_A) a[i] = relu_bf8(a[i]);
    }
    #pragma unroll
    for (int j = 0; j < FRAG_N; ++j)
      b[j] = *reinterpret_cast<const bf16x8*>(&Bs[(wc * (BN / WN) + j * 16 + lr) * 32 + lk]);
    #pragma unroll
    for (int i = 0; i < FRAG_M; ++i)
      #pragma unroll
      for (int j = 0; j < FRAG_N; ++j)
        acc[i][j] = __builtin_amdgcn_mfma_f32_16x16x32_bf16(a[i], b[j], acc[i][j], 0, 0, 0);
    __syncthreads();
  }
  #pragma unroll
  for (int j = 0; j < FRAG_N; ++j) {
    const int col = n0 + wc * (BN / WN) + j * 16 + lr;
    if (col >= NP) continue;
    const bool real = col < Nreal;
    const float bv = real ? bp[col] : 0.f;
    float s = 0.f, q = 0.f;
    #pragma unroll
    for (int i = 0; i < FRAG_M; ++i) {
      #pragma unroll
      for (int r = 0; r < 4; ++r) {
        const int row = row0 + wr * (128 / WM) + i * 16 + lrow + r;
        float v = acc[i][j][r] + bv;
        if (EPI == EPI_RELU) v = fmaxf(v, 0.f);
        if (EPI == EPI_TANH) v = tanhf(v);
        if (EPI == EPI_COND) { v *= bf2f(emb[(size_t)row * 256 + col]); v = fmaxf(v, 0.f); }
        if (!real) v = 0.f;
        const unsigned short hv = f2bf(v);
        Cp[(size_t)row * CS + col] = hv;
        if (EPI == EPI_STATS) {
          const float vr = bf2f(hv);
          s += vr;
          q = fmaf(vr, vr, q);
        }
      }
    }
    if (EPI == EPI_STATS) {
      s += __shfl_xor(s, 16); s += __shfl_xor(s, 32);
      q += __shfl_xor(q, 16); q += __shfl_xor(q, 32);
      if (lane < 16) {
        atomicAdd(&sum[col], s);
        atomicAdd(&sumsq[col], q);
      }
    }
  }
}

// ---------------------------------------------------------------------------
// Mod-einsum GEMM v2: barrier-free K-loop, both operands L2->VGPR.
// Tile 128 rows x 128 cols, 4 waves 2x2. grid (16, 128): m = x>>1, half = x&1.
// A read directly from row-major out_bf (wave consumes 16 full 64B lines per
// fragment). B from Wt2 MFMA-fragment layout (contiguous 1KB per fragment).
// Epilogue: bn2 stats + Cs LDS staging -> coalesced 16B stores (R8-proven).
__global__ __launch_bounds__(256) void gemm_mod_frag(
    const unsigned short* __restrict__ Abf,   // out_bf [16384][256]
    const unsigned short* __restrict__ Wt2,   // fragment layout, 1 MB
    const float* __restrict__ bias2,
    unsigned short* __restrict__ H,           // [16384][2048]
    float* __restrict__ sum, float* __restrict__ sumsq)
{
  __shared__ unsigned short Cs[128 * 136];    // 34 KB
  const int tid = threadIdx.x;
  const int wid = tid >> 6, lane = tid & 63;
  const int wr = wid >> 1, wc = wid & 1;
  const int lr = lane & 15, hi = lane >> 4;
  const int m = blockIdx.x >> 1, half = blockIdx.x & 1;
  const int row0 = blockIdx.y * 128;

  const unsigned short* Wbase =
      Wt2 + (size_t)(m * 16 + half * 8 + wc * 4) * 8 * 512 + lane * 8;
  const unsigned short* Abase = Abf + (size_t)(row0 + wr * 64 + lr) * 256 + hi * 8;

  f32x4 acc[4][4] = {};
  #pragma unroll 2
  for (int ks = 0; ks < 8; ++ks) {
    bf16x8 a[4], b[4];
    #pragma unroll
    for (int i = 0; i < 4; ++i)
      a[i] = *reinterpret_cast<const bf16x8*>(Abase + (size_t)i * 16 * 256 + ks * 32);
    #pragma unroll
    for (int j = 0; j < 4; ++j)
      b[j] = *reinterpret_cast<const bf16x8*>(Wbase + ((size_t)j * 8 + ks) * 512);
    #pragma unroll
    for (int i = 0; i < 4; ++i)
      #pragma unroll
      for (int j = 0; j < 4; ++j)
        acc[i][j] = __builtin_amdgcn_mfma_f32_16x16x32_bf16(a[i], b[j], acc[i][j], 0, 0, 0);
  }

  // Epilogue: bias + bf16 quantize -> Cs; fused bn2 stats from quantized H.
  #pragma unroll
  for (int j = 0; j < 4; ++j) {
    const int J = half * 8 + wc * 4 + j;
    const int gc = m * 256 + J * 16 + lr;
    const float bv = bias2[gc];
    float s = 0.f, q = 0.f;
    #pragma unroll
    for (int i = 0; i < 4; ++i) {
      #pragma unroll
      for (int r = 0; r < 4; ++r) {
        const unsigned short hv = f2bf(acc[i][j][r] + bv);
        Cs[(wr * 64 + i * 16 + hi * 4 + r) * 136 + wc * 64 + j * 16 + lr] = hv;
        const float vr = bf2f(hv);
        s += vr;
        q = fmaf(vr, vr, q);
      }
    }
    s += __shfl_xor(s, 16); s += __shfl_xor(s, 32);
    q += __shfl_xor(q, 16); q += __shfl_xor(q, 32);
    if (lane < 16) {
      atomicAdd(&sum[gc], s);
      atomicAdd(&sumsq[gc], q);
    }
  }
  __syncthreads();
  // Coalesced H stores: thread (row=tid>>2, q=tid&3) writes 32 contiguous cols.
  const int colbase = m * 256 + half * 128;
  #pragma unroll
  for (int pass = 0; pass < 2; ++pass) {
    const int row = pass * 64 + (tid >> 2);
    const int qc = (tid & 3) * 32;
    #pragma unroll
    for (int v = 0; v < 4; ++v) {
      const uint4 d = *reinterpret_cast<const uint4*>(&Cs[row * 136 + qc + v * 8]);
      *reinterpret_cast<uint4*>(&H[(size_t)(row0 + row) * 2048 + colbase + qc + v * 8]) = d;
    }
  }
}

// ---------------------------------------------------------------------------
// Gumbel softmax over groups of 8 (bf16 logits).
__global__ void gumbel8(const unsigned short* __restrict__ logit, const float* __restrict__ u,
                        float* __restrict__ out, int u_off, int u_stride)
{
  const int idx = blockIdx.x * 256 + threadIdx.x;
  const int b = idx >> 3, m = idx & 7;
  const unsigned short* lp = logit + (size_t)b * 64 + m * 8;
  const float* up = u + (size_t)b * u_stride + u_off + m * 8;
  float v[8];
  #pragma unroll
  for (int j = 0; j < 8; ++j) {
    const float uu = fminf(fmaxf(up[j], 1e-10f), 0.9999999f);
    v[j] = bf2f(lp[j]) - logf(-logf(uu));
  }
  float mx = v[0];
  #pragma unroll
  for (int j = 1; j < 8; ++j) mx = fmaxf(mx, v[j]);
  float s = 0.f;
  #pragma unroll
  for (int j = 0; j < 8; ++j) { v[j] = expf(v[j] - mx); s += v[j]; }
  const float inv = 1.f / s;
  float* op = out + (size_t)b * 64 + m * 8;
  #pragma unroll
  for (int j = 0; j < 8; ++j) op[j] = v[j] * inv;
}

__global__ void final_select_k(const unsigned short* __restrict__ si, const float* __restrict__ Wf,
                               const float* __restrict__ bias, const float* __restrict__ u,
                               float* __restrict__ fs)
{
  const int idx = blockIdx.x * 256 + threadIdx.x;
  const int b = idx >> 3, j = idx & 7;
  const unsigned short* sp = si + (size_t)b * 256;
  float acc = bias[j];
  for (int k = 0; k < 256; ++k) acc = fmaf(bf2f(sp[k]), Wf[k * 8 + j], acc);
  const float uu = fminf(fmaxf(u[(size_t)b * 8 + j], 1e-10f), 0.9999999f);
  float v = acc - logf(-logf(uu));
  float mx = v;
  #pragma unroll
  for (int d = 1; d < 8; d <<= 1) mx = fmaxf(mx, __shfl_xor(mx, d, 8));
  float e = expf(v - mx);
  float s = e;
  #pragma unroll
  for (int d = 1; d < 8; d <<= 1) s += __shfl_xor(s, d, 8);
  fs[(size_t)b * 8 + j] = e / s;
}

// ---------------------------------------------------------------------------
// Fold mod weights with inline bn1 finalize. grid (8, 8, 9).
__global__ __launch_bounds__(256) void fold_modw_all(
    const float* __restrict__ W, const float* __restrict__ g1,
    const float* __restrict__ b1, const float* __restrict__ modb,
    const float* __restrict__ sum1, const float* __restrict__ sumsq1,
    unsigned short* __restrict__ Wt, float* __restrict__ bias2)
{
  const float invB = 1.f / 16384.f;
  if (blockIdx.z == 8) {
    if (blockIdx.y != 0) return;
    const int m = blockIdx.x, h = threadIdx.x;
    float acc = modb[m * 256 + h];
    for (int d = 0; d < 256; ++d) {
      const float mean = sum1[d] * invB;
      const float var = sumsq1[d] * invB - mean * mean;
      const float r = rsqrtf(var + 1e-5f);
      const float c = b1[m * 256 + d] - mean * r * g1[m * 256 + d];
      acc = fmaf(c, W[((size_t)m * 256 + d) * 256 + h], acc);
    }
    bias2[m * 256 + h] = acc;
    return;
  }
  __shared__ float t[32][33];
  const int m = blockIdx.z, d0 = blockIdx.y * 32, h0 = blockIdx.x * 32;
  const int tx = threadIdx.x & 31, ty = threadIdx.x >> 5;
  #pragma unroll
  for (int p = 0; p < 4; ++p) {
    const int d = d0 + ty + p * 8;
    const float mean = sum1[d] * invB;
    const float var = sumsq1[d] * invB - mean * mean;
    const float r = rsqrtf(var + 1e-5f);
    t[ty + p * 8][tx] = W[((size_t)m * 256 + d) * 256 + h0 + tx] * r * g1[m * 256 + d];
  }
  __syncthreads();
  #pragma unroll
  for (int p = 0; p < 4; ++p) {
    const int h = h0 + ty + p * 8;
    Wt[((size_t)m * 256 + h) * 256 + d0 + tx] = f2bf(t[tx][ty + p * 8]);
  }
}

// Reshuffle modWt [m][h][d] -> Wt2 MFMA-fragment layout (verified R6-R8).
__global__ __launch_bounds__(256) void reshuffle_w(
    const unsigned short* __restrict__ modWt, unsigned short* __restrict__ Wt2)
{
  const int idx = blockIdx.x * 256 + threadIdx.x;   // 16384
  const int ks = idx & 7, col = (idx >> 3) & 255, m = idx >> 11;
  const unsigned short* src = modWt + ((size_t)m * 256 + col) * 256 + ks * 32;
  unsigned short* dst = Wt2 + (size_t)((m * 16 + (col >> 4)) * 8 + ks) * 512 + (col & 15) * 8;
  #pragma unroll
  for (int h2 = 0; h2 < 4; ++h2)
    *reinterpret_cast<uint4*>(dst + h2 * 128) = *reinterpret_cast<const uint4*>(src + h2 * 8);
}

// bn2 finalize (H already includes bias2): scale2/shift2.
__global__ void finalize_bn2(const float* __restrict__ sum, const float* __restrict__ sumsq,
                             const float* __restrict__ g, const float* __restrict__ b,
                             float* __restrict__ scale, float* __restrict__ shift)
{
  const int i = blockIdx.x * 256 + threadIdx.x;   // 2048
  const float invB = 1.f / 16384.f;
  const float m = sum[i] * invB;
  const float v = sumsq[i] * invB - m * m;
  const float r = rsqrtf(v + 1e-5f);
  const float sc = r * g[i];
  scale[i] = sc;
  shift[i] = b[i] - m * sc;
}

// ---------------------------------------------------------------------------
// Cascade (R5-proven): bn2 apply + 3 select rounds + final mix -> ovec bf16.
__global__ __launch_bounds__(256) void final_cascade(
    const unsigned short* __restrict__ H, const float* __restrict__ scale2,
    const float* __restrict__ shift2, const float* __restrict__ gs0,
    const float* __restrict__ gs1, const float* __restrict__ gs2,
    const float* __restrict__ fs, unsigned short* __restrict__ ovec)
{
  const int wave = threadIdx.x >> 6, lane = threadIdx.x & 63;
  const int b = __builtin_amdgcn_readfirstlane(blockIdx.x * 4 + wave);
  const int c0 = lane << 2;

  float prev[8][4];
  #pragma unroll
  for (int m = 0; m < 8; ++m) {
    const int gc = m * 256 + c0;
    const ushort4 h = *reinterpret_cast<const ushort4*>(&H[(size_t)b * 2048 + gc]);
    const float4 sc = *reinterpret_cast<const float4*>(&scale2[gc]);
    const float4 sh = *reinterpret_cast<const float4*>(&shift2[gc]);
    prev[m][0] = bf2f(h.x) * sc.x + sh.x;
    prev[m][1] = bf2f(h.y) * sc.y + sh.y;
    prev[m][2] = bf2f(h.z) * sc.z + sh.z;
    prev[m][3] = bf2f(h.w) * sc.w + sh.w;
  }

  const float* sel0 = gs2 + (size_t)b * 64;
  const float* sel1 = gs1 + (size_t)b * 64;
  const float* sel2 = gs0 + (size_t)b * 64;
  #pragma unroll
  for (int l = 0; l < 3; ++l) {
    const float* sp = (l == 0) ? sel0 : (l == 1) ? sel1 : sel2;
    float nw[8][4];
    #pragma unroll
    for (int m = 0; m < 8; ++m) {
      float a0 = 0.f, a1 = 0.f, a2 = 0.f, a3 = 0.f;
      #pragma unroll
      for (int k = 0; k < 8; ++k) {
        const float s = sp[m * 8 + k];
        a0 = fmaf(s, prev[k][0], a0);
        a1 = fmaf(s, prev[k][1], a1);
        a2 = fmaf(s, prev[k][2], a2);
        a3 = fmaf(s, prev[k][3], a3);
      }
      nw[m][0] = fmaxf(a0, 0.f); nw[m][1] = fmaxf(a1, 0.f);
      nw[m][2] = fmaxf(a2, 0.f); nw[m][3] = fmaxf(a3, 0.f);
    }
    #pragma unroll
    for (int m = 0; m < 8; ++m)
      #pragma unroll
      for (int c = 0; c < 4; ++c)
        prev[m][c] = nw[m][c];
  }

  const float* fp = fs + (size_t)b * 8;
  float ov[4] = {0.f, 0.f, 0.f, 0.f};
  #pragma unroll
  for (int m = 0; m < 8; ++m) {
    const float s = fp[m];
    ov[0] = fmaf(s, prev[m][0], ov[0]);
    ov[1] = fmaf(s, prev[m][1], ov[1]);
    ov[2] = fmaf(s, prev[m][2], ov[2]);
    ov[3] = fmaf(s, prev[m][3], ov[3]);
  }
  ushort4 o;
  o.x = f2bf(ov[0]); o.y = f2bf(ov[1]); o.z = f2bf(ov[2]); o.w = f2bf(ov[3]);
  *reinterpret_cast<ushort4*>(&ovec[(size_t)b * 256 + c0]) = o;
}

// ---------------------------------------------------------------------------
// Last GEMM (R5-proven): out[16384][18] f32 = ovec_bf @ lastWt^T + lastb.
__global__ __launch_bounds__(256) void gemm_last(
    const unsigned short* __restrict__ A, const unsigned short* __restrict__ Wt,
    const float* __restrict__ bias, float* __restrict__ out)
{
  __shared__ unsigned short As[128 * 32];
  __shared__ unsigned short Bs[64 * 32];
  const int row0 = blockIdx.y * 128;
  const int tid = threadIdx.x;
  const int wid = tid >> 6, lane = tid & 63;
  const int arow = tid >> 2;
  const int kcol = (tid & 3) * 8;
  const int lr = lane & 15, lk = (lane >> 4) * 8;
  const int lrow = (lane >> 4) * 4;

  f32x4 acc[2][4] = {};
  for (int k0 = 0; k0 < 256; k0 += 32) {
    gload_lds16(A + (size_t)(row0 + arow) * 256 + k0 + kcol, (char*)As + tid * 16);
    gload_lds16(A + (size_t)(row0 + 64 + arow) * 256 + k0 + kcol, (char*)As + 4096 + tid * 16);
    gload_lds16(Wt + (size_t)arow * 256 + k0 + kcol, (char*)Bs + tid * 16);
    __syncthreads();
    bf16x8 a[2], b[4];
    #pragma unroll
    for (int i = 0; i < 2; ++i)
      a[i] = *reinterpret_cast<const bf16x8*>(&As[(wid * 32 + i * 16 + lr) * 32 + lk]);
    #pragma unroll
    for (int j = 0; j < 4; ++j)
      b[j] = *reinterpret_cast<const bf16x8*>(&Bs[(j * 16 + lr) * 32 + lk]);
    #pragma unroll
    for (int i = 0; i < 2; ++i)
      #pragma unroll
      for (int j = 0; j < 4; ++j)
        acc[i][j] = __builtin_amdgcn_mfma_f32_16x16x32_bf16(a[i], b[j], acc[i][j], 0, 0, 0);
    __syncthreads();
  }
  #pragma unroll
  for (int j = 0; j < 2; ++j) {
    const int col = j * 16 + lr;
    if (col >= 18) continue;
    const float bv = bias[col];
    #pragma unroll
    for (int i = 0; i < 2; ++i) {
      #pragma unroll
      for (int r = 0; r < 4; ++r) {
        const int row = row0 + wid * 32 + i * 16 + lrow + r;
        out[(size_t)row * 18 + col] = acc[i][j][r] + bv;
      }
    }
  }
}

extern "C" void kernel_launch(void* const* d_in, const int* in_sizes, int n_in,
                              void* d_out, int out_size, void* d_ws, size_t ws_size,
                              hipStream_t stream)
{
  (void)in_sizes; (void)n_in; (void)out_size; (void)ws_size;
  const float* x       = (const float*)d_in[0];
  const float* embi    = (const float*)d_in[1];
  const float* u_sel   = (const float*)d_in[2];
  const float* u_fin   = (const float*)d_in[3];
  const float* base_W0 = (const float*)d_in[4];
  const float* base_b0 = (const float*)d_in[5];
  const float* base_W1 = (const float*)d_in[6];
  const float* base_b1 = (const float*)d_in[7];
  const float* em_W0   = (const float*)d_in[8];
  const float* em_b0   = (const float*)d_in[9];
  const float* gat_W0  = (const float*)d_in[10];
  const float* gat_b0  = (const float*)d_in[11];
  const float* gat_W1  = (const float*)d_in[12];
  const float* gat_b1  = (const float*)d_in[13];
  const float* sel_W   = (const float*)d_in[14];
  const float* sel_b   = (const float*)d_in[15];
  const float* selF_W  = (const float*)d_in[16];
  const float* selF_b  = (const float*)d_in[17];
  const float* cond_W  = (const float*)d_in[18];
  const float* cond_b  = (const float*)d_in[19];
  const float* mod_W   = (const float*)d_in[20];
  const float* mod_b   = (const float*)d_in[21];
  const float* last_W  = (const float*)d_in[22];
  const float* last_b  = (const float*)d_in[23];
  const float* bn1_g   = (const float*)d_in[24];
  const float* bn1_b   = (const float*)d_in[25];
  const float* bn2_g   = (const float*)d_in[26];
  const float* bn2_b   = (const float*)d_in[27];

  // --- workspace layout (byte offsets) ---
  char* WSB = (char*)d_ws;
  unsigned short* h_big    = (unsigned short*)(WSB + 0);          // 16384x2048 bf16
  unsigned short* h1e      = (unsigned short*)(WSB + 67108864);   // 16384x416 (em)
  unsigned short* ovec_bf  = (unsigned short*)(WSB + 67108864);   // overlaps dead h1e
  unsigned short* h1       = (unsigned short*)(WSB + 81000448);   // 16384x416 (base)
  unsigned short* x_bf     = (unsigned short*)(WSB + 94631936);   // 16384x128
  unsigned short* e_bf     = (unsigned short*)(WSB + 98826240);   // 16384x128
  unsigned short* emb_bf   = (unsigned short*)(WSB + 103020544);  // 16384x256
  unsigned short* si_bf    = (unsigned short*)(WSB + 111409152);  // 16384x256
  unsigned short* out_bf   = (unsigned short*)(WSB + 119797760);  // 16384x256
  unsigned short* logit_bf = (unsigned short*)(WSB + 128186368);  // 16384x64
  float* gs0   = (float*)(WSB + 130283520);  // 16384x64
  float* gs1   = (float*)(WSB + 134477824);
  float* gs2   = (float*)(WSB + 138672128);
  float* bufFs = (float*)(WSB + 142866432);  // 16384x8
  unsigned short* W0t   = (unsigned short*)(WSB + 143390720);  // 512x128
  unsigned short* emW0t = (unsigned short*)(WSB + 143521792);  // 512x128
  unsigned short* W1t   = (unsigned short*)(WSB + 143652864);  // 256x416
  unsigned short* g0t   = (unsigned short*)(WSB + 143865856);  // 256x416
  unsigned short* g1t   = (unsigned short*)(WSB + 144078848);  // 256x256
  unsigned short* selWt = (unsigned short*)(WSB + 144209920);  // 3x64x256
  unsigned short* condWt= (unsigned short*)(WSB + 144308224);  // 3x256x64
  unsigned short* modWt = (unsigned short*)(WSB + 144406528);  // 8x256x256
  unsigned short* Wt2   = (unsigned short*)(WSB + 145455104);  // 1 MB frag layout
  float* bias2  = (float*)(WSB + 146503680);  // 2048
  float* stats  = (float*)(WSB + 146511872);  // 4608 floats
  unsigned short* lastWt = (unsigned short*)(WSB + 146530304); // 64x256 bf16
  float* scale2 = (float*)(WSB + 146563072);  // 2048
  float* shift2 = (float*)(WSB + 146571264);  // 2048
  float* sum1   = stats;        float* sumsq1 = stats + 256;
  float* sum2   = stats + 512;  float* sumsq2 = stats + 2560;

  const dim3 blk(256);
  // fused prep (converts + weight transposes + stats zero)
  prep_all<<<dim3(4601), blk, 0, stream>>>(
      x, embi, base_W0, em_W0, base_W1, gat_W0, gat_W1, sel_W, cond_W, last_W,
      x_bf, e_bf, W0t, emW0t, W1t, g0t, g1t, selWt, condWt, lastWt, stats);

  // batched W0 GEMMs: z=0 base (x -> h1), z=1 em (e -> h1e), both RELU
  gemm_bf16<128, 2, 2, EPI_RELU, false><<<dim3(4, 128, 2), blk, 0, stream>>>(
      x_bf, 128, W0t, base_b0, h1, 416, 400, 416, 128, nullptr, nullptr, nullptr,
      e_bf, emW0t, em_b0, h1e);
  // base W1 -> out (fused bn1 stats); BN=64 tiles for occupancy
  gemm_bf16<64, 4, 1, EPI_STATS, false><<<dim3(4, 128), blk, 0, stream>>>(
      h1, 416, W1t, base_b1, out_bf, 256, 256, 256, 416, nullptr, sum1, sumsq1,
      nullptr, nullptr, nullptr, nullptr);
  // gating (BN=64)
  gemm_bf16<64, 4, 1, EPI_RELU, false><<<dim3(4, 128), blk, 0, stream>>>(
      h1e, 416, g0t, gat_b0, si_bf, 256, 256, 256, 416, nullptr, nullptr, nullptr,
      nullptr, nullptr, nullptr, nullptr);
  gemm_bf16<64, 4, 1, EPI_NONE, false><<<dim3(4, 128), blk, 0, stream>>>(
      si_bf, 256, g1t, gat_b1, emb_bf, 256, 256, 256, 256, nullptr, nullptr, nullptr,
      nullptr, nullptr, nullptr, nullptr);
  // select loop
  float* gs[3] = {gs0, gs1, gs2};
  for (int i = 0; i < 3; ++i) {
    if (i == 0)
      gemm_bf16<64, 4, 1, EPI_TANH, true><<<dim3(1, 128), blk, 0, stream>>>(
          emb_bf, 256, selWt, sel_b, logit_bf, 64, 64, 64, 256, nullptr, nullptr, nullptr,
          nullptr, nullptr, nullptr, nullptr);
    else
      gemm_bf16<64, 4, 1, EPI_TANH, false><<<dim3(1, 128), blk, 0, stream>>>(
          si_bf, 256, selWt + i * 16384, sel_b + i * 64, logit_bf, 64, 64, 64, 256,
          nullptr, nullptr, nullptr, nullptr, nullptr, nullptr, nullptr);
    gumbel8<<<dim3(512), blk, 0, stream>>>(logit_bf, u_sel, gs[i], i * 64, 192);
    gemm_bf16<64, 4, 1, EPI_COND, false><<<dim3(4, 128), blk, 0, stream>>>(
        logit_bf, 64, condWt + i * 16384, cond_b + i * 256, si_bf, 256, 256, 256, 64,
        emb_bf, nullptr, nullptr, nullptr, nullptr, nullptr, nullptr);
  }
  final_select_k<<<dim3(512), blk, 0, stream>>>(si_bf, selF_W, selF_b, u_fin, bufFs);
  // bn1 finalize + mod weight fold + bias2, then fragment reshuffle
  fold_modw_all<<<dim3(8, 8, 9), blk, 0, stream>>>(
      mod_W, bn1_g, bn1_b, mod_b, sum1, sumsq1, modWt, bias2);
  reshuffle_w<<<dim3(64), blk, 0, stream>>>(modWt, Wt2);
  // mod einsum -> h_big (bf16) with fused bn2 stats (barrier-free frag kernel)
  gemm_mod_frag<<<dim3(16, 128), blk, 0, stream>>>(
      out_bf, Wt2, bias2, h_big, sum2, sumsq2);
  finalize_bn2<<<dim3(8), blk, 0, stream>>>(sum2, sumsq2, bn2_g, bn2_b, scale2, shift2);
  // cascade -> ovec (bf16), then last GEMM -> d_out f32
  final_cascade<<<dim3(4096), blk, 0, stream>>>(
      h_big, scale2, shift2, gs0, gs1, gs2, bufFs, ovec_bf);
  gemm_last<<<dim3(1, 128), blk, 0, stream>>>(ovec_bf, lastWt, last_b, (float*)d_out);
}

// Round 11
// 256.619 us; speedup vs baseline: 5.9207x; 1.1257x over previous
//
#include <hip/hip_runtime.h>
#include <math.h>

// ---------------------------------------------------------------------------
// ModularSelectCascadeNet forward. B=16384, M=8, NUM_LAYERS=4.
// R11 (= R10 + compile fix): mod GEMM reverted to R5-proven LDS structure +
//      XCD swizzle; sel+gumbel+cond fused per iteration; W0 GEMM reads f32
//      inputs directly. 14 dispatches.
// ---------------------------------------------------------------------------

typedef short bf16x8 __attribute__((ext_vector_type(8)));
typedef float f32x4 __attribute__((ext_vector_type(4)));

__device__ __forceinline__ unsigned short f2bf(float f) {
  unsigned u = __float_as_uint(f);
  u += 0x7fffu + ((u >> 16) & 1u);
  return (unsigned short)(u >> 16);
}
__device__ __forceinline__ float bf2f(unsigned short h) {
  return __uint_as_float(((unsigned)h) << 16);
}
__device__ __forceinline__ unsigned pack2(float a, float b) {
  return ((unsigned)f2bf(b) << 16) | f2bf(a);
}
__device__ __forceinline__ void gload_lds16(const void* g, void* l) {
  __builtin_amdgcn_global_load_lds(
      (const __attribute__((address_space(1))) unsigned int*)g,
      (__attribute__((address_space(3))) unsigned int*)l, 16, 0, 0);
}
__device__ __forceinline__ bf16x8 relu_bf8(bf16x8 v) {
  bf16x8 r;
  #pragma unroll
  for (int j = 0; j < 8; ++j) r[j] = v[j] > 0 ? v[j] : (short)0;
  return r;
}

#define EPI_NONE  0
#define EPI_RELU  1
#define EPI_STATS 4

// ---------------------------------------------------------------------------
// Prep: weight transposes (bf16, zero-padded) + lastW + stats zero. 505 blocks.
__global__ __launch_bounds__(256) void prep_all(
    const float* __restrict__ base_W0, const float* __restrict__ em_W0,
    const float* __restrict__ base_W1, const float* __restrict__ gat_W0,
    const float* __restrict__ gat_W1, const float* __restrict__ sel_W,
    const float* __restrict__ cond_W, const float* __restrict__ last_W,
    unsigned short* __restrict__ W0t, unsigned short* __restrict__ emW0t,
    unsigned short* __restrict__ W1t, unsigned short* __restrict__ g0t,
    unsigned short* __restrict__ g1t, unsigned short* __restrict__ selWt,
    unsigned short* __restrict__ condWt, unsigned short* __restrict__ lastWt,
    float* __restrict__ stats)
{
  __shared__ float t[32][33];
  int bid = blockIdx.x;
  const int tid = threadIdx.x;
  const int tx = tid & 31, ty = tid >> 5;

  if (bid < 496) {
    const float* src; unsigned short* dst; int K, N, KP, gx, local;
    if (bid < 64)       { src = base_W0; dst = W0t;   K = 128; N = 400; KP = 128; gx = 4;  local = bid; }
    else if (bid < 128) { src = em_W0;   dst = emW0t; K = 128; N = 400; KP = 128; gx = 4;  local = bid - 64; }
    else if (bid < 232) { src = base_W1; dst = W1t;   K = 400; N = 256; KP = 416; gx = 13; local = bid - 128; }
    else if (bid < 336) { src = gat_W0;  dst = g0t;   K = 400; N = 256; KP = 416; gx = 13; local = bid - 232; }
    else if (bid < 400) { src = gat_W1;  dst = g1t;   K = 256; N = 256; KP = 256; gx = 8;  local = bid - 336; }
    else if (bid < 448) {
      const int i = (bid - 400) / 16;
      src = sel_W + i * 16384; dst = selWt + i * 16384;
      K = 256; N = 64; KP = 256; gx = 8; local = (bid - 400) % 16;
    } else {
      const int i = (bid - 448) / 16;
      src = cond_W + i * 16384; dst = condWt + i * 16384;
      K = 64; N = 256; KP = 64; gx = 2; local = (bid - 448) % 16;
    }
    const int k0 = (local % gx) * 32, n0 = (local / gx) * 32;
    #pragma unroll
    for (int p = 0; p < 4; ++p) {
      const int k = k0 + ty + p * 8;
      t[ty + p * 8][tx] = (k < K && n0 + tx < N) ? src[(size_t)k * N + n0 + tx] : 0.f;
    }
    __syncthreads();
    #pragma unroll
    for (int p = 0; p < 4; ++p) {
      const int n = n0 + ty + p * 8;
      dst[(size_t)n * KP + k0 + tx] = f2bf(t[tx][ty + p * 8]);
    }
    return;
  }
  bid -= 496;

  if (bid < 8) {
    const int k0 = bid * 32;
    #pragma unroll
    for (int p = 0; p < 4; ++p)
      t[ty + p * 8][tx] = (tx < 18) ? last_W[(size_t)(k0 + ty + p * 8) * 18 + tx] : 0.f;
    __syncthreads();
    #pragma unroll
    for (int p = 0; p < 4; ++p) {
      const int n = ty + p * 8;
      lastWt[(size_t)n * 256 + k0 + tx] = f2bf(t[tx][n]);
      lastWt[(size_t)(n + 32) * 256 + k0 + tx] = 0;
    }
    return;
  }

  for (int i = tid; i < 4608; i += 256) stats[i] = 0.f;
}

// ---------------------------------------------------------------------------
// W0 GEMM: A is fp32 (x or emb input), converted during reg->LDS staging.
// BM=128, BN=128, K=128, WM=2 WN=2. grid (4, 128, 2): z selects base/em.
__global__ __launch_bounds__(256) void gemm_w0(
    const float* __restrict__ Ax, const float* __restrict__ Ae,
    const unsigned short* __restrict__ Wx, const unsigned short* __restrict__ We,
    const float* __restrict__ bx, const float* __restrict__ be,
    unsigned short* __restrict__ Cx, unsigned short* __restrict__ Ce)
{
  __shared__ unsigned short As[128 * 32];
  __shared__ unsigned short Bs[128 * 32];
  const float* Ap = blockIdx.z ? Ae : Ax;
  const unsigned short* Wp = blockIdx.z ? We : Wx;
  const float* bp = blockIdx.z ? be : bx;
  unsigned short* Cp = blockIdx.z ? Ce : Cx;
  const int row0 = blockIdx.y * 128;
  const int n0 = blockIdx.x * 128;
  const int tid = threadIdx.x;
  const int wid = tid >> 6, lane = tid & 63;
  const int wr = wid >> 1, wc = wid & 1;
  const int arow = tid >> 2, kcol = (tid & 3) * 8;
  const int lr = lane & 15, lk = (lane >> 4) * 8;
  const int lrow = (lane >> 4) * 4;

  f32x4 acc[4][4] = {};
  for (int k0 = 0; k0 < 128; k0 += 32) {
    // A: fp32 -> bf16 reg staging, gload-16 lane pattern (conflict-free).
    {
      const float4* s1 = reinterpret_cast<const float4*>(
          Ap + (size_t)(row0 + arow) * 128 + k0 + kcol);
      uint4 w1 = {pack2(s1[0].x, s1[0].y), pack2(s1[0].z, s1[0].w),
                  pack2(s1[1].x, s1[1].y), pack2(s1[1].z, s1[1].w)};
      *reinterpret_cast<uint4*>(&As[arow * 32 + kcol]) = w1;
      const float4* s2 = reinterpret_cast<const float4*>(
          Ap + (size_t)(row0 + 64 + arow) * 128 + k0 + kcol);
      uint4 w2 = {pack2(s2[0].x, s2[0].y), pack2(s2[0].z, s2[0].w),
                  pack2(s2[1].x, s2[1].y), pack2(s2[1].z, s2[1].w)};
      *reinterpret_cast<uint4*>(&As[(64 + arow) * 32 + kcol]) = w2;
    }
    gload_lds16(Wp + (size_t)(n0 + arow) * 128 + k0 + kcol, (char*)Bs + tid * 16);
    gload_lds16(Wp + (size_t)(n0 + 64 + arow) * 128 + k0 + kcol,
                (char*)Bs + 4096 + tid * 16);
    __syncthreads();
    bf16x8 a[4], b[4];
    #pragma unroll
    for (int i = 0; i < 4; ++i)
      a[i] = *reinterpret_cast<const bf16x8*>(&As[(wr * 64 + i * 16 + lr) * 32 + lk]);
    #pragma unroll
    for (int j = 0; j < 4; ++j)
      b[j] = *reinterpret_cast<const bf16x8*>(&Bs[(wc * 64 + j * 16 + lr) * 32 + lk]);
    #pragma unroll
    for (int i = 0; i < 4; ++i)
      #pragma unroll
      for (int j = 0; j < 4; ++j)
        acc[i][j] = __builtin_amdgcn_mfma_f32_16x16x32_bf16(a[i], b[j], acc[i][j], 0, 0, 0);
    __syncthreads();
  }
  #pragma unroll
  for (int j = 0; j < 4; ++j) {
    const int col = n0 + wc * 64 + j * 16 + lr;
    if (col >= 416) continue;
    const bool real = col < 400;
    const float bv = real ? bp[col] : 0.f;
    #pragma unroll
    for (int i = 0; i < 4; ++i) {
      #pragma unroll
      for (int r = 0; r < 4; ++r) {
        const int row = row0 + wr * 64 + i * 16 + lrow + r;
        float v = real ? fmaxf(acc[i][j][r] + bv, 0.f) : 0.f;
        Cp[(size_t)row * 416 + col] = f2bf(v);
      }
    }
  }
}

// ---------------------------------------------------------------------------
// Generic bf16 MFMA GEMM for the front chain. BM=128, BK=32.
template<int BN, int WM, int WN, int EPI, bool RELU_A>
__global__ __launch_bounds__(256) void gemm_bf16(
    const unsigned short* __restrict__ A, int AS,
    const unsigned short* __restrict__ Wt, const float* __restrict__ bias,
    unsigned short* __restrict__ C, int CS, int Nreal, int NP, int K,
    const unsigned short* __restrict__ emb,
    float* __restrict__ sum, float* __restrict__ sumsq)
{
  constexpr int FRAG_M = 128 / WM / 16;
  constexpr int FRAG_N = BN / WN / 16;
  __shared__ unsigned short As[128 * 32];
  __shared__ unsigned short Bs[BN * 32];
  const int row0 = blockIdx.y * 128;
  const int n0 = blockIdx.x * BN;
  const int tid = threadIdx.x;
  const int wid = tid >> 6, lane = tid & 63;
  const int wr = wid / WN, wc = wid % WN;
  const int arow = tid >> 2;
  const int kcol = (tid & 3) * 8;
  const int lr = lane & 15, lk = (lane >> 4) * 8;
  const int lrow = (lane >> 4) * 4;

  f32x4 acc[FRAG_M][FRAG_N] = {};
  for (int k0 = 0; k0 < K; k0 += 32) {
    gload_lds16(A + (size_t)(row0 + arow) * AS + k0 + kcol, (char*)As + tid * 16);
    gload_lds16(A + (size_t)(row0 + 64 + arow) * AS + k0 + kcol, (char*)As + 4096 + tid * 16);
    gload_lds16(Wt + (size_t)(n0 + arow) * K + k0 + kcol, (char*)Bs + tid * 16);
    if constexpr (BN == 128)
      gload_lds16(Wt + (size_t)(n0 + 64 + arow) * K + k0 + kcol, (char*)Bs + 4096 + tid * 16);
    __syncthreads();
    bf16x8 a[FRAG_M], b[FRAG_N];
    #pragma unroll
    for (int i = 0; i < FRAG_M; ++i) {
      a[i] = *reinterpret_cast<const bf16x8*>(&As[(wr * (128 / WM) + i * 16 + lr) * 32 + lk]);
      if (RELU_A) a[i] = relu_bf8(a[i]);
    }
    #pragma unroll
    for (int j = 0; j < FRAG_N; ++j)
      b[j] = *reinterpret_cast<const bf16x8*>(&Bs[(wc * (BN / WN) + j * 16 + lr) * 32 + lk]);
    #pragma unroll
    for (int i = 0; i < FRAG_M; ++i)
      #pragma unroll
      for (int j = 0; j < FRAG_N; ++j)
        acc[i][j] = __builtin_amdgcn_mfma_f32_16x16x32_bf16(a[i], b[j], acc[i][j], 0, 0, 0);
    __syncthreads();
  }
  #pragma unroll
  for (int j = 0; j < FRAG_N; ++j) {
    const int col = n0 + wc * (BN / WN) + j * 16 + lr;
    if (col >= NP) continue;
    const bool real = col < Nreal;
    const float bv = real ? bias[col] : 0.f;
    float s = 0.f, q = 0.f;
    #pragma unroll
    for (int i = 0; i < FRAG_M; ++i) {
      #pragma unroll
      for (int r = 0; r < 4; ++r) {
        const int row = row0 + wr * (128 / WM) + i * 16 + lrow + r;
        float v = acc[i][j][r] + bv;
        if (EPI == EPI_RELU) v = fmaxf(v, 0.f);
        if (!real) v = 0.f;
        const unsigned short hv = f2bf(v);
        C[(size_t)row * CS + col] = hv;
        if (EPI == EPI_STATS) {
          const float vr = bf2f(hv);
          s += vr;
          q = fmaf(vr, vr, q);
        }
      }
    }
    if (EPI == EPI_STATS) {
      s += __shfl_xor(s, 16); s += __shfl_xor(s, 32);
      q += __shfl_xor(q, 16); q += __shfl_xor(q, 32);
      if (lane < 16) {
        atomicAdd(&sum[col], s);
        atomicAdd(&sumsq[col], q);
      }
    }
  }
}

// ---------------------------------------------------------------------------
// Mod-einsum GEMM: R5-proven LDS structure + bijective XCD swizzle.
// 1-D grid of 2048 blocks; swz=(lin&7)*256+lin>>3 -> each XCD gets 16
// contiguous row-stripes x all 16 col tiles (A-stripe L2-resident per XCD).
__global__ __launch_bounds__(256) void gemm_mod(
    const unsigned short* __restrict__ A,    // out_bf [16384][256]
    const unsigned short* __restrict__ Wt,   // modWt [2048][256]
    const float* __restrict__ bias, unsigned short* __restrict__ C,
    float* __restrict__ sum, float* __restrict__ sumsq)
{
  __shared__ unsigned short As[128 * 32];
  __shared__ unsigned short Bs[128 * 32];
  const int lin = blockIdx.x;
  const int swz = (lin & 7) * 256 + (lin >> 3);
  const int row0 = (swz >> 4) * 128;
  const int n0 = (swz & 15) * 128;
  const int tid = threadIdx.x;
  const int wid = tid >> 6, lane = tid & 63;
  const int wr = wid >> 1, wc = wid & 1;
  const int arow = tid >> 2;
  const int kcol = (tid & 3) * 8;
  const int lr = lane & 15, lk = (lane >> 4) * 8;
  const int lrow = (lane >> 4) * 4;

  f32x4 acc[4][4] = {};
  for (int k0 = 0; k0 < 256; k0 += 32) {
    gload_lds16(A + (size_t)(row0 + arow) * 256 + k0 + kcol, (char*)As + tid * 16);
    gload_lds16(A + (size_t)(row0 + 64 + arow) * 256 + k0 + kcol, (char*)As + 4096 + tid * 16);
    gload_lds16(Wt + (size_t)(n0 + arow) * 256 + k0 + kcol, (char*)Bs + tid * 16);
    gload_lds16(Wt + (size_t)(n0 + 64 + arow) * 256 + k0 + kcol, (char*)Bs + 4096 + tid * 16);
    __syncthreads();
    bf16x8 a[4], b[4];
    #pragma unroll
    for (int i = 0; i < 4; ++i)
      a[i] = *reinterpret_cast<const bf16x8*>(&As[(wr * 64 + i * 16 + lr) * 32 + lk]);
    #pragma unroll
    for (int j = 0; j < 4; ++j)
      b[j] = *reinterpret_cast<const bf16x8*>(&Bs[(wc * 64 + j * 16 + lr) * 32 + lk]);
    #pragma unroll
    for (int i = 0; i < 4; ++i)
      #pragma unroll
      for (int j = 0; j < 4; ++j)
        acc[i][j] = __builtin_amdgcn_mfma_f32_16x16x32_bf16(a[i], b[j], acc[i][j], 0, 0, 0);
    __syncthreads();
  }
  #pragma unroll
  for (int j = 0; j < 4; ++j) {
    const int col = n0 + wc * 64 + j * 16 + lr;
    const float bv = bias[col];
    float s = 0.f, q = 0.f;
    #pragma unroll
    for (int i = 0; i < 4; ++i) {
      #pragma unroll
      for (int r = 0; r < 4; ++r) {
        const int row = row0 + wr * 64 + i * 16 + lrow + r;
        const unsigned short hv = f2bf(acc[i][j][r] + bv);
        C[(size_t)row * 2048 + col] = hv;
        const float vr = bf2f(hv);
        s += vr;
        q = fmaf(vr, vr, q);
      }
    }
    s += __shfl_xor(s, 16); s += __shfl_xor(s, 32);
    q += __shfl_xor(q, 16); q += __shfl_xor(q, 32);
    if (lane < 16) {
      atomicAdd(&sum[col], s);
      atomicAdd(&sumsq[col], q);
    }
  }
}

// ---------------------------------------------------------------------------
// Fused select iteration: logits = tanh(A @ selWt^T + selb) (LDS only);
// gs = gumbel_softmax(logits, u); siout = relu((logits @ condWt^T + condb)*emb).
// 128 rows/block, grid 128. Phase1 WM=4/WN=1; phase3 WM=2/WN=2, B from L2.
template<bool RELU_A>
__global__ __launch_bounds__(256) void fused_select(
    const unsigned short* __restrict__ A, const unsigned short* __restrict__ selWt,
    const float* __restrict__ selb, const unsigned short* __restrict__ condWt,
    const float* __restrict__ condb, const unsigned short* __restrict__ emb,
    const float* __restrict__ u, int u_off,
    float* __restrict__ gs, unsigned short* __restrict__ siout)
{
  __shared__ unsigned short As[128 * 32];   // 8 KB
  __shared__ unsigned short Bs[64 * 32];    // 4 KB
  __shared__ unsigned short Ls[128 * 72];   // 18.4 KB logits (pad 72)
  const int tid = threadIdx.x;
  const int wid = tid >> 6, lane = tid & 63;
  const int lr = lane & 15, hi = lane >> 4;
  const int lk = hi * 8;
  const int row0 = blockIdx.x * 128;
  const int arow = tid >> 2, kcol = (tid & 3) * 8;

  // ---- phase 1: sel GEMM (K=256, N=64) ----
  {
    f32x4 acc[2][4] = {};
    for (int k0 = 0; k0 < 256; k0 += 32) {
      gload_lds16(A + (size_t)(row0 + arow) * 256 + k0 + kcol, (char*)As + tid * 16);
      gload_lds16(A + (size_t)(row0 + 64 + arow) * 256 + k0 + kcol, (char*)As + 4096 + tid * 16);
      gload_lds16(selWt + (size_t)arow * 256 + k0 + kcol, (char*)Bs + tid * 16);
      __syncthreads();
      bf16x8 a[2], b[4];
      #pragma unroll
      for (int i = 0; i < 2; ++i) {
        a[i] = *reinterpret_cast<const bf16x8*>(&As[(wid * 32 + i * 16 + lr) * 32 + lk]);
        if (RELU_A) a[i] = relu_bf8(a[i]);
      }
      #pragma unroll
      for (int j = 0; j < 4; ++j)
        b[j] = *reinterpret_cast<const bf16x8*>(&Bs[(j * 16 + lr) * 32 + lk]);
      #pragma unroll
      for (int i = 0; i < 2; ++i)
        #pragma unroll
        for (int j = 0; j < 4; ++j)
          acc[i][j] = __builtin_amdgcn_mfma_f32_16x16x32_bf16(a[i], b[j], acc[i][j], 0, 0, 0);
      __syncthreads();
    }
    #pragma unroll
    for (int j = 0; j < 4; ++j) {
      const int col = j * 16 + lr;
      const float bv = selb[col];
      #pragma unroll
      for (int i = 0; i < 2; ++i)
        #pragma unroll
        for (int r = 0; r < 4; ++r) {
          const int row = wid * 32 + i * 16 + hi * 4 + r;
          Ls[row * 72 + col] = f2bf(tanhf(acc[i][j][r] + bv));
        }
    }
  }
  __syncthreads();

  // ---- phase 2: gumbel softmax (1024 (b,m) pairs, 4 per thread) ----
  #pragma unroll
  for (int p = 0; p < 4; ++p) {
    const int pair = p * 256 + tid;
    const int bl = pair >> 3, mm = pair & 7;
    const int bg = row0 + bl;
    float v[8];
    #pragma unroll
    for (int jj = 0; jj < 8; ++jj) v[jj] = bf2f(Ls[bl * 72 + mm * 8 + jj]);
    const float* up = u + (size_t)bg * 192 + u_off + mm * 8;
    #pragma unroll
    for (int jj = 0; jj < 8; ++jj) {
      const float uu = fminf(fmaxf(up[jj], 1e-10f), 0.9999999f);
      v[jj] -= logf(-logf(uu));
    }
    float mx = v[0];
    #pragma unroll
    for (int jj = 1; jj < 8; ++jj) mx = fmaxf(mx, v[jj]);
    float s = 0.f;
    #pragma unroll
    for (int jj = 0; jj < 8; ++jj) { v[jj] = expf(v[jj] - mx); s += v[jj]; }
    const float inv = 1.f / s;
    float* op = gs + (size_t)bg * 64 + mm * 8;
    #pragma unroll
    for (int jj = 0; jj < 8; ++jj) op[jj] = v[jj] * inv;
  }

  // ---- phase 3: cond GEMM (A = Ls, K=64, N=256; B direct from L2) ----
  {
    const int wr2 = wid >> 1, wc2 = wid & 1;
    f32x4 acc2[4][8] = {};
    #pragma unroll
    for (int kq = 0; kq < 2; ++kq) {
      const int k0 = kq * 32;
      bf16x8 a2[4];
      #pragma unroll
      for (int i = 0; i < 4; ++i)
        a2[i] = *reinterpret_cast<const bf16x8*>(
            &Ls[(wr2 * 64 + i * 16 + lr) * 72 + k0 + hi * 8]);
      #pragma unroll
      for (int j = 0; j < 8; ++j) {
        const bf16x8 b2 = *reinterpret_cast<const bf16x8*>(
            condWt + (size_t)(wc2 * 128 + j * 16 + lr) * 64 + k0 + hi * 8);
        #pragma unroll
        for (int i = 0; i < 4; ++i)
          acc2[i][j] = __builtin_amdgcn_mfma_f32_16x16x32_bf16(a2[i], b2, acc2[i][j], 0, 0, 0);
      }
    }
    #pragma unroll
    for (int j = 0; j < 8; ++j) {
      const int col = wc2 * 128 + j * 16 + lr;
      const float bv = condb[col];
      #pragma unroll
      for (int i = 0; i < 4; ++i)
        #pragma unroll
        for (int r = 0; r < 4; ++r) {
          const int row = row0 + wr2 * 64 + i * 16 + hi * 4 + r;
          float vv = (acc2[i][j][r] + bv) * bf2f(emb[(size_t)row * 256 + col]);
          siout[(size_t)row * 256 + col] = f2bf(fmaxf(vv, 0.f));
        }
    }
  }
}

__global__ void final_select_k(const unsigned short* __restrict__ si, const float* __restrict__ Wf,
                               const float* __restrict__ bias, const float* __restrict__ u,
                               float* __restrict__ fs)
{
  const int idx = blockIdx.x * 256 + threadIdx.x;
  const int b = idx >> 3, j = idx & 7;
  const unsigned short* sp = si + (size_t)b * 256;
  float acc = bias[j];
  for (int k = 0; k < 256; ++k) acc = fmaf(bf2f(sp[k]), Wf[k * 8 + j], acc);
  const float uu = fminf(fmaxf(u[(size_t)b * 8 + j], 1e-10f), 0.9999999f);
  float v = acc - logf(-logf(uu));
  float mx = v;
  #pragma unroll
  for (int d = 1; d < 8; d <<= 1) mx = fmaxf(mx, __shfl_xor(mx, d, 8));
  float e = expf(v - mx);
  float s = e;
  #pragma unroll
  for (int d = 1; d < 8; d <<= 1) s += __shfl_xor(s, d, 8);
  fs[(size_t)b * 8 + j] = e / s;
}

// ---------------------------------------------------------------------------
// Fold mod weights with inline bn1 finalize. grid (8, 8, 9).
__global__ __launch_bounds__(256) void fold_modw_all(
    const float* __restrict__ W, const float* __restrict__ g1,
    const float* __restrict__ b1, const float* __restrict__ modb,
    const float* __restrict__ sum1, const float* __restrict__ sumsq1,
    unsigned short* __restrict__ Wt, float* __restrict__ bias2)
{
  const float invB = 1.f / 16384.f;
  if (blockIdx.z == 8) {
    if (blockIdx.y != 0) return;
    const int m = blockIdx.x, h = threadIdx.x;
    float acc = modb[m * 256 + h];
    for (int d = 0; d < 256; ++d) {
      const float mean = sum1[d] * invB;
      const float var = sumsq1[d] * invB - mean * mean;
      const float r = rsqrtf(var + 1e-5f);
      const float c = b1[m * 256 + d] - mean * r * g1[m * 256 + d];
      acc = fmaf(c, W[((size_t)m * 256 + d) * 256 + h], acc);
    }
    bias2[m * 256 + h] = acc;
    return;
  }
  __shared__ float t[32][33];
  const int m = blockIdx.z, d0 = blockIdx.y * 32, h0 = blockIdx.x * 32;
  const int tx = threadIdx.x & 31, ty = threadIdx.x >> 5;
  #pragma unroll
  for (int p = 0; p < 4; ++p) {
    const int d = d0 + ty + p * 8;
    const float mean = sum1[d] * invB;
    const float var = sumsq1[d] * invB - mean * mean;
    const float r = rsqrtf(var + 1e-5f);
    t[ty + p * 8][tx] = W[((size_t)m * 256 + d) * 256 + h0 + tx] * r * g1[m * 256 + d];
  }
  __syncthreads();
  #pragma unroll
  for (int p = 0; p < 4; ++p) {
    const int h = h0 + ty + p * 8;
    Wt[((size_t)m * 256 + h) * 256 + d0 + tx] = f2bf(t[tx][ty + p * 8]);
  }
}

// bn2 finalize (H already includes bias2): scale2/shift2.
__global__ void finalize_bn2(const float* __restrict__ sum, const float* __restrict__ sumsq,
                             const float* __restrict__ g, const float* __restrict__ b,
                             float* __restrict__ scale, float* __restrict__ shift)
{
  const int i = blockIdx.x * 256 + threadIdx.x;
  const float invB = 1.f / 16384.f;
  const float m = sum[i] * invB;
  const float v = sumsq[i] * invB - m * m;
  const float r = rsqrtf(v + 1e-5f);
  const float sc = r * g[i];
  scale[i] = sc;
  shift[i] = b[i] - m * sc;
}

// ---------------------------------------------------------------------------
// Cascade (R5-proven).
__global__ __launch_bounds__(256) void final_cascade(
    const unsigned short* __restrict__ H, const float* __restrict__ scale2,
    const float* __restrict__ shift2, const float* __restrict__ gs0,
    const float* __restrict__ gs1, const float* __restrict__ gs2,
    const float* __restrict__ fs, unsigned short* __restrict__ ovec)
{
  const int wave = threadIdx.x >> 6, lane = threadIdx.x & 63;
  const int b = __builtin_amdgcn_readfirstlane(blockIdx.x * 4 + wave);
  const int c0 = lane << 2;

  float prev[8][4];
  #pragma unroll
  for (int m = 0; m < 8; ++m) {
    const int gc = m * 256 + c0;
    const ushort4 h = *reinterpret_cast<const ushort4*>(&H[(size_t)b * 2048 + gc]);
    const float4 sc = *reinterpret_cast<const float4*>(&scale2[gc]);
    const float4 sh = *reinterpret_cast<const float4*>(&shift2[gc]);
    prev[m][0] = bf2f(h.x) * sc.x + sh.x;
    prev[m][1] = bf2f(h.y) * sc.y + sh.y;
    prev[m][2] = bf2f(h.z) * sc.z + sh.z;
    prev[m][3] = bf2f(h.w) * sc.w + sh.w;
  }

  const float* sel0 = gs2 + (size_t)b * 64;
  const float* sel1 = gs1 + (size_t)b * 64;
  const float* sel2 = gs0 + (size_t)b * 64;
  #pragma unroll
  for (int l = 0; l < 3; ++l) {
    const float* sp = (l == 0) ? sel0 : (l == 1) ? sel1 : sel2;
    float nw[8][4];
    #pragma unroll
    for (int m = 0; m < 8; ++m) {
      float a0 = 0.f, a1 = 0.f, a2 = 0.f, a3 = 0.f;
      #pragma unroll
      for (int k = 0; k < 8; ++k) {
        const float s = sp[m * 8 + k];
        a0 = fmaf(s, prev[k][0], a0);
        a1 = fmaf(s, prev[k][1], a1);
        a2 = fmaf(s, prev[k][2], a2);
        a3 = fmaf(s, prev[k][3], a3);
      }
      nw[m][0] = fmaxf(a0, 0.f); nw[m][1] = fmaxf(a1, 0.f);
      nw[m][2] = fmaxf(a2, 0.f); nw[m][3] = fmaxf(a3, 0.f);
    }
    #pragma unroll
    for (int m = 0; m < 8; ++m)
      #pragma unroll
      for (int c = 0; c < 4; ++c)
        prev[m][c] = nw[m][c];
  }

  const float* fp = fs + (size_t)b * 8;
  float ov[4] = {0.f, 0.f, 0.f, 0.f};
  #pragma unroll
  for (int m = 0; m < 8; ++m) {
    const float s = fp[m];
    ov[0] = fmaf(s, prev[m][0], ov[0]);
    ov[1] = fmaf(s, prev[m][1], ov[1]);
    ov[2] = fmaf(s, prev[m][2], ov[2]);
    ov[3] = fmaf(s, prev[m][3], ov[3]);
  }
  ushort4 o;
  o.x = f2bf(ov[0]); o.y = f2bf(ov[1]); o.z = f2bf(ov[2]); o.w = f2bf(ov[3]);
  *reinterpret_cast<ushort4*>(&ovec[(size_t)b * 256 + c0]) = o;
}

// ---------------------------------------------------------------------------
// Last GEMM (R5-proven): out[16384][18] f32 = ovec_bf @ lastWt^T + lastb.
__global__ __launch_bounds__(256) void gemm_last(
    const unsigned short* __restrict__ A, const unsigned short* __restrict__ Wt,
    const float* __restrict__ bias, float* __restrict__ out)
{
  __shared__ unsigned short As[128 * 32];
  __shared__ unsigned short Bs[64 * 32];
  const int row0 = blockIdx.y * 128;
  const int tid = threadIdx.x;
  const int wid = tid >> 6, lane = tid & 63;
  const int arow = tid >> 2;
  const int kcol = (tid & 3) * 8;
  const int lr = lane & 15, lk = (lane >> 4) * 8;
  const int lrow = (lane >> 4) * 4;

  f32x4 acc[2][4] = {};
  for (int k0 = 0; k0 < 256; k0 += 32) {
    gload_lds16(A + (size_t)(row0 + arow) * 256 + k0 + kcol, (char*)As + tid * 16);
    gload_lds16(A + (size_t)(row0 + 64 + arow) * 256 + k0 + kcol, (char*)As + 4096 + tid * 16);
    gload_lds16(Wt + (size_t)arow * 256 + k0 + kcol, (char*)Bs + tid * 16);
    __syncthreads();
    bf16x8 a[2], b[4];
    #pragma unroll
    for (int i = 0; i < 2; ++i)
      a[i] = *reinterpret_cast<const bf16x8*>(&As[(wid * 32 + i * 16 + lr) * 32 + lk]);
    #pragma unroll
    for (int j = 0; j < 4; ++j)
      b[j] = *reinterpret_cast<const bf16x8*>(&Bs[(j * 16 + lr) * 32 + lk]);
    #pragma unroll
    for (int i = 0; i < 2; ++i)
      #pragma unroll
      for (int j = 0; j < 4; ++j)
        acc[i][j] = __builtin_amdgcn_mfma_f32_16x16x32_bf16(a[i], b[j], acc[i][j], 0, 0, 0);
    __syncthreads();
  }
  #pragma unroll
  for (int j = 0; j < 2; ++j) {
    const int col = j * 16 + lr;
    if (col >= 18) continue;
    const float bv = bias[col];
    #pragma unroll
    for (int i = 0; i < 2; ++i) {
      #pragma unroll
      for (int r = 0; r < 4; ++r) {
        const int row = row0 + wid * 32 + i * 16 + lrow + r;
        out[(size_t)row * 18 + col] = acc[i][j][r] + bv;
      }
    }
  }
}

extern "C" void kernel_launch(void* const* d_in, const int* in_sizes, int n_in,
                              void* d_out, int out_size, void* d_ws, size_t ws_size,
                              hipStream_t stream)
{
  (void)in_sizes; (void)n_in; (void)out_size; (void)ws_size;
  const float* x       = (const float*)d_in[0];
  const float* embi    = (const float*)d_in[1];
  const float* u_sel   = (const float*)d_in[2];
  const float* u_fin   = (const float*)d_in[3];
  const float* base_W0 = (const float*)d_in[4];
  const float* base_b0 = (const float*)d_in[5];
  const float* base_W1 = (const float*)d_in[6];
  const float* base_b1 = (const float*)d_in[7];
  const float* em_W0   = (const float*)d_in[8];
  const float* em_b0   = (const float*)d_in[9];
  const float* gat_W0  = (const float*)d_in[10];
  const float* gat_b0  = (const float*)d_in[11];
  const float* gat_W1  = (const float*)d_in[12];
  const float* gat_b1  = (const float*)d_in[13];
  const float* sel_W   = (const float*)d_in[14];
  const float* sel_b   = (const float*)d_in[15];
  const float* selF_W  = (const float*)d_in[16];
  const float* selF_b  = (const float*)d_in[17];
  const float* cond_W  = (const float*)d_in[18];
  const float* cond_b  = (const float*)d_in[19];
  const float* mod_W   = (const float*)d_in[20];
  const float* mod_b   = (const float*)d_in[21];
  const float* last_W  = (const float*)d_in[22];
  const float* last_b  = (const float*)d_in[23];
  const float* bn1_g   = (const float*)d_in[24];
  const float* bn1_b   = (const float*)d_in[25];
  const float* bn2_g   = (const float*)d_in[26];
  const float* bn2_b   = (const float*)d_in[27];

  // --- workspace layout (byte offsets) ---
  char* WSB = (char*)d_ws;
  unsigned short* h_big    = (unsigned short*)(WSB + 0);          // 16384x2048 bf16
  unsigned short* h1e      = (unsigned short*)(WSB + 67108864);   // 16384x416 (em)
  unsigned short* ovec_bf  = (unsigned short*)(WSB + 67108864);   // overlaps dead h1e
  unsigned short* h1       = (unsigned short*)(WSB + 81000448);   // 16384x416 (base)
  unsigned short* emb_bf   = (unsigned short*)(WSB + 103020544);  // 16384x256
  unsigned short* si_bf    = (unsigned short*)(WSB + 111409152);  // 16384x256
  unsigned short* out_bf   = (unsigned short*)(WSB + 119797760);  // 16384x256
  float* gs0   = (float*)(WSB + 130283520);  // 16384x64
  float* gs1   = (float*)(WSB + 134477824);
  float* gs2   = (float*)(WSB + 138672128);
  float* bufFs = (float*)(WSB + 142866432);  // 16384x8
  unsigned short* W0t   = (unsigned short*)(WSB + 143390720);  // 512x128
  unsigned short* emW0t = (unsigned short*)(WSB + 143521792);  // 512x128
  unsigned short* W1t   = (unsigned short*)(WSB + 143652864);  // 256x416
  unsigned short* g0t   = (unsigned short*)(WSB + 143865856);  // 256x416
  unsigned short* g1t   = (unsigned short*)(WSB + 144078848);  // 256x256
  unsigned short* selWt = (unsigned short*)(WSB + 144209920);  // 3x64x256
  unsigned short* condWt= (unsigned short*)(WSB + 144308224);  // 3x256x64
  unsigned short* modWt = (unsigned short*)(WSB + 144406528);  // 8x256x256
  float* bias2  = (float*)(WSB + 146503680);  // 2048
  float* stats  = (float*)(WSB + 146511872);  // 4608 floats
  unsigned short* lastWt = (unsigned short*)(WSB + 146530304); // 64x256 bf16
  float* scale2 = (float*)(WSB + 146563072);  // 2048
  float* shift2 = (float*)(WSB + 146571264);  // 2048
  float* sum1   = stats;        float* sumsq1 = stats + 256;
  float* sum2   = stats + 512;  float* sumsq2 = stats + 2560;

  const dim3 blk(256);
  // prep (weight transposes + stats zero) — no input converts anymore
  prep_all<<<dim3(505), blk, 0, stream>>>(
      base_W0, em_W0, base_W1, gat_W0, gat_W1, sel_W, cond_W, last_W,
      W0t, emW0t, W1t, g0t, g1t, selWt, condWt, lastWt, stats);

  // batched W0 GEMMs from fp32 inputs: z=0 base (x -> h1), z=1 em (e -> h1e)
  gemm_w0<<<dim3(4, 128, 2), blk, 0, stream>>>(
      x, embi, W0t, emW0t, base_b0, em_b0, h1, h1e);
  // base W1 -> out (fused bn1 stats)
  gemm_bf16<64, 4, 1, EPI_STATS, false><<<dim3(4, 128), blk, 0, stream>>>(
      h1, 416, W1t, base_b1, out_bf, 256, 256, 256, 416, nullptr, sum1, sumsq1);
  // gating
  gemm_bf16<64, 4, 1, EPI_RELU, false><<<dim3(4, 128), blk, 0, stream>>>(
      h1e, 416, g0t, gat_b0, si_bf, 256, 256, 256, 416, nullptr, nullptr, nullptr);
  gemm_bf16<64, 4, 1, EPI_NONE, false><<<dim3(4, 128), blk, 0, stream>>>(
      si_bf, 256, g1t, gat_b1, emb_bf, 256, 256, 256, 256, nullptr, nullptr, nullptr);
  // fused select loop (sel GEMM + gumbel + cond GEMM per iteration)
  fused_select<true><<<dim3(128), blk, 0, stream>>>(
      emb_bf, selWt, sel_b, condWt, cond_b, emb_bf, u_sel, 0, gs0, si_bf);
  fused_select<false><<<dim3(128), blk, 0, stream>>>(
      si_bf, selWt + 16384, sel_b + 64, condWt + 16384, cond_b + 256, emb_bf,
      u_sel, 64, gs1, si_bf);
  fused_select<false><<<dim3(128), blk, 0, stream>>>(
      si_bf, selWt + 32768, sel_b + 128, condWt + 32768, cond_b + 512, emb_bf,
      u_sel, 128, gs2, si_bf);
  final_select_k<<<dim3(512), blk, 0, stream>>>(si_bf, selF_W, selF_b, u_fin, bufFs);
  // bn1 finalize + mod weight fold + bias2
  fold_modw_all<<<dim3(8, 8, 9), blk, 0, stream>>>(
      mod_W, bn1_g, bn1_b, mod_b, sum1, sumsq1, modWt, bias2);
  // mod einsum -> h_big (bf16) with fused bn2 stats (R5 structure + XCD swizzle)
  gemm_mod<<<dim3(2048), blk, 0, stream>>>(out_bf, modWt, bias2, h_big, sum2, sumsq2);
  finalize_bn2<<<dim3(8), blk, 0, stream>>>(sum2, sumsq2, bn2_g, bn2_b, scale2, shift2);
  // cascade -> ovec (bf16), then last GEMM -> d_out f32
  final_cascade<<<dim3(4096), blk, 0, stream>>>(
      h_big, scale2, shift2, gs0, gs1, gs2, bufFs, ovec_bf);
  gemm_last<<<dim3(1, 128), blk, 0, stream>>>(ovec_bf, lastWt, last_b, (float*)d_out);
}

// Round 12
// 254.854 us; speedup vs baseline: 5.9617x; 1.0069x over previous
//
#include <hip/hip_runtime.h>
#include <math.h>

// ---------------------------------------------------------------------------
// ModularSelectCascadeNet forward. B=16384, M=8, NUM_LAYERS=4.
// R12: gemm_mod + LDS XOR swizzle + Cs store staging; W1/g0 batched;
//      final_select as MFMA kernel. 13 dispatches.
// ---------------------------------------------------------------------------

typedef short bf16x8 __attribute__((ext_vector_type(8)));
typedef float f32x4 __attribute__((ext_vector_type(4)));

__device__ __forceinline__ unsigned short f2bf(float f) {
  unsigned u = __float_as_uint(f);
  u += 0x7fffu + ((u >> 16) & 1u);
  return (unsigned short)(u >> 16);
}
__device__ __forceinline__ float bf2f(unsigned short h) {
  return __uint_as_float(((unsigned)h) << 16);
}
__device__ __forceinline__ unsigned pack2(float a, float b) {
  return ((unsigned)f2bf(b) << 16) | f2bf(a);
}
__device__ __forceinline__ void gload_lds16(const void* g, void* l) {
  __builtin_amdgcn_global_load_lds(
      (const __attribute__((address_space(1))) unsigned int*)g,
      (__attribute__((address_space(3))) unsigned int*)l, 16, 0, 0);
}
__device__ __forceinline__ bf16x8 relu_bf8(bf16x8 v) {
  bf16x8 r;
  #pragma unroll
  for (int j = 0; j < 8; ++j) r[j] = v[j] > 0 ? v[j] : (short)0;
  return r;
}

#define EPI_NONE  0
#define EPI_RELU  1
#define EPI_STATS 4

// ---------------------------------------------------------------------------
// Prep: weight transposes + lastW + selFt + stats zero. 506 blocks.
__global__ __launch_bounds__(256) void prep_all(
    const float* __restrict__ base_W0, const float* __restrict__ em_W0,
    const float* __restrict__ base_W1, const float* __restrict__ gat_W0,
    const float* __restrict__ gat_W1, const float* __restrict__ sel_W,
    const float* __restrict__ cond_W, const float* __restrict__ last_W,
    const float* __restrict__ selF_W,
    unsigned short* __restrict__ W0t, unsigned short* __restrict__ emW0t,
    unsigned short* __restrict__ W1t, unsigned short* __restrict__ g0t,
    unsigned short* __restrict__ g1t, unsigned short* __restrict__ selWt,
    unsigned short* __restrict__ condWt, unsigned short* __restrict__ lastWt,
    unsigned short* __restrict__ selFt, float* __restrict__ stats)
{
  __shared__ float t[32][33];
  int bid = blockIdx.x;
  const int tid = threadIdx.x;
  const int tx = tid & 31, ty = tid >> 5;

  if (bid < 496) {
    const float* src; unsigned short* dst; int K, N, KP, gx, local;
    if (bid < 64)       { src = base_W0; dst = W0t;   K = 128; N = 400; KP = 128; gx = 4;  local = bid; }
    else if (bid < 128) { src = em_W0;   dst = emW0t; K = 128; N = 400; KP = 128; gx = 4;  local = bid - 64; }
    else if (bid < 232) { src = base_W1; dst = W1t;   K = 400; N = 256; KP = 416; gx = 13; local = bid - 128; }
    else if (bid < 336) { src = gat_W0;  dst = g0t;   K = 400; N = 256; KP = 416; gx = 13; local = bid - 232; }
    else if (bid < 400) { src = gat_W1;  dst = g1t;   K = 256; N = 256; KP = 256; gx = 8;  local = bid - 336; }
    else if (bid < 448) {
      const int i = (bid - 400) / 16;
      src = sel_W + i * 16384; dst = selWt + i * 16384;
      K = 256; N = 64; KP = 256; gx = 8; local = (bid - 400) % 16;
    } else {
      const int i = (bid - 448) / 16;
      src = cond_W + i * 16384; dst = condWt + i * 16384;
      K = 64; N = 256; KP = 64; gx = 2; local = (bid - 448) % 16;
    }
    const int k0 = (local % gx) * 32, n0 = (local / gx) * 32;
    #pragma unroll
    for (int p = 0; p < 4; ++p) {
      const int k = k0 + ty + p * 8;
      t[ty + p * 8][tx] = (k < K && n0 + tx < N) ? src[(size_t)k * N + n0 + tx] : 0.f;
    }
    __syncthreads();
    #pragma unroll
    for (int p = 0; p < 4; ++p) {
      const int n = n0 + ty + p * 8;
      dst[(size_t)n * KP + k0 + tx] = f2bf(t[tx][ty + p * 8]);
    }
    return;
  }
  bid -= 496;

  if (bid < 8) {
    const int k0 = bid * 32;
    #pragma unroll
    for (int p = 0; p < 4; ++p)
      t[ty + p * 8][tx] = (tx < 18) ? last_W[(size_t)(k0 + ty + p * 8) * 18 + tx] : 0.f;
    __syncthreads();
    #pragma unroll
    for (int p = 0; p < 4; ++p) {
      const int n = ty + p * 8;
      lastWt[(size_t)n * 256 + k0 + tx] = f2bf(t[tx][n]);
      lastWt[(size_t)(n + 32) * 256 + k0 + tx] = 0;
    }
    return;
  }
  bid -= 8;

  if (bid == 0) {  // selFt: [256][8] f32 -> bf16 [16][256] (rows 8..15 zero)
    const int k = tid;
    #pragma unroll
    for (int j = 0; j < 8; ++j) selFt[j * 256 + k] = f2bf(selF_W[k * 8 + j]);
    #pragma unroll
    for (int j = 8; j < 16; ++j) selFt[j * 256 + k] = 0;
    return;
  }

  for (int i = tid; i < 4608; i += 256) stats[i] = 0.f;
}

// ---------------------------------------------------------------------------
// W0 GEMM (fp32 A, converted during reg->LDS staging). grid (4, 128, 2).
__global__ __launch_bounds__(256) void gemm_w0(
    const float* __restrict__ Ax, const float* __restrict__ Ae,
    const unsigned short* __restrict__ Wx, const unsigned short* __restrict__ We,
    const float* __restrict__ bx, const float* __restrict__ be,
    unsigned short* __restrict__ Cx, unsigned short* __restrict__ Ce)
{
  __shared__ unsigned short As[128 * 32];
  __shared__ unsigned short Bs[128 * 32];
  const float* Ap = blockIdx.z ? Ae : Ax;
  const unsigned short* Wp = blockIdx.z ? We : Wx;
  const float* bp = blockIdx.z ? be : bx;
  unsigned short* Cp = blockIdx.z ? Ce : Cx;
  const int row0 = blockIdx.y * 128;
  const int n0 = blockIdx.x * 128;
  const int tid = threadIdx.x;
  const int wid = tid >> 6, lane = tid & 63;
  const int wr = wid >> 1, wc = wid & 1;
  const int arow = tid >> 2, kcol = (tid & 3) * 8;
  const int lr = lane & 15, lk = (lane >> 4) * 8;
  const int lrow = (lane >> 4) * 4;

  f32x4 acc[4][4] = {};
  for (int k0 = 0; k0 < 128; k0 += 32) {
    {
      const float4* s1 = reinterpret_cast<const float4*>(
          Ap + (size_t)(row0 + arow) * 128 + k0 + kcol);
      uint4 w1 = {pack2(s1[0].x, s1[0].y), pack2(s1[0].z, s1[0].w),
                  pack2(s1[1].x, s1[1].y), pack2(s1[1].z, s1[1].w)};
      *reinterpret_cast<uint4*>(&As[arow * 32 + kcol]) = w1;
      const float4* s2 = reinterpret_cast<const float4*>(
          Ap + (size_t)(row0 + 64 + arow) * 128 + k0 + kcol);
      uint4 w2 = {pack2(s2[0].x, s2[0].y), pack2(s2[0].z, s2[0].w),
                  pack2(s2[1].x, s2[1].y), pack2(s2[1].z, s2[1].w)};
      *reinterpret_cast<uint4*>(&As[(64 + arow) * 32 + kcol]) = w2;
    }
    gload_lds16(Wp + (size_t)(n0 + arow) * 128 + k0 + kcol, (char*)Bs + tid * 16);
    gload_lds16(Wp + (size_t)(n0 + 64 + arow) * 128 + k0 + kcol,
                (char*)Bs + 4096 + tid * 16);
    __syncthreads();
    bf16x8 a[4], b[4];
    #pragma unroll
    for (int i = 0; i < 4; ++i)
      a[i] = *reinterpret_cast<const bf16x8*>(&As[(wr * 64 + i * 16 + lr) * 32 + lk]);
    #pragma unroll
    for (int j = 0; j < 4; ++j)
      b[j] = *reinterpret_cast<const bf16x8*>(&Bs[(wc * 64 + j * 16 + lr) * 32 + lk]);
    #pragma unroll
    for (int i = 0; i < 4; ++i)
      #pragma unroll
      for (int j = 0; j < 4; ++j)
        acc[i][j] = __builtin_amdgcn_mfma_f32_16x16x32_bf16(a[i], b[j], acc[i][j], 0, 0, 0);
    __syncthreads();
  }
  #pragma unroll
  for (int j = 0; j < 4; ++j) {
    const int col = n0 + wc * 64 + j * 16 + lr;
    if (col >= 416) continue;
    const bool real = col < 400;
    const float bv = real ? bp[col] : 0.f;
    #pragma unroll
    for (int i = 0; i < 4; ++i) {
      #pragma unroll
      for (int r = 0; r < 4; ++r) {
        const int row = row0 + wr * 64 + i * 16 + lrow + r;
        float v = real ? fmaxf(acc[i][j][r] + bv, 0.f) : 0.f;
        Cp[(size_t)row * 416 + col] = f2bf(v);
      }
    }
  }
}

// ---------------------------------------------------------------------------
// Batched mid GEMM: z=0: out = h1 @ W1t + b1 (raw, bn1 stats);
//                   z=1: si = relu(h1e @ g0t + gb0). BN=64, WM=4, K=416.
__global__ __launch_bounds__(256) void gemm_mid(
    const unsigned short* __restrict__ A0, const unsigned short* __restrict__ W0,
    const float* __restrict__ b0, unsigned short* __restrict__ C0,
    const unsigned short* __restrict__ A1, const unsigned short* __restrict__ W1,
    const float* __restrict__ b1, unsigned short* __restrict__ C1,
    float* __restrict__ sum, float* __restrict__ sumsq)
{
  __shared__ unsigned short As[128 * 32];
  __shared__ unsigned short Bs[64 * 32];
  const bool z1 = blockIdx.z != 0;
  const unsigned short* A = z1 ? A1 : A0;
  const unsigned short* Wt = z1 ? W1 : W0;
  const float* bias = z1 ? b1 : b0;
  unsigned short* C = z1 ? C1 : C0;
  const int row0 = blockIdx.y * 128;
  const int n0 = blockIdx.x * 64;
  const int tid = threadIdx.x;
  const int wid = tid >> 6, lane = tid & 63;
  const int arow = tid >> 2, kcol = (tid & 3) * 8;
  const int lr = lane & 15, lk = (lane >> 4) * 8;
  const int lrow = (lane >> 4) * 4;

  f32x4 acc[2][4] = {};
  for (int k0 = 0; k0 < 416; k0 += 32) {
    gload_lds16(A + (size_t)(row0 + arow) * 416 + k0 + kcol, (char*)As + tid * 16);
    gload_lds16(A + (size_t)(row0 + 64 + arow) * 416 + k0 + kcol, (char*)As + 4096 + tid * 16);
    gload_lds16(Wt + (size_t)(n0 + arow) * 416 + k0 + kcol, (char*)Bs + tid * 16);
    __syncthreads();
    bf16x8 a[2], b[4];
    #pragma unroll
    for (int i = 0; i < 2; ++i)
      a[i] = *reinterpret_cast<const bf16x8*>(&As[(wid * 32 + i * 16 + lr) * 32 + lk]);
    #pragma unroll
    for (int j = 0; j < 4; ++j)
      b[j] = *reinterpret_cast<const bf16x8*>(&Bs[(j * 16 + lr) * 32 + lk]);
    #pragma unroll
    for (int i = 0; i < 2; ++i)
      #pragma unroll
      for (int j = 0; j < 4; ++j)
        acc[i][j] = __builtin_amdgcn_mfma_f32_16x16x32_bf16(a[i], b[j], acc[i][j], 0, 0, 0);
    __syncthreads();
  }
  #pragma unroll
  for (int j = 0; j < 4; ++j) {
    const int col = n0 + j * 16 + lr;
    const float bv = bias[col];
    float s = 0.f, q = 0.f;
    #pragma unroll
    for (int i = 0; i < 2; ++i) {
      #pragma unroll
      for (int r = 0; r < 4; ++r) {
        const int row = row0 + wid * 32 + i * 16 + lrow + r;
        float v = acc[i][j][r] + bv;
        if (z1) v = fmaxf(v, 0.f);
        const unsigned short hv = f2bf(v);
        C[(size_t)row * 256 + col] = hv;
        if (!z1) {
          const float vr = bf2f(hv);
          s += vr;
          q = fmaf(vr, vr, q);
        }
      }
    }
    if (!z1) {
      s += __shfl_xor(s, 16); s += __shfl_xor(s, 32);
      q += __shfl_xor(q, 16); q += __shfl_xor(q, 32);
      if (lane < 16) {
        atomicAdd(&sum[col], s);
        atomicAdd(&sumsq[col], q);
      }
    }
  }
}

// ---------------------------------------------------------------------------
// Generic bf16 MFMA GEMM (used for g1). BM=128, BK=32.
template<int BN, int WM, int WN, int EPI, bool RELU_A>
__global__ __launch_bounds__(256) void gemm_bf16(
    const unsigned short* __restrict__ A, int AS,
    const unsigned short* __restrict__ Wt, const float* __restrict__ bias,
    unsigned short* __restrict__ C, int CS, int Nreal, int NP, int K,
    const unsigned short* __restrict__ emb,
    float* __restrict__ sum, float* __restrict__ sumsq)
{
  constexpr int FRAG_M = 128 / WM / 16;
  constexpr int FRAG_N = BN / WN / 16;
  __shared__ unsigned short As[128 * 32];
  __shared__ unsigned short Bs[BN * 32];
  const int row0 = blockIdx.y * 128;
  const int n0 = blockIdx.x * BN;
  const int tid = threadIdx.x;
  const int wid = tid >> 6, lane = tid & 63;
  const int wr = wid / WN, wc = wid % WN;
  const int arow = tid >> 2;
  const int kcol = (tid & 3) * 8;
  const int lr = lane & 15, lk = (lane >> 4) * 8;
  const int lrow = (lane >> 4) * 4;

  f32x4 acc[FRAG_M][FRAG_N] = {};
  for (int k0 = 0; k0 < K; k0 += 32) {
    gload_lds16(A + (size_t)(row0 + arow) * AS + k0 + kcol, (char*)As + tid * 16);
    gload_lds16(A + (size_t)(row0 + 64 + arow) * AS + k0 + kcol, (char*)As + 4096 + tid * 16);
    gload_lds16(Wt + (size_t)(n0 + arow) * K + k0 + kcol, (char*)Bs + tid * 16);
    if constexpr (BN == 128)
      gload_lds16(Wt + (size_t)(n0 + 64 + arow) * K + k0 + kcol, (char*)Bs + 4096 + tid * 16);
    __syncthreads();
    bf16x8 a[FRAG_M], b[FRAG_N];
    #pragma unroll
    for (int i = 0; i < FRAG_M; ++i) {
      a[i] = *reinterpret_cast<const bf16x8*>(&As[(wr * (128 / WM) + i * 16 + lr) * 32 + lk]);
      if (RELU_A) a[i] = relu_bf8(a[i]);
    }
    #pragma unroll
    for (int j = 0; j < FRAG_N; ++j)
      b[j] = *reinterpret_cast<const bf16x8*>(&Bs[(wc * (BN / WN) + j * 16 + lr) * 32 + lk]);
    #pragma unroll
    for (int i = 0; i < FRAG_M; ++i)
      #pragma unroll
      for (int j = 0; j < FRAG_N; ++j)
        acc[i][j] = __builtin_amdgcn_mfma_f32_16x16x32_bf16(a[i], b[j], acc[i][j], 0, 0, 0);
    __syncthreads();
  }
  #pragma unroll
  for (int j = 0; j < FRAG_N; ++j) {
    const int col = n0 + wc * (BN / WN) + j * 16 + lr;
    if (col >= NP) continue;
    const bool real = col < Nreal;
    const float bv = real ? bias[col] : 0.f;
    float s = 0.f, q = 0.f;
    #pragma unroll
    for (int i = 0; i < FRAG_M; ++i) {
      #pragma unroll
      for (int r = 0; r < 4; ++r) {
        const int row = row0 + wr * (128 / WM) + i * 16 + lrow + r;
        float v = acc[i][j][r] + bv;
        if (EPI == EPI_RELU) v = fmaxf(v, 0.f);
        if (!real) v = 0.f;
        const unsigned short hv = f2bf(v);
        C[(size_t)row * CS + col] = hv;
        if (EPI == EPI_STATS) {
          const float vr = bf2f(hv);
          s += vr;
          q = fmaf(vr, vr, q);
        }
      }
    }
    if (EPI == EPI_STATS) {
      s += __shfl_xor(s, 16); s += __shfl_xor(s, 32);
      q += __shfl_xor(q, 16); q += __shfl_xor(q, 32);
      if (lane < 16) {
        atomicAdd(&sum[col], s);
        atomicAdd(&sumsq[col], q);
      }
    }
  }
}

// ---------------------------------------------------------------------------
// Mod-einsum GEMM v3: R11 structure + XCD swizzle + LDS XOR swizzle (2-way)
// + Cs store staging with chunk-permuted coalesced stores.
__global__ __launch_bounds__(256) void gemm_mod(
    const unsigned short* __restrict__ A,    // out_bf [16384][256]
    const unsigned short* __restrict__ Wt,   // modWt [2048][256]
    const float* __restrict__ bias, unsigned short* __restrict__ C,
    float* __restrict__ sum, float* __restrict__ sumsq)
{
  __shared__ unsigned short As[128 * 32];
  __shared__ unsigned short Bs[128 * 32];
  __shared__ unsigned short Cs[128 * 136];
  const int lin = blockIdx.x;
  const int swz = (lin & 7) * 256 + (lin >> 3);
  const int row0 = (swz >> 4) * 128;
  const int n0 = (swz & 15) * 128;
  const int tid = threadIdx.x;
  const int wid = tid >> 6, lane = tid & 63;
  const int wr = wid >> 1, wc = wid & 1;
  const int arow = tid >> 2;
  const int lr = lane & 15, hi = lane >> 4;
  const int s_lr = (lr + (lr >> 2)) & 3;               // read-side XOR key
  const int cswz = ((tid & 3) ^ ((arow + (arow >> 2)) & 3)) * 8;  // staging key

  f32x4 acc[4][4] = {};
  for (int k0 = 0; k0 < 256; k0 += 32) {
    gload_lds16(A + (size_t)(row0 + arow) * 256 + k0 + cswz, (char*)As + tid * 16);
    gload_lds16(A + (size_t)(row0 + 64 + arow) * 256 + k0 + cswz, (char*)As + 4096 + tid * 16);
    gload_lds16(Wt + (size_t)(n0 + arow) * 256 + k0 + cswz, (char*)Bs + tid * 16);
    gload_lds16(Wt + (size_t)(n0 + 64 + arow) * 256 + k0 + cswz, (char*)Bs + 4096 + tid * 16);
    __syncthreads();
    const int rchunk = (hi ^ s_lr) * 8;
    bf16x8 a[4], b[4];
    #pragma unroll
    for (int i = 0; i < 4; ++i)
      a[i] = *reinterpret_cast<const bf16x8*>(&As[(wr * 64 + i * 16 + lr) * 32 + rchunk]);
    #pragma unroll
    for (int j = 0; j < 4; ++j)
      b[j] = *reinterpret_cast<const bf16x8*>(&Bs[(wc * 64 + j * 16 + lr) * 32 + rchunk]);
    #pragma unroll
    for (int i = 0; i < 4; ++i)
      #pragma unroll
      for (int j = 0; j < 4; ++j)
        acc[i][j] = __builtin_amdgcn_mfma_f32_16x16x32_bf16(a[i], b[j], acc[i][j], 0, 0, 0);
    __syncthreads();
  }

  // Epilogue: bias + quantize -> Cs; fused bn2 stats.
  #pragma unroll
  for (int j = 0; j < 4; ++j) {
    const int col = n0 + wc * 64 + j * 16 + lr;
    const float bv = bias[col];
    float s = 0.f, q = 0.f;
    #pragma unroll
    for (int i = 0; i < 4; ++i) {
      #pragma unroll
      for (int r = 0; r < 4; ++r) {
        const unsigned short hv = f2bf(acc[i][j][r] + bv);
        Cs[(wr * 64 + i * 16 + hi * 4 + r) * 136 + wc * 64 + j * 16 + lr] = hv;
        const float vr = bf2f(hv);
        s += vr;
        q = fmaf(vr, vr, q);
      }
    }
    s += __shfl_xor(s, 16); s += __shfl_xor(s, 32);
    q += __shfl_xor(q, 16); q += __shfl_xor(q, 32);
    if (lane < 16) {
      atomicAdd(&sum[col], s);
      atomicAdd(&sumsq[col], q);
    }
  }
  __syncthreads();
  // Coalesced stores; chunk assignment permuted by row to avoid Cs-read conflicts.
  const int colbase = n0;
  const int qrow = tid >> 2;
  const int qc = (((tid & 3) ^ qrow) & 3) * 32;
  #pragma unroll
  for (int pass = 0; pass < 2; ++pass) {
    const int row = pass * 64 + qrow;
    #pragma unroll
    for (int v = 0; v < 4; ++v) {
      const uint4 d = *reinterpret_cast<const uint4*>(&Cs[row * 136 + qc + v * 8]);
      *reinterpret_cast<uint4*>(&C[(size_t)(row0 + row) * 2048 + colbase + qc + v * 8]) = d;
    }
  }
}

// ---------------------------------------------------------------------------
// Fused select iteration (R11-proven).
template<bool RELU_A>
__global__ __launch_bounds__(256) void fused_select(
    const unsigned short* __restrict__ A, const unsigned short* __restrict__ selWt,
    const float* __restrict__ selb, const unsigned short* __restrict__ condWt,
    const float* __restrict__ condb, const unsigned short* __restrict__ emb,
    const float* __restrict__ u, int u_off,
    float* __restrict__ gs, unsigned short* __restrict__ siout)
{
  __shared__ unsigned short As[128 * 32];
  __shared__ unsigned short Bs[64 * 32];
  __shared__ unsigned short Ls[128 * 72];
  const int tid = threadIdx.x;
  const int wid = tid >> 6, lane = tid & 63;
  const int lr = lane & 15, hi = lane >> 4;
  const int lk = hi * 8;
  const int row0 = blockIdx.x * 128;
  const int arow = tid >> 2, kcol = (tid & 3) * 8;

  {
    f32x4 acc[2][4] = {};
    for (int k0 = 0; k0 < 256; k0 += 32) {
      gload_lds16(A + (size_t)(row0 + arow) * 256 + k0 + kcol, (char*)As + tid * 16);
      gload_lds16(A + (size_t)(row0 + 64 + arow) * 256 + k0 + kcol, (char*)As + 4096 + tid * 16);
      gload_lds16(selWt + (size_t)arow * 256 + k0 + kcol, (char*)Bs + tid * 16);
      __syncthreads();
      bf16x8 a[2], b[4];
      #pragma unroll
      for (int i = 0; i < 2; ++i) {
        a[i] = *reinterpret_cast<const bf16x8*>(&As[(wid * 32 + i * 16 + lr) * 32 + lk]);
        if (RELU_A) a[i] = relu_bf8(a[i]);
      }
      #pragma unroll
      for (int j = 0; j < 4; ++j)
        b[j] = *reinterpret_cast<const bf16x8*>(&Bs[(j * 16 + lr) * 32 + lk]);
      #pragma unroll
      for (int i = 0; i < 2; ++i)
        #pragma unroll
        for (int j = 0; j < 4; ++j)
          acc[i][j] = __builtin_amdgcn_mfma_f32_16x16x32_bf16(a[i], b[j], acc[i][j], 0, 0, 0);
      __syncthreads();
    }
    #pragma unroll
    for (int j = 0; j < 4; ++j) {
      const int col = j * 16 + lr;
      const float bv = selb[col];
      #pragma unroll
      for (int i = 0; i < 2; ++i)
        #pragma unroll
        for (int r = 0; r < 4; ++r) {
          const int row = wid * 32 + i * 16 + hi * 4 + r;
          Ls[row * 72 + col] = f2bf(tanhf(acc[i][j][r] + bv));
        }
    }
  }
  __syncthreads();

  #pragma unroll
  for (int p = 0; p < 4; ++p) {
    const int pair = p * 256 + tid;
    const int bl = pair >> 3, mm = pair & 7;
    const int bg = row0 + bl;
    float v[8];
    #pragma unroll
    for (int jj = 0; jj < 8; ++jj) v[jj] = bf2f(Ls[bl * 72 + mm * 8 + jj]);
    const float* up = u + (size_t)bg * 192 + u_off + mm * 8;
    #pragma unroll
    for (int jj = 0; jj < 8; ++jj) {
      const float uu = fminf(fmaxf(up[jj], 1e-10f), 0.9999999f);
      v[jj] -= logf(-logf(uu));
    }
    float mx = v[0];
    #pragma unroll
    for (int jj = 1; jj < 8; ++jj) mx = fmaxf(mx, v[jj]);
    float s = 0.f;
    #pragma unroll
    for (int jj = 0; jj < 8; ++jj) { v[jj] = expf(v[jj] - mx); s += v[jj]; }
    const float inv = 1.f / s;
    float* op = gs + (size_t)bg * 64 + mm * 8;
    #pragma unroll
    for (int jj = 0; jj < 8; ++jj) op[jj] = v[jj] * inv;
  }

  {
    const int wr2 = wid >> 1, wc2 = wid & 1;
    f32x4 acc2[4][8] = {};
    #pragma unroll
    for (int kq = 0; kq < 2; ++kq) {
      const int k0 = kq * 32;
      bf16x8 a2[4];
      #pragma unroll
      for (int i = 0; i < 4; ++i)
        a2[i] = *reinterpret_cast<const bf16x8*>(
            &Ls[(wr2 * 64 + i * 16 + lr) * 72 + k0 + hi * 8]);
      #pragma unroll
      for (int j = 0; j < 8; ++j) {
        const bf16x8 b2 = *reinterpret_cast<const bf16x8*>(
            condWt + (size_t)(wc2 * 128 + j * 16 + lr) * 64 + k0 + hi * 8);
        #pragma unroll
        for (int i = 0; i < 4; ++i)
          acc2[i][j] = __builtin_amdgcn_mfma_f32_16x16x32_bf16(a2[i], b2, acc2[i][j], 0, 0, 0);
      }
    }
    #pragma unroll
    for (int j = 0; j < 8; ++j) {
      const int col = wc2 * 128 + j * 16 + lr;
      const float bv = condb[col];
      #pragma unroll
      for (int i = 0; i < 4; ++i)
        #pragma unroll
        for (int r = 0; r < 4; ++r) {
          const int row = row0 + wr2 * 64 + i * 16 + hi * 4 + r;
          float vv = (acc2[i][j][r] + bv) * bf2f(emb[(size_t)row * 256 + col]);
          siout[(size_t)row * 256 + col] = f2bf(fmaxf(vv, 0.f));
        }
    }
  }
}

// ---------------------------------------------------------------------------
// Final select: MFMA GEMM (K=256, N=16 pad, 8 real) + gumbel epilogue.
// grid (1, 128).
__global__ __launch_bounds__(256) void gemm_fsel(
    const unsigned short* __restrict__ A, const unsigned short* __restrict__ Wt,
    const float* __restrict__ bias, const float* __restrict__ u,
    float* __restrict__ fs)
{
  __shared__ unsigned short As[128 * 32];
  __shared__ unsigned short Bs[16 * 32];
  const int row0 = blockIdx.y * 128;
  const int tid = threadIdx.x;
  const int wid = tid >> 6, lane = tid & 63;
  const int arow = tid >> 2, kcol = (tid & 3) * 8;
  const int lr = lane & 15, hi = lane >> 4;
  const int lk = hi * 8;

  f32x4 acc[2] = {};
  for (int k0 = 0; k0 < 256; k0 += 32) {
    gload_lds16(A + (size_t)(row0 + arow) * 256 + k0 + kcol, (char*)As + tid * 16);
    gload_lds16(A + (size_t)(row0 + 64 + arow) * 256 + k0 + kcol, (char*)As + 4096 + tid * 16);
    if (wid == 0)
      gload_lds16(Wt + (size_t)(lane >> 2) * 256 + k0 + (lane & 3) * 8, (char*)Bs + lane * 16);
    __syncthreads();
    bf16x8 a[2];
    #pragma unroll
    for (int i = 0; i < 2; ++i)
      a[i] = *reinterpret_cast<const bf16x8*>(&As[(wid * 32 + i * 16 + lr) * 32 + lk]);
    const bf16x8 b = *reinterpret_cast<const bf16x8*>(&Bs[lr * 32 + lk]);
    #pragma unroll
    for (int i = 0; i < 2; ++i)
      acc[i] = __builtin_amdgcn_mfma_f32_16x16x32_bf16(a[i], b, acc[i], 0, 0, 0);
    __syncthreads();
  }
  const float bv = (lr < 8) ? bias[lr] : 0.f;
  #pragma unroll
  for (int i = 0; i < 2; ++i) {
    #pragma unroll
    for (int r = 0; r < 4; ++r) {
      const int row = row0 + wid * 32 + i * 16 + hi * 4 + r;
      float v = acc[i][r] + bv;
      if (lr < 8) {
        const float uu = fminf(fmaxf(u[(size_t)row * 8 + lr], 1e-10f), 0.9999999f);
        v -= logf(-logf(uu));
      }
      float mx = v;
      mx = fmaxf(mx, __shfl_xor(mx, 1));
      mx = fmaxf(mx, __shfl_xor(mx, 2));
      mx = fmaxf(mx, __shfl_xor(mx, 4));
      const float e = expf(v - mx);
      float ssum = e;
      ssum += __shfl_xor(ssum, 1);
      ssum += __shfl_xor(ssum, 2);
      ssum += __shfl_xor(ssum, 4);
      if (lr < 8) fs[(size_t)row * 8 + lr] = e / ssum;
    }
  }
}

// ---------------------------------------------------------------------------
// Fold mod weights with inline bn1 finalize. grid (8, 8, 9).
__global__ __launch_bounds__(256) void fold_modw_all(
    const float* __restrict__ W, const float* __restrict__ g1,
    const float* __restrict__ b1, const float* __restrict__ modb,
    const float* __restrict__ sum1, const float* __restrict__ sumsq1,
    unsigned short* __restrict__ Wt, float* __restrict__ bias2)
{
  const float invB = 1.f / 16384.f;
  if (blockIdx.z == 8) {
    if (blockIdx.y != 0) return;
    const int m = blockIdx.x, h = threadIdx.x;
    float acc = modb[m * 256 + h];
    for (int d = 0; d < 256; ++d) {
      const float mean = sum1[d] * invB;
      const float var = sumsq1[d] * invB - mean * mean;
      const float r = rsqrtf(var + 1e-5f);
      const float c = b1[m * 256 + d] - mean * r * g1[m * 256 + d];
      acc = fmaf(c, W[((size_t)m * 256 + d) * 256 + h], acc);
    }
    bias2[m * 256 + h] = acc;
    return;
  }
  __shared__ float t[32][33];
  const int m = blockIdx.z, d0 = blockIdx.y * 32, h0 = blockIdx.x * 32;
  const int tx = threadIdx.x & 31, ty = threadIdx.x >> 5;
  #pragma unroll
  for (int p = 0; p < 4; ++p) {
    const int d = d0 + ty + p * 8;
    const float mean = sum1[d] * invB;
    const float var = sumsq1[d] * invB - mean * mean;
    const float r = rsqrtf(var + 1e-5f);
    t[ty + p * 8][tx] = W[((size_t)m * 256 + d) * 256 + h0 + tx] * r * g1[m * 256 + d];
  }
  __syncthreads();
  #pragma unroll
  for (int p = 0; p < 4; ++p) {
    const int h = h0 + ty + p * 8;
    Wt[((size_t)m * 256 + h) * 256 + d0 + tx] = f2bf(t[tx][ty + p * 8]);
  }
}

// bn2 finalize.
__global__ void finalize_bn2(const float* __restrict__ sum, const float* __restrict__ sumsq,
                             const float* __restrict__ g, const float* __restrict__ b,
                             float* __restrict__ scale, float* __restrict__ shift)
{
  const int i = blockIdx.x * 256 + threadIdx.x;
  const float invB = 1.f / 16384.f;
  const float m = sum[i] * invB;
  const float v = sumsq[i] * invB - m * m;
  const float r = rsqrtf(v + 1e-5f);
  const float sc = r * g[i];
  scale[i] = sc;
  shift[i] = b[i] - m * sc;
}

// ---------------------------------------------------------------------------
// Cascade (R5-proven).
__global__ __launch_bounds__(256) void final_cascade(
    const unsigned short* __restrict__ H, const float* __restrict__ scale2,
    const float* __restrict__ shift2, const float* __restrict__ gs0,
    const float* __restrict__ gs1, const float* __restrict__ gs2,
    const float* __restrict__ fs, unsigned short* __restrict__ ovec)
{
  const int wave = threadIdx.x >> 6, lane = threadIdx.x & 63;
  const int b = __builtin_amdgcn_readfirstlane(blockIdx.x * 4 + wave);
  const int c0 = lane << 2;

  float prev[8][4];
  #pragma unroll
  for (int m = 0; m < 8; ++m) {
    const int gc = m * 256 + c0;
    const ushort4 h = *reinterpret_cast<const ushort4*>(&H[(size_t)b * 2048 + gc]);
    const float4 sc = *reinterpret_cast<const float4*>(&scale2[gc]);
    const float4 sh = *reinterpret_cast<const float4*>(&shift2[gc]);
    prev[m][0] = bf2f(h.x) * sc.x + sh.x;
    prev[m][1] = bf2f(h.y) * sc.y + sh.y;
    prev[m][2] = bf2f(h.z) * sc.z + sh.z;
    prev[m][3] = bf2f(h.w) * sc.w + sh.w;
  }

  const float* sel0 = gs2 + (size_t)b * 64;
  const float* sel1 = gs1 + (size_t)b * 64;
  const float* sel2 = gs0 + (size_t)b * 64;
  #pragma unroll
  for (int l = 0; l < 3; ++l) {
    const float* sp = (l == 0) ? sel0 : (l == 1) ? sel1 : sel2;
    float nw[8][4];
    #pragma unroll
    for (int m = 0; m < 8; ++m) {
      float a0 = 0.f, a1 = 0.f, a2 = 0.f, a3 = 0.f;
      #pragma unroll
      for (int k = 0; k < 8; ++k) {
        const float s = sp[m * 8 + k];
        a0 = fmaf(s, prev[k][0], a0);
        a1 = fmaf(s, prev[k][1], a1);
        a2 = fmaf(s, prev[k][2], a2);
        a3 = fmaf(s, prev[k][3], a3);
      }
      nw[m][0] = fmaxf(a0, 0.f); nw[m][1] = fmaxf(a1, 0.f);
      nw[m][2] = fmaxf(a2, 0.f); nw[m][3] = fmaxf(a3, 0.f);
    }
    #pragma unroll
    for (int m = 0; m < 8; ++m)
      #pragma unroll
      for (int c = 0; c < 4; ++c)
        prev[m][c] = nw[m][c];
  }

  const float* fp = fs + (size_t)b * 8;
  float ov[4] = {0.f, 0.f, 0.f, 0.f};
  #pragma unroll
  for (int m = 0; m < 8; ++m) {
    const float s = fp[m];
    ov[0] = fmaf(s, prev[m][0], ov[0]);
    ov[1] = fmaf(s, prev[m][1], ov[1]);
    ov[2] = fmaf(s, prev[m][2], ov[2]);
    ov[3] = fmaf(s, prev[m][3], ov[3]);
  }
  ushort4 o;
  o.x = f2bf(ov[0]); o.y = f2bf(ov[1]); o.z = f2bf(ov[2]); o.w = f2bf(ov[3]);
  *reinterpret_cast<ushort4*>(&ovec[(size_t)b * 256 + c0]) = o;
}

// ---------------------------------------------------------------------------
// Last GEMM (R5-proven).
__global__ __launch_bounds__(256) void gemm_last(
    const unsigned short* __restrict__ A, const unsigned short* __restrict__ Wt,
    const float* __restrict__ bias, float* __restrict__ out)
{
  __shared__ unsigned short As[128 * 32];
  __shared__ unsigned short Bs[64 * 32];
  const int row0 = blockIdx.y * 128;
  const int tid = threadIdx.x;
  const int wid = tid >> 6, lane = tid & 63;
  const int arow = tid >> 2;
  const int kcol = (tid & 3) * 8;
  const int lr = lane & 15, lk = (lane >> 4) * 8;
  const int lrow = (lane >> 4) * 4;

  f32x4 acc[2][4] = {};
  for (int k0 = 0; k0 < 256; k0 += 32) {
    gload_lds16(A + (size_t)(row0 + arow) * 256 + k0 + kcol, (char*)As + tid * 16);
    gload_lds16(A + (size_t)(row0 + 64 + arow) * 256 + k0 + kcol, (char*)As + 4096 + tid * 16);
    gload_lds16(Wt + (size_t)arow * 256 + k0 + kcol, (char*)Bs + tid * 16);
    __syncthreads();
    bf16x8 a[2], b[4];
    #pragma unroll
    for (int i = 0; i < 2; ++i)
      a[i] = *reinterpret_cast<const bf16x8*>(&As[(wid * 32 + i * 16 + lr) * 32 + lk]);
    #pragma unroll
    for (int j = 0; j < 4; ++j)
      b[j] = *reinterpret_cast<const bf16x8*>(&Bs[(j * 16 + lr) * 32 + lk]);
    #pragma unroll
    for (int i = 0; i < 2; ++i)
      #pragma unroll
      for (int j = 0; j < 4; ++j)
        acc[i][j] = __builtin_amdgcn_mfma_f32_16x16x32_bf16(a[i], b[j], acc[i][j], 0, 0, 0);
    __syncthreads();
  }
  #pragma unroll
  for (int j = 0; j < 2; ++j) {
    const int col = j * 16 + lr;
    if (col >= 18) continue;
    const float bv = bias[col];
    #pragma unroll
    for (int i = 0; i < 2; ++i) {
      #pragma unroll
      for (int r = 0; r < 4; ++r) {
        const int row = row0 + wid * 32 + i * 16 + lrow + r;
        out[(size_t)row * 18 + col] = acc[i][j][r] + bv;
      }
    }
  }
}

extern "C" void kernel_launch(void* const* d_in, const int* in_sizes, int n_in,
                              void* d_out, int out_size, void* d_ws, size_t ws_size,
                              hipStream_t stream)
{
  (void)in_sizes; (void)n_in; (void)out_size; (void)ws_size;
  const float* x       = (const float*)d_in[0];
  const float* embi    = (const float*)d_in[1];
  const float* u_sel   = (const float*)d_in[2];
  const float* u_fin   = (const float*)d_in[3];
  const float* base_W0 = (const float*)d_in[4];
  const float* base_b0 = (const float*)d_in[5];
  const float* base_W1 = (const float*)d_in[6];
  const float* base_b1 = (const float*)d_in[7];
  const float* em_W0   = (const float*)d_in[8];
  const float* em_b0   = (const float*)d_in[9];
  const float* gat_W0  = (const float*)d_in[10];
  const float* gat_b0  = (const float*)d_in[11];
  const float* gat_W1  = (const float*)d_in[12];
  const float* gat_b1  = (const float*)d_in[13];
  const float* sel_W   = (const float*)d_in[14];
  const float* sel_b   = (const float*)d_in[15];
  const float* selF_W  = (const float*)d_in[16];
  const float* selF_b  = (const float*)d_in[17];
  const float* cond_W  = (const float*)d_in[18];
  const float* cond_b  = (const float*)d_in[19];
  const float* mod_W   = (const float*)d_in[20];
  const float* mod_b   = (const float*)d_in[21];
  const float* last_W  = (const float*)d_in[22];
  const float* last_b  = (const float*)d_in[23];
  const float* bn1_g   = (const float*)d_in[24];
  const float* bn1_b   = (const float*)d_in[25];
  const float* bn2_g   = (const float*)d_in[26];
  const float* bn2_b   = (const float*)d_in[27];

  // --- workspace layout (byte offsets) ---
  char* WSB = (char*)d_ws;
  unsigned short* h_big    = (unsigned short*)(WSB + 0);          // 16384x2048 bf16
  unsigned short* h1e      = (unsigned short*)(WSB + 67108864);   // 16384x416 (em)
  unsigned short* ovec_bf  = (unsigned short*)(WSB + 67108864);   // overlaps dead h1e
  unsigned short* h1       = (unsigned short*)(WSB + 81000448);   // 16384x416 (base)
  unsigned short* emb_bf   = (unsigned short*)(WSB + 103020544);  // 16384x256
  unsigned short* si_bf    = (unsigned short*)(WSB + 111409152);  // 16384x256
  unsigned short* out_bf   = (unsigned short*)(WSB + 119797760);  // 16384x256
  float* gs0   = (float*)(WSB + 130283520);  // 16384x64
  float* gs1   = (float*)(WSB + 134477824);
  float* gs2   = (float*)(WSB + 138672128);
  float* bufFs = (float*)(WSB + 142866432);  // 16384x8
  unsigned short* W0t   = (unsigned short*)(WSB + 143390720);  // 512x128
  unsigned short* emW0t = (unsigned short*)(WSB + 143521792);  // 512x128
  unsigned short* W1t   = (unsigned short*)(WSB + 143652864);  // 256x416
  unsigned short* g0t   = (unsigned short*)(WSB + 143865856);  // 256x416
  unsigned short* g1t   = (unsigned short*)(WSB + 144078848);  // 256x256
  unsigned short* selWt = (unsigned short*)(WSB + 144209920);  // 3x64x256
  unsigned short* condWt= (unsigned short*)(WSB + 144308224);  // 3x256x64
  unsigned short* modWt = (unsigned short*)(WSB + 144406528);  // 8x256x256
  float* bias2  = (float*)(WSB + 146503680);  // 2048
  float* stats  = (float*)(WSB + 146511872);  // 4608 floats
  unsigned short* lastWt = (unsigned short*)(WSB + 146530304); // 64x256 bf16
  float* scale2 = (float*)(WSB + 146563072);  // 2048
  float* shift2 = (float*)(WSB + 146571264);  // 2048
  unsigned short* selFt = (unsigned short*)(WSB + 146579456);  // 16x256 bf16
  float* sum1   = stats;        float* sumsq1 = stats + 256;
  float* sum2   = stats + 512;  float* sumsq2 = stats + 2560;

  const dim3 blk(256);
  // prep (weight transposes + selFt + stats zero)
  prep_all<<<dim3(506), blk, 0, stream>>>(
      base_W0, em_W0, base_W1, gat_W0, gat_W1, sel_W, cond_W, last_W, selF_W,
      W0t, emW0t, W1t, g0t, g1t, selWt, condWt, lastWt, selFt, stats);

  // batched W0 GEMMs from fp32 inputs
  gemm_w0<<<dim3(4, 128, 2), blk, 0, stream>>>(
      x, embi, W0t, emW0t, base_b0, em_b0, h1, h1e);
  // batched mid GEMMs: z=0 W1->out (bn1 stats), z=1 g0->si (relu)
  gemm_mid<<<dim3(4, 128, 2), blk, 0, stream>>>(
      h1, W1t, base_b1, out_bf, h1e, g0t, gat_b0, si_bf, sum1, sumsq1);
  // g1 -> emb
  gemm_bf16<64, 4, 1, EPI_NONE, false><<<dim3(4, 128), blk, 0, stream>>>(
      si_bf, 256, g1t, gat_b1, emb_bf, 256, 256, 256, 256, nullptr, nullptr, nullptr);
  // fused select loop
  fused_select<true><<<dim3(128), blk, 0, stream>>>(
      emb_bf, selWt, sel_b, condWt, cond_b, emb_bf, u_sel, 0, gs0, si_bf);
  fused_select<false><<<dim3(128), blk, 0, stream>>>(
      si_bf, selWt + 16384, sel_b + 64, condWt + 16384, cond_b + 256, emb_bf,
      u_sel, 64, gs1, si_bf);
  fused_select<false><<<dim3(128), blk, 0, stream>>>(
      si_bf, selWt + 32768, sel_b + 128, condWt + 32768, cond_b + 512, emb_bf,
      u_sel, 128, gs2, si_bf);
  // final select (MFMA)
  gemm_fsel<<<dim3(1, 128), blk, 0, stream>>>(si_bf, selFt, selF_b, u_fin, bufFs);
  // bn1 finalize + mod weight fold + bias2
  fold_modw_all<<<dim3(8, 8, 9), blk, 0, stream>>>(
      mod_W, bn1_g, bn1_b, mod_b, sum1, sumsq1, modWt, bias2);
  // mod einsum -> h_big (fused bn2 stats)
  gemm_mod<<<dim3(2048), blk, 0, stream>>>(out_bf, modWt, bias2, h_big, sum2, sumsq2);
  finalize_bn2<<<dim3(8), blk, 0, stream>>>(sum2, sumsq2, bn2_g, bn2_b, scale2, shift2);
  // cascade -> ovec, then last GEMM -> d_out
  final_cascade<<<dim3(4096), blk, 0, stream>>>(
      h_big, scale2, shift2, gs0, gs1, gs2, bufFs, ovec_bf);
  gemm_last<<<dim3(1, 128), blk, 0, stream>>>(ovec_bf, lastWt, last_b, (float*)d_out);
}

// Round 13
// 248.103 us; speedup vs baseline: 6.1239x; 1.0272x over previous
//
#include <hip/hip_runtime.h>
#include <math.h>

// ---------------------------------------------------------------------------
// ModularSelectCascadeNet forward. B=16384, M=8, NUM_LAYERS=4.
// R13: R12 with gemm_mod reverted to the R11-proven form (43 µs local optimum;
//      R12's swizzle+Cs variant halved occupancy and regressed to 51 µs).
// ---------------------------------------------------------------------------

typedef short bf16x8 __attribute__((ext_vector_type(8)));
typedef float f32x4 __attribute__((ext_vector_type(4)));

__device__ __forceinline__ unsigned short f2bf(float f) {
  unsigned u = __float_as_uint(f);
  u += 0x7fffu + ((u >> 16) & 1u);
  return (unsigned short)(u >> 16);
}
__device__ __forceinline__ float bf2f(unsigned short h) {
  return __uint_as_float(((unsigned)h) << 16);
}
__device__ __forceinline__ unsigned pack2(float a, float b) {
  return ((unsigned)f2bf(b) << 16) | f2bf(a);
}
__device__ __forceinline__ void gload_lds16(const void* g, void* l) {
  __builtin_amdgcn_global_load_lds(
      (const __attribute__((address_space(1))) unsigned int*)g,
      (__attribute__((address_space(3))) unsigned int*)l, 16, 0, 0);
}
__device__ __forceinline__ bf16x8 relu_bf8(bf16x8 v) {
  bf16x8 r;
  #pragma unroll
  for (int j = 0; j < 8; ++j) r[j] = v[j] > 0 ? v[j] : (short)0;
  return r;
}

#define EPI_NONE  0
#define EPI_RELU  1
#define EPI_STATS 4

// ---------------------------------------------------------------------------
// Prep: weight transposes + lastW + selFt + stats zero. 506 blocks.
__global__ __launch_bounds__(256) void prep_all(
    const float* __restrict__ base_W0, const float* __restrict__ em_W0,
    const float* __restrict__ base_W1, const float* __restrict__ gat_W0,
    const float* __restrict__ gat_W1, const float* __restrict__ sel_W,
    const float* __restrict__ cond_W, const float* __restrict__ last_W,
    const float* __restrict__ selF_W,
    unsigned short* __restrict__ W0t, unsigned short* __restrict__ emW0t,
    unsigned short* __restrict__ W1t, unsigned short* __restrict__ g0t,
    unsigned short* __restrict__ g1t, unsigned short* __restrict__ selWt,
    unsigned short* __restrict__ condWt, unsigned short* __restrict__ lastWt,
    unsigned short* __restrict__ selFt, float* __restrict__ stats)
{
  __shared__ float t[32][33];
  int bid = blockIdx.x;
  const int tid = threadIdx.x;
  const int tx = tid & 31, ty = tid >> 5;

  if (bid < 496) {
    const float* src; unsigned short* dst; int K, N, KP, gx, local;
    if (bid < 64)       { src = base_W0; dst = W0t;   K = 128; N = 400; KP = 128; gx = 4;  local = bid; }
    else if (bid < 128) { src = em_W0;   dst = emW0t; K = 128; N = 400; KP = 128; gx = 4;  local = bid - 64; }
    else if (bid < 232) { src = base_W1; dst = W1t;   K = 400; N = 256; KP = 416; gx = 13; local = bid - 128; }
    else if (bid < 336) { src = gat_W0;  dst = g0t;   K = 400; N = 256; KP = 416; gx = 13; local = bid - 232; }
    else if (bid < 400) { src = gat_W1;  dst = g1t;   K = 256; N = 256; KP = 256; gx = 8;  local = bid - 336; }
    else if (bid < 448) {
      const int i = (bid - 400) / 16;
      src = sel_W + i * 16384; dst = selWt + i * 16384;
      K = 256; N = 64; KP = 256; gx = 8; local = (bid - 400) % 16;
    } else {
      const int i = (bid - 448) / 16;
      src = cond_W + i * 16384; dst = condWt + i * 16384;
      K = 64; N = 256; KP = 64; gx = 2; local = (bid - 448) % 16;
    }
    const int k0 = (local % gx) * 32, n0 = (local / gx) * 32;
    #pragma unroll
    for (int p = 0; p < 4; ++p) {
      const int k = k0 + ty + p * 8;
      t[ty + p * 8][tx] = (k < K && n0 + tx < N) ? src[(size_t)k * N + n0 + tx] : 0.f;
    }
    __syncthreads();
    #pragma unroll
    for (int p = 0; p < 4; ++p) {
      const int n = n0 + ty + p * 8;
      dst[(size_t)n * KP + k0 + tx] = f2bf(t[tx][ty + p * 8]);
    }
    return;
  }
  bid -= 496;

  if (bid < 8) {
    const int k0 = bid * 32;
    #pragma unroll
    for (int p = 0; p < 4; ++p)
      t[ty + p * 8][tx] = (tx < 18) ? last_W[(size_t)(k0 + ty + p * 8) * 18 + tx] : 0.f;
    __syncthreads();
    #pragma unroll
    for (int p = 0; p < 4; ++p) {
      const int n = ty + p * 8;
      lastWt[(size_t)n * 256 + k0 + tx] = f2bf(t[tx][n]);
      lastWt[(size_t)(n + 32) * 256 + k0 + tx] = 0;
    }
    return;
  }
  bid -= 8;

  if (bid == 0) {  // selFt: [256][8] f32 -> bf16 [16][256] (rows 8..15 zero)
    const int k = tid;
    #pragma unroll
    for (int j = 0; j < 8; ++j) selFt[j * 256 + k] = f2bf(selF_W[k * 8 + j]);
    #pragma unroll
    for (int j = 8; j < 16; ++j) selFt[j * 256 + k] = 0;
    return;
  }

  for (int i = tid; i < 4608; i += 256) stats[i] = 0.f;
}

// ---------------------------------------------------------------------------
// W0 GEMM (fp32 A, converted during reg->LDS staging). grid (4, 128, 2).
__global__ __launch_bounds__(256) void gemm_w0(
    const float* __restrict__ Ax, const float* __restrict__ Ae,
    const unsigned short* __restrict__ Wx, const unsigned short* __restrict__ We,
    const float* __restrict__ bx, const float* __restrict__ be,
    unsigned short* __restrict__ Cx, unsigned short* __restrict__ Ce)
{
  __shared__ unsigned short As[128 * 32];
  __shared__ unsigned short Bs[128 * 32];
  const float* Ap = blockIdx.z ? Ae : Ax;
  const unsigned short* Wp = blockIdx.z ? We : Wx;
  const float* bp = blockIdx.z ? be : bx;
  unsigned short* Cp = blockIdx.z ? Ce : Cx;
  const int row0 = blockIdx.y * 128;
  const int n0 = blockIdx.x * 128;
  const int tid = threadIdx.x;
  const int wid = tid >> 6, lane = tid & 63;
  const int wr = wid >> 1, wc = wid & 1;
  const int arow = tid >> 2, kcol = (tid & 3) * 8;
  const int lr = lane & 15, lk = (lane >> 4) * 8;
  const int lrow = (lane >> 4) * 4;

  f32x4 acc[4][4] = {};
  for (int k0 = 0; k0 < 128; k0 += 32) {
    {
      const float4* s1 = reinterpret_cast<const float4*>(
          Ap + (size_t)(row0 + arow) * 128 + k0 + kcol);
      uint4 w1 = {pack2(s1[0].x, s1[0].y), pack2(s1[0].z, s1[0].w),
                  pack2(s1[1].x, s1[1].y), pack2(s1[1].z, s1[1].w)};
      *reinterpret_cast<uint4*>(&As[arow * 32 + kcol]) = w1;
      const float4* s2 = reinterpret_cast<const float4*>(
          Ap + (size_t)(row0 + 64 + arow) * 128 + k0 + kcol);
      uint4 w2 = {pack2(s2[0].x, s2[0].y), pack2(s2[0].z, s2[0].w),
                  pack2(s2[1].x, s2[1].y), pack2(s2[1].z, s2[1].w)};
      *reinterpret_cast<uint4*>(&As[(64 + arow) * 32 + kcol]) = w2;
    }
    gload_lds16(Wp + (size_t)(n0 + arow) * 128 + k0 + kcol, (char*)Bs + tid * 16);
    gload_lds16(Wp + (size_t)(n0 + 64 + arow) * 128 + k0 + kcol,
                (char*)Bs + 4096 + tid * 16);
    __syncthreads();
    bf16x8 a[4], b[4];
    #pragma unroll
    for (int i = 0; i < 4; ++i)
      a[i] = *reinterpret_cast<const bf16x8*>(&As[(wr * 64 + i * 16 + lr) * 32 + lk]);
    #pragma unroll
    for (int j = 0; j < 4; ++j)
      b[j] = *reinterpret_cast<const bf16x8*>(&Bs[(wc * 64 + j * 16 + lr) * 32 + lk]);
    #pragma unroll
    for (int i = 0; i < 4; ++i)
      #pragma unroll
      for (int j = 0; j < 4; ++j)
        acc[i][j] = __builtin_amdgcn_mfma_f32_16x16x32_bf16(a[i], b[j], acc[i][j], 0, 0, 0);
    __syncthreads();
  }
  #pragma unroll
  for (int j = 0; j < 4; ++j) {
    const int col = n0 + wc * 64 + j * 16 + lr;
    if (col >= 416) continue;
    const bool real = col < 400;
    const float bv = real ? bp[col] : 0.f;
    #pragma unroll
    for (int i = 0; i < 4; ++i) {
      #pragma unroll
      for (int r = 0; r < 4; ++r) {
        const int row = row0 + wr * 64 + i * 16 + lrow + r;
        float v = real ? fmaxf(acc[i][j][r] + bv, 0.f) : 0.f;
        Cp[(size_t)row * 416 + col] = f2bf(v);
      }
    }
  }
}

// ---------------------------------------------------------------------------
// Batched mid GEMM: z=0: out = h1 @ W1t + b1 (raw, bn1 stats);
//                   z=1: si = relu(h1e @ g0t + gb0). BN=64, WM=4, K=416.
__global__ __launch_bounds__(256) void gemm_mid(
    const unsigned short* __restrict__ A0, const unsigned short* __restrict__ W0,
    const float* __restrict__ b0, unsigned short* __restrict__ C0,
    const unsigned short* __restrict__ A1, const unsigned short* __restrict__ W1,
    const float* __restrict__ b1, unsigned short* __restrict__ C1,
    float* __restrict__ sum, float* __restrict__ sumsq)
{
  __shared__ unsigned short As[128 * 32];
  __shared__ unsigned short Bs[64 * 32];
  const bool z1 = blockIdx.z != 0;
  const unsigned short* A = z1 ? A1 : A0;
  const unsigned short* Wt = z1 ? W1 : W0;
  const float* bias = z1 ? b1 : b0;
  unsigned short* C = z1 ? C1 : C0;
  const int row0 = blockIdx.y * 128;
  const int n0 = blockIdx.x * 64;
  const int tid = threadIdx.x;
  const int wid = tid >> 6, lane = tid & 63;
  const int arow = tid >> 2, kcol = (tid & 3) * 8;
  const int lr = lane & 15, lk = (lane >> 4) * 8;
  const int lrow = (lane >> 4) * 4;

  f32x4 acc[2][4] = {};
  for (int k0 = 0; k0 < 416; k0 += 32) {
    gload_lds16(A + (size_t)(row0 + arow) * 416 + k0 + kcol, (char*)As + tid * 16);
    gload_lds16(A + (size_t)(row0 + 64 + arow) * 416 + k0 + kcol, (char*)As + 4096 + tid * 16);
    gload_lds16(Wt + (size_t)(n0 + arow) * 416 + k0 + kcol, (char*)Bs + tid * 16);
    __syncthreads();
    bf16x8 a[2], b[4];
    #pragma unroll
    for (int i = 0; i < 2; ++i)
      a[i] = *reinterpret_cast<const bf16x8*>(&As[(wid * 32 + i * 16 + lr) * 32 + lk]);
    #pragma unroll
    for (int j = 0; j < 4; ++j)
      b[j] = *reinterpret_cast<const bf16x8*>(&Bs[(j * 16 + lr) * 32 + lk]);
    #pragma unroll
    for (int i = 0; i < 2; ++i)
      #pragma unroll
      for (int j = 0; j < 4; ++j)
        acc[i][j] = __builtin_amdgcn_mfma_f32_16x16x32_bf16(a[i], b[j], acc[i][j], 0, 0, 0);
    __syncthreads();
  }
  #pragma unroll
  for (int j = 0; j < 4; ++j) {
    const int col = n0 + j * 16 + lr;
    const float bv = bias[col];
    float s = 0.f, q = 0.f;
    #pragma unroll
    for (int i = 0; i < 2; ++i) {
      #pragma unroll
      for (int r = 0; r < 4; ++r) {
        const int row = row0 + wid * 32 + i * 16 + lrow + r;
        float v = acc[i][j][r] + bv;
        if (z1) v = fmaxf(v, 0.f);
        const unsigned short hv = f2bf(v);
        C[(size_t)row * 256 + col] = hv;
        if (!z1) {
          const float vr = bf2f(hv);
          s += vr;
          q = fmaf(vr, vr, q);
        }
      }
    }
    if (!z1) {
      s += __shfl_xor(s, 16); s += __shfl_xor(s, 32);
      q += __shfl_xor(q, 16); q += __shfl_xor(q, 32);
      if (lane < 16) {
        atomicAdd(&sum[col], s);
        atomicAdd(&sumsq[col], q);
      }
    }
  }
}

// ---------------------------------------------------------------------------
// Generic bf16 MFMA GEMM (used for g1). BM=128, BK=32.
template<int BN, int WM, int WN, int EPI, bool RELU_A>
__global__ __launch_bounds__(256) void gemm_bf16(
    const unsigned short* __restrict__ A, int AS,
    const unsigned short* __restrict__ Wt, const float* __restrict__ bias,
    unsigned short* __restrict__ C, int CS, int Nreal, int NP, int K,
    const unsigned short* __restrict__ emb,
    float* __restrict__ sum, float* __restrict__ sumsq)
{
  constexpr int FRAG_M = 128 / WM / 16;
  constexpr int FRAG_N = BN / WN / 16;
  __shared__ unsigned short As[128 * 32];
  __shared__ unsigned short Bs[BN * 32];
  const int row0 = blockIdx.y * 128;
  const int n0 = blockIdx.x * BN;
  const int tid = threadIdx.x;
  const int wid = tid >> 6, lane = tid & 63;
  const int wr = wid / WN, wc = wid % WN;
  const int arow = tid >> 2;
  const int kcol = (tid & 3) * 8;
  const int lr = lane & 15, lk = (lane >> 4) * 8;
  const int lrow = (lane >> 4) * 4;

  f32x4 acc[FRAG_M][FRAG_N] = {};
  for (int k0 = 0; k0 < K; k0 += 32) {
    gload_lds16(A + (size_t)(row0 + arow) * AS + k0 + kcol, (char*)As + tid * 16);
    gload_lds16(A + (size_t)(row0 + 64 + arow) * AS + k0 + kcol, (char*)As + 4096 + tid * 16);
    gload_lds16(Wt + (size_t)(n0 + arow) * K + k0 + kcol, (char*)Bs + tid * 16);
    if constexpr (BN == 128)
      gload_lds16(Wt + (size_t)(n0 + 64 + arow) * K + k0 + kcol, (char*)Bs + 4096 + tid * 16);
    __syncthreads();
    bf16x8 a[FRAG_M], b[FRAG_N];
    #pragma unroll
    for (int i = 0; i < FRAG_M; ++i) {
      a[i] = *reinterpret_cast<const bf16x8*>(&As[(wr * (128 / WM) + i * 16 + lr) * 32 + lk]);
      if (RELU_A) a[i] = relu_bf8(a[i]);
    }
    #pragma unroll
    for (int j = 0; j < FRAG_N; ++j)
      b[j] = *reinterpret_cast<const bf16x8*>(&Bs[(wc * (BN / WN) + j * 16 + lr) * 32 + lk]);
    #pragma unroll
    for (int i = 0; i < FRAG_M; ++i)
      #pragma unroll
      for (int j = 0; j < FRAG_N; ++j)
        acc[i][j] = __builtin_amdgcn_mfma_f32_16x16x32_bf16(a[i], b[j], acc[i][j], 0, 0, 0);
    __syncthreads();
  }
  #pragma unroll
  for (int j = 0; j < FRAG_N; ++j) {
    const int col = n0 + wc * (BN / WN) + j * 16 + lr;
    if (col >= NP) continue;
    const bool real = col < Nreal;
    const float bv = real ? bias[col] : 0.f;
    float s = 0.f, q = 0.f;
    #pragma unroll
    for (int i = 0; i < FRAG_M; ++i) {
      #pragma unroll
      for (int r = 0; r < 4; ++r) {
        const int row = row0 + wr * (128 / WM) + i * 16 + lrow + r;
        float v = acc[i][j][r] + bv;
        if (EPI == EPI_RELU) v = fmaxf(v, 0.f);
        if (!real) v = 0.f;
        const unsigned short hv = f2bf(v);
        C[(size_t)row * CS + col] = hv;
        if (EPI == EPI_STATS) {
          const float vr = bf2f(hv);
          s += vr;
          q = fmaf(vr, vr, q);
        }
      }
    }
    if (EPI == EPI_STATS) {
      s += __shfl_xor(s, 16); s += __shfl_xor(s, 32);
      q += __shfl_xor(q, 16); q += __shfl_xor(q, 32);
      if (lane < 16) {
        atomicAdd(&sum[col], s);
        atomicAdd(&sumsq[col], q);
      }
    }
  }
}

// ---------------------------------------------------------------------------
// Mod-einsum GEMM (R11-proven form): R5 LDS structure + bijective XCD swizzle.
// 1-D grid of 2048 blocks; swz=(lin&7)*256+lin>>3.
__global__ __launch_bounds__(256) void gemm_mod(
    const unsigned short* __restrict__ A,    // out_bf [16384][256]
    const unsigned short* __restrict__ Wt,   // modWt [2048][256]
    const float* __restrict__ bias, unsigned short* __restrict__ C,
    float* __restrict__ sum, float* __restrict__ sumsq)
{
  __shared__ unsigned short As[128 * 32];
  __shared__ unsigned short Bs[128 * 32];
  const int lin = blockIdx.x;
  const int swz = (lin & 7) * 256 + (lin >> 3);
  const int row0 = (swz >> 4) * 128;
  const int n0 = (swz & 15) * 128;
  const int tid = threadIdx.x;
  const int wid = tid >> 6, lane = tid & 63;
  const int wr = wid >> 1, wc = wid & 1;
  const int arow = tid >> 2;
  const int kcol = (tid & 3) * 8;
  const int lr = lane & 15, lk = (lane >> 4) * 8;
  const int lrow = (lane >> 4) * 4;

  f32x4 acc[4][4] = {};
  for (int k0 = 0; k0 < 256; k0 += 32) {
    gload_lds16(A + (size_t)(row0 + arow) * 256 + k0 + kcol, (char*)As + tid * 16);
    gload_lds16(A + (size_t)(row0 + 64 + arow) * 256 + k0 + kcol, (char*)As + 4096 + tid * 16);
    gload_lds16(Wt + (size_t)(n0 + arow) * 256 + k0 + kcol, (char*)Bs + tid * 16);
    gload_lds16(Wt + (size_t)(n0 + 64 + arow) * 256 + k0 + kcol, (char*)Bs + 4096 + tid * 16);
    __syncthreads();
    bf16x8 a[4], b[4];
    #pragma unroll
    for (int i = 0; i < 4; ++i)
      a[i] = *reinterpret_cast<const bf16x8*>(&As[(wr * 64 + i * 16 + lr) * 32 + lk]);
    #pragma unroll
    for (int j = 0; j < 4; ++j)
      b[j] = *reinterpret_cast<const bf16x8*>(&Bs[(wc * 64 + j * 16 + lr) * 32 + lk]);
    #pragma unroll
    for (int i = 0; i < 4; ++i)
      #pragma unroll
      for (int j = 0; j < 4; ++j)
        acc[i][j] = __builtin_amdgcn_mfma_f32_16x16x32_bf16(a[i], b[j], acc[i][j], 0, 0, 0);
    __syncthreads();
  }
  #pragma unroll
  for (int j = 0; j < 4; ++j) {
    const int col = n0 + wc * 64 + j * 16 + lr;
    const float bv = bias[col];
    float s = 0.f, q = 0.f;
    #pragma unroll
    for (int i = 0; i < 4; ++i) {
      #pragma unroll
      for (int r = 0; r < 4; ++r) {
        const int row = row0 + wr * 64 + i * 16 + lrow + r;
        const unsigned short hv = f2bf(acc[i][j][r] + bv);
        C[(size_t)row * 2048 + col] = hv;
        const float vr = bf2f(hv);
        s += vr;
        q = fmaf(vr, vr, q);
      }
    }
    s += __shfl_xor(s, 16); s += __shfl_xor(s, 32);
    q += __shfl_xor(q, 16); q += __shfl_xor(q, 32);
    if (lane < 16) {
      atomicAdd(&sum[col], s);
      atomicAdd(&sumsq[col], q);
    }
  }
}

// ---------------------------------------------------------------------------
// Fused select iteration (R11-proven).
template<bool RELU_A>
__global__ __launch_bounds__(256) void fused_select(
    const unsigned short* __restrict__ A, const unsigned short* __restrict__ selWt,
    const float* __restrict__ selb, const unsigned short* __restrict__ condWt,
    const float* __restrict__ condb, const unsigned short* __restrict__ emb,
    const float* __restrict__ u, int u_off,
    float* __restrict__ gs, unsigned short* __restrict__ siout)
{
  __shared__ unsigned short As[128 * 32];
  __shared__ unsigned short Bs[64 * 32];
  __shared__ unsigned short Ls[128 * 72];
  const int tid = threadIdx.x;
  const int wid = tid >> 6, lane = tid & 63;
  const int lr = lane & 15, hi = lane >> 4;
  const int lk = hi * 8;
  const int row0 = blockIdx.x * 128;
  const int arow = tid >> 2, kcol = (tid & 3) * 8;

  {
    f32x4 acc[2][4] = {};
    for (int k0 = 0; k0 < 256; k0 += 32) {
      gload_lds16(A + (size_t)(row0 + arow) * 256 + k0 + kcol, (char*)As + tid * 16);
      gload_lds16(A + (size_t)(row0 + 64 + arow) * 256 + k0 + kcol, (char*)As + 4096 + tid * 16);
      gload_lds16(selWt + (size_t)arow * 256 + k0 + kcol, (char*)Bs + tid * 16);
      __syncthreads();
      bf16x8 a[2], b[4];
      #pragma unroll
      for (int i = 0; i < 2; ++i) {
        a[i] = *reinterpret_cast<const bf16x8*>(&As[(wid * 32 + i * 16 + lr) * 32 + lk]);
        if (RELU_A) a[i] = relu_bf8(a[i]);
      }
      #pragma unroll
      for (int j = 0; j < 4; ++j)
        b[j] = *reinterpret_cast<const bf16x8*>(&Bs[(j * 16 + lr) * 32 + lk]);
      #pragma unroll
      for (int i = 0; i < 2; ++i)
        #pragma unroll
        for (int j = 0; j < 4; ++j)
          acc[i][j] = __builtin_amdgcn_mfma_f32_16x16x32_bf16(a[i], b[j], acc[i][j], 0, 0, 0);
      __syncthreads();
    }
    #pragma unroll
    for (int j = 0; j < 4; ++j) {
      const int col = j * 16 + lr;
      const float bv = selb[col];
      #pragma unroll
      for (int i = 0; i < 2; ++i)
        #pragma unroll
        for (int r = 0; r < 4; ++r) {
          const int row = wid * 32 + i * 16 + hi * 4 + r;
          Ls[row * 72 + col] = f2bf(tanhf(acc[i][j][r] + bv));
        }
    }
  }
  __syncthreads();

  #pragma unroll
  for (int p = 0; p < 4; ++p) {
    const int pair = p * 256 + tid;
    const int bl = pair >> 3, mm = pair & 7;
    const int bg = row0 + bl;
    float v[8];
    #pragma unroll
    for (int jj = 0; jj < 8; ++jj) v[jj] = bf2f(Ls[bl * 72 + mm * 8 + jj]);
    const float* up = u + (size_t)bg * 192 + u_off + mm * 8;
    #pragma unroll
    for (int jj = 0; jj < 8; ++jj) {
      const float uu = fminf(fmaxf(up[jj], 1e-10f), 0.9999999f);
      v[jj] -= logf(-logf(uu));
    }
    float mx = v[0];
    #pragma unroll
    for (int jj = 1; jj < 8; ++jj) mx = fmaxf(mx, v[jj]);
    float s = 0.f;
    #pragma unroll
    for (int jj = 0; jj < 8; ++jj) { v[jj] = expf(v[jj] - mx); s += v[jj]; }
    const float inv = 1.f / s;
    float* op = gs + (size_t)bg * 64 + mm * 8;
    #pragma unroll
    for (int jj = 0; jj < 8; ++jj) op[jj] = v[jj] * inv;
  }

  {
    const int wr2 = wid >> 1, wc2 = wid & 1;
    f32x4 acc2[4][8] = {};
    #pragma unroll
    for (int kq = 0; kq < 2; ++kq) {
      const int k0 = kq * 32;
      bf16x8 a2[4];
      #pragma unroll
      for (int i = 0; i < 4; ++i)
        a2[i] = *reinterpret_cast<const bf16x8*>(
            &Ls[(wr2 * 64 + i * 16 + lr) * 72 + k0 + hi * 8]);
      #pragma unroll
      for (int j = 0; j < 8; ++j) {
        const bf16x8 b2 = *reinterpret_cast<const bf16x8*>(
            condWt + (size_t)(wc2 * 128 + j * 16 + lr) * 64 + k0 + hi * 8);
        #pragma unroll
        for (int i = 0; i < 4; ++i)
          acc2[i][j] = __builtin_amdgcn_mfma_f32_16x16x32_bf16(a2[i], b2, acc2[i][j], 0, 0, 0);
      }
    }
    #pragma unroll
    for (int j = 0; j < 8; ++j) {
      const int col = wc2 * 128 + j * 16 + lr;
      const float bv = condb[col];
      #pragma unroll
      for (int i = 0; i < 4; ++i)
        #pragma unroll
        for (int r = 0; r < 4; ++r) {
          const int row = row0 + wr2 * 64 + i * 16 + hi * 4 + r;
          float vv = (acc2[i][j][r] + bv) * bf2f(emb[(size_t)row * 256 + col]);
          siout[(size_t)row * 256 + col] = f2bf(fmaxf(vv, 0.f));
        }
    }
  }
}

// ---------------------------------------------------------------------------
// Final select: MFMA GEMM (K=256, N=16 pad, 8 real) + gumbel epilogue.
__global__ __launch_bounds__(256) void gemm_fsel(
    const unsigned short* __restrict__ A, const unsigned short* __restrict__ Wt,
    const float* __restrict__ bias, const float* __restrict__ u,
    float* __restrict__ fs)
{
  __shared__ unsigned short As[128 * 32];
  __shared__ unsigned short Bs[16 * 32];
  const int row0 = blockIdx.y * 128;
  const int tid = threadIdx.x;
  const int wid = tid >> 6, lane = tid & 63;
  const int arow = tid >> 2, kcol = (tid & 3) * 8;
  const int lr = lane & 15, hi = lane >> 4;
  const int lk = hi * 8;

  f32x4 acc[2] = {};
  for (int k0 = 0; k0 < 256; k0 += 32) {
    gload_lds16(A + (size_t)(row0 + arow) * 256 + k0 + kcol, (char*)As + tid * 16);
    gload_lds16(A + (size_t)(row0 + 64 + arow) * 256 + k0 + kcol, (char*)As + 4096 + tid * 16);
    if (wid == 0)
      gload_lds16(Wt + (size_t)(lane >> 2) * 256 + k0 + (lane & 3) * 8, (char*)Bs + lane * 16);
    __syncthreads();
    bf16x8 a[2];
    #pragma unroll
    for (int i = 0; i < 2; ++i)
      a[i] = *reinterpret_cast<const bf16x8*>(&As[(wid * 32 + i * 16 + lr) * 32 + lk]);
    const bf16x8 b = *reinterpret_cast<const bf16x8*>(&Bs[lr * 32 + lk]);
    #pragma unroll
    for (int i = 0; i < 2; ++i)
      acc[i] = __builtin_amdgcn_mfma_f32_16x16x32_bf16(a[i], b, acc[i], 0, 0, 0);
    __syncthreads();
  }
  const float bv = (lr < 8) ? bias[lr] : 0.f;
  #pragma unroll
  for (int i = 0; i < 2; ++i) {
    #pragma unroll
    for (int r = 0; r < 4; ++r) {
      const int row = row0 + wid * 32 + i * 16 + hi * 4 + r;
      float v = acc[i][r] + bv;
      if (lr < 8) {
        const float uu = fminf(fmaxf(u[(size_t)row * 8 + lr], 1e-10f), 0.9999999f);
        v -= logf(-logf(uu));
      }
      float mx = v;
      mx = fmaxf(mx, __shfl_xor(mx, 1));
      mx = fmaxf(mx, __shfl_xor(mx, 2));
      mx = fmaxf(mx, __shfl_xor(mx, 4));
      const float e = expf(v - mx);
      float ssum = e;
      ssum += __shfl_xor(ssum, 1);
      ssum += __shfl_xor(ssum, 2);
      ssum += __shfl_xor(ssum, 4);
      if (lr < 8) fs[(size_t)row * 8 + lr] = e / ssum;
    }
  }
}

// ---------------------------------------------------------------------------
// Fold mod weights with inline bn1 finalize. grid (8, 8, 9).
__global__ __launch_bounds__(256) void fold_modw_all(
    const float* __restrict__ W, const float* __restrict__ g1,
    const float* __restrict__ b1, const float* __restrict__ modb,
    const float* __restrict__ sum1, const float* __restrict__ sumsq1,
    unsigned short* __restrict__ Wt, float* __restrict__ bias2)
{
  const float invB = 1.f / 16384.f;
  if (blockIdx.z == 8) {
    if (blockIdx.y != 0) return;
    const int m = blockIdx.x, h = threadIdx.x;
    float acc = modb[m * 256 + h];
    for (int d = 0; d < 256; ++d) {
      const float mean = sum1[d] * invB;
      const float var = sumsq1[d] * invB - mean * mean;
      const float r = rsqrtf(var + 1e-5f);
      const float c = b1[m * 256 + d] - mean * r * g1[m * 256 + d];
      acc = fmaf(c, W[((size_t)m * 256 + d) * 256 + h], acc);
    }
    bias2[m * 256 + h] = acc;
    return;
  }
  __shared__ float t[32][33];
  const int m = blockIdx.z, d0 = blockIdx.y * 32, h0 = blockIdx.x * 32;
  const int tx = threadIdx.x & 31, ty = threadIdx.x >> 5;
  #pragma unroll
  for (int p = 0; p < 4; ++p) {
    const int d = d0 + ty + p * 8;
    const float mean = sum1[d] * invB;
    const float var = sumsq1[d] * invB - mean * mean;
    const float r = rsqrtf(var + 1e-5f);
    t[ty + p * 8][tx] = W[((size_t)m * 256 + d) * 256 + h0 + tx] * r * g1[m * 256 + d];
  }
  __syncthreads();
  #pragma unroll
  for (int p = 0; p < 4; ++p) {
    const int h = h0 + ty + p * 8;
    Wt[((size_t)m * 256 + h) * 256 + d0 + tx] = f2bf(t[tx][ty + p * 8]);
  }
}

// bn2 finalize.
__global__ void finalize_bn2(const float* __restrict__ sum, const float* __restrict__ sumsq,
                             const float* __restrict__ g, const float* __restrict__ b,
                             float* __restrict__ scale, float* __restrict__ shift)
{
  const int i = blockIdx.x * 256 + threadIdx.x;
  const float invB = 1.f / 16384.f;
  const float m = sum[i] * invB;
  const float v = sumsq[i] * invB - m * m;
  const float r = rsqrtf(v + 1e-5f);
  const float sc = r * g[i];
  scale[i] = sc;
  shift[i] = b[i] - m * sc;
}

// ---------------------------------------------------------------------------
// Cascade (R5-proven).
__global__ __launch_bounds__(256) void final_cascade(
    const unsigned short* __restrict__ H, const float* __restrict__ scale2,
    const float* __restrict__ shift2, const float* __restrict__ gs0,
    const float* __restrict__ gs1, const float* __restrict__ gs2,
    const float* __restrict__ fs, unsigned short* __restrict__ ovec)
{
  const int wave = threadIdx.x >> 6, lane = threadIdx.x & 63;
  const int b = __builtin_amdgcn_readfirstlane(blockIdx.x * 4 + wave);
  const int c0 = lane << 2;

  float prev[8][4];
  #pragma unroll
  for (int m = 0; m < 8; ++m) {
    const int gc = m * 256 + c0;
    const ushort4 h = *reinterpret_cast<const ushort4*>(&H[(size_t)b * 2048 + gc]);
    const float4 sc = *reinterpret_cast<const float4*>(&scale2[gc]);
    const float4 sh = *reinterpret_cast<const float4*>(&shift2[gc]);
    prev[m][0] = bf2f(h.x) * sc.x + sh.x;
    prev[m][1] = bf2f(h.y) * sc.y + sh.y;
    prev[m][2] = bf2f(h.z) * sc.z + sh.z;
    prev[m][3] = bf2f(h.w) * sc.w + sh.w;
  }

  const float* sel0 = gs2 + (size_t)b * 64;
  const float* sel1 = gs1 + (size_t)b * 64;
  const float* sel2 = gs0 + (size_t)b * 64;
  #pragma unroll
  for (int l = 0; l < 3; ++l) {
    const float* sp = (l == 0) ? sel0 : (l == 1) ? sel1 : sel2;
    float nw[8][4];
    #pragma unroll
    for (int m = 0; m < 8; ++m) {
      float a0 = 0.f, a1 = 0.f, a2 = 0.f, a3 = 0.f;
      #pragma unroll
      for (int k = 0; k < 8; ++k) {
        const float s = sp[m * 8 + k];
        a0 = fmaf(s, prev[k][0], a0);
        a1 = fmaf(s, prev[k][1], a1);
        a2 = fmaf(s, prev[k][2], a2);
        a3 = fmaf(s, prev[k][3], a3);
      }
      nw[m][0] = fmaxf(a0, 0.f); nw[m][1] = fmaxf(a1, 0.f);
      nw[m][2] = fmaxf(a2, 0.f); nw[m][3] = fmaxf(a3, 0.f);
    }
    #pragma unroll
    for (int m = 0; m < 8; ++m)
      #pragma unroll
      for (int c = 0; c < 4; ++c)
        prev[m][c] = nw[m][c];
  }

  const float* fp = fs + (size_t)b * 8;
  float ov[4] = {0.f, 0.f, 0.f, 0.f};
  #pragma unroll
  for (int m = 0; m < 8; ++m) {
    const float s = fp[m];
    ov[0] = fmaf(s, prev[m][0], ov[0]);
    ov[1] = fmaf(s, prev[m][1], ov[1]);
    ov[2] = fmaf(s, prev[m][2], ov[2]);
    ov[3] = fmaf(s, prev[m][3], ov[3]);
  }
  ushort4 o;
  o.x = f2bf(ov[0]); o.y = f2bf(ov[1]); o.z = f2bf(ov[2]); o.w = f2bf(ov[3]);
  *reinterpret_cast<ushort4*>(&ovec[(size_t)b * 256 + c0]) = o;
}

// ---------------------------------------------------------------------------
// Last GEMM (R5-proven).
__global__ __launch_bounds__(256) void gemm_last(
    const unsigned short* __restrict__ A, const unsigned short* __restrict__ Wt,
    const float* __restrict__ bias, float* __restrict__ out)
{
  __shared__ unsigned short As[128 * 32];
  __shared__ unsigned short Bs[64 * 32];
  const int row0 = blockIdx.y * 128;
  const int tid = threadIdx.x;
  const int wid = tid >> 6, lane = tid & 63;
  const int arow = tid >> 2;
  const int kcol = (tid & 3) * 8;
  const int lr = lane & 15, lk = (lane >> 4) * 8;
  const int lrow = (lane >> 4) * 4;

  f32x4 acc[2][4] = {};
  for (int k0 = 0; k0 < 256; k0 += 32) {
    gload_lds16(A + (size_t)(row0 + arow) * 256 + k0 + kcol, (char*)As + tid * 16);
    gload_lds16(A + (size_t)(row0 + 64 + arow) * 256 + k0 + kcol, (char*)As + 4096 + tid * 16);
    gload_lds16(Wt + (size_t)arow * 256 + k0 + kcol, (char*)Bs + tid * 16);
    __syncthreads();
    bf16x8 a[2], b[4];
    #pragma unroll
    for (int i = 0; i < 2; ++i)
      a[i] = *reinterpret_cast<const bf16x8*>(&As[(wid * 32 + i * 16 + lr) * 32 + lk]);
    #pragma unroll
    for (int j = 0; j < 4; ++j)
      b[j] = *reinterpret_cast<const bf16x8*>(&Bs[(j * 16 + lr) * 32 + lk]);
    #pragma unroll
    for (int i = 0; i < 2; ++i)
      #pragma unroll
      for (int j = 0; j < 4; ++j)
        acc[i][j] = __builtin_amdgcn_mfma_f32_16x16x32_bf16(a[i], b[j], acc[i][j], 0, 0, 0);
    __syncthreads();
  }
  #pragma unroll
  for (int j = 0; j < 2; ++j) {
    const int col = j * 16 + lr;
    if (col >= 18) continue;
    const float bv = bias[col];
    #pragma unroll
    for (int i = 0; i < 2; ++i) {
      #pragma unroll
      for (int r = 0; r < 4; ++r) {
        const int row = row0 + wid * 32 + i * 16 + lrow + r;
        out[(size_t)row * 18 + col] = acc[i][j][r] + bv;
      }
    }
  }
}

extern "C" void kernel_launch(void* const* d_in, const int* in_sizes, int n_in,
                              void* d_out, int out_size, void* d_ws, size_t ws_size,
                              hipStream_t stream)
{
  (void)in_sizes; (void)n_in; (void)out_size; (void)ws_size;
  const float* x       = (const float*)d_in[0];
  const float* embi    = (const float*)d_in[1];
  const float* u_sel   = (const float*)d_in[2];
  const float* u_fin   = (const float*)d_in[3];
  const float* base_W0 = (const float*)d_in[4];
  const float* base_b0 = (const float*)d_in[5];
  const float* base_W1 = (const float*)d_in[6];
  const float* base_b1 = (const float*)d_in[7];
  const float* em_W0   = (const float*)d_in[8];
  const float* em_b0   = (const float*)d_in[9];
  const float* gat_W0  = (const float*)d_in[10];
  const float* gat_b0  = (const float*)d_in[11];
  const float* gat_W1  = (const float*)d_in[12];
  const float* gat_b1  = (const float*)d_in[13];
  const float* sel_W   = (const float*)d_in[14];
  const float* sel_b   = (const float*)d_in[15];
  const float* selF_W  = (const float*)d_in[16];
  const float* selF_b  = (const float*)d_in[17];
  const float* cond_W  = (const float*)d_in[18];
  const float* cond_b  = (const float*)d_in[19];
  const float* mod_W   = (const float*)d_in[20];
  const float* mod_b   = (const float*)d_in[21];
  const float* last_W  = (const float*)d_in[22];
  const float* last_b  = (const float*)d_in[23];
  const float* bn1_g   = (const float*)d_in[24];
  const float* bn1_b   = (const float*)d_in[25];
  const float* bn2_g   = (const float*)d_in[26];
  const float* bn2_b   = (const float*)d_in[27];

  // --- workspace layout (byte offsets) ---
  char* WSB = (char*)d_ws;
  unsigned short* h_big    = (unsigned short*)(WSB + 0);          // 16384x2048 bf16
  unsigned short* h1e      = (unsigned short*)(WSB + 67108864);   // 16384x416 (em)
  unsigned short* ovec_bf  = (unsigned short*)(WSB + 67108864);   // overlaps dead h1e
  unsigned short* h1       = (unsigned short*)(WSB + 81000448);   // 16384x416 (base)
  unsigned short* emb_bf   = (unsigned short*)(WSB + 103020544);  // 16384x256
  unsigned short* si_bf    = (unsigned short*)(WSB + 111409152);  // 16384x256
  unsigned short* out_bf   = (unsigned short*)(WSB + 119797760);  // 16384x256
  float* gs0   = (float*)(WSB + 130283520);  // 16384x64
  float* gs1   = (float*)(WSB + 134477824);
  float* gs2   = (float*)(WSB + 138672128);
  float* bufFs = (float*)(WSB + 142866432);  // 16384x8
  unsigned short* W0t   = (unsigned short*)(WSB + 143390720);  // 512x128
  unsigned short* emW0t = (unsigned short*)(WSB + 143521792);  // 512x128
  unsigned short* W1t   = (unsigned short*)(WSB + 143652864);  // 256x416
  unsigned short* g0t   = (unsigned short*)(WSB + 143865856);  // 256x416
  unsigned short* g1t   = (unsigned short*)(WSB + 144078848);  // 256x256
  unsigned short* selWt = (unsigned short*)(WSB + 144209920);  // 3x64x256
  unsigned short* condWt= (unsigned short*)(WSB + 144308224);  // 3x256x64
  unsigned short* modWt = (unsigned short*)(WSB + 144406528);  // 8x256x256
  float* bias2  = (float*)(WSB + 146503680);  // 2048
  float* stats  = (float*)(WSB + 146511872);  // 4608 floats
  unsigned short* lastWt = (unsigned short*)(WSB + 146530304); // 64x256 bf16
  float* scale2 = (float*)(WSB + 146563072);  // 2048
  float* shift2 = (float*)(WSB + 146571264);  // 2048
  unsigned short* selFt = (unsigned short*)(WSB + 146579456);  // 16x256 bf16
  float* sum1   = stats;        float* sumsq1 = stats + 256;
  float* sum2   = stats + 512;  float* sumsq2 = stats + 2560;

  const dim3 blk(256);
  // prep (weight transposes + selFt + stats zero)
  prep_all<<<dim3(506), blk, 0, stream>>>(
      base_W0, em_W0, base_W1, gat_W0, gat_W1, sel_W, cond_W, last_W, selF_W,
      W0t, emW0t, W1t, g0t, g1t, selWt, condWt, lastWt, selFt, stats);

  // batched W0 GEMMs from fp32 inputs
  gemm_w0<<<dim3(4, 128, 2), blk, 0, stream>>>(
      x, embi, W0t, emW0t, base_b0, em_b0, h1, h1e);
  // batched mid GEMMs: z=0 W1->out (bn1 stats), z=1 g0->si (relu)
  gemm_mid<<<dim3(4, 128, 2), blk, 0, stream>>>(
      h1, W1t, base_b1, out_bf, h1e, g0t, gat_b0, si_bf, sum1, sumsq1);
  // g1 -> emb
  gemm_bf16<64, 4, 1, EPI_NONE, false><<<dim3(4, 128), blk, 0, stream>>>(
      si_bf, 256, g1t, gat_b1, emb_bf, 256, 256, 256, 256, nullptr, nullptr, nullptr);
  // fused select loop
  fused_select<true><<<dim3(128), blk, 0, stream>>>(
      emb_bf, selWt, sel_b, condWt, cond_b, emb_bf, u_sel, 0, gs0, si_bf);
  fused_select<false><<<dim3(128), blk, 0, stream>>>(
      si_bf, selWt + 16384, sel_b + 64, condWt + 16384, cond_b + 256, emb_bf,
      u_sel, 64, gs1, si_bf);
  fused_select<false><<<dim3(128), blk, 0, stream>>>(
      si_bf, selWt + 32768, sel_b + 128, condWt + 32768, cond_b + 512, emb_bf,
      u_sel, 128, gs2, si_bf);
  // final select (MFMA)
  gemm_fsel<<<dim3(1, 128), blk, 0, stream>>>(si_bf, selFt, selF_b, u_fin, bufFs);
  // bn1 finalize + mod weight fold + bias2
  fold_modw_all<<<dim3(8, 8, 9), blk, 0, stream>>>(
      mod_W, bn1_g, bn1_b, mod_b, sum1, sumsq1, modWt, bias2);
  // mod einsum -> h_big (fused bn2 stats)
  gemm_mod<<<dim3(2048), blk, 0, stream>>>(out_bf, modWt, bias2, h_big, sum2, sumsq2);
  finalize_bn2<<<dim3(8), blk, 0, stream>>>(sum2, sumsq2, bn2_g, bn2_b, scale2, shift2);
  // cascade -> ovec, then last GEMM -> d_out
  final_cascade<<<dim3(4096), blk, 0, stream>>>(
      h_big, scale2, shift2, gs0, gs1, gs2, bufFs, ovec_bf);
  gemm_last<<<dim3(1, 128), blk, 0, stream>>>(ovec_bf, lastWt, last_b, (float*)d_out);
}